// Round 2
// baseline (1035.594 us; speedup 1.0000x reference)
//
#include <hip/hip_runtime.h>

// ---------------- problem constants ----------------
constexpr int N_NODES = 30000;
constexpr int N_EDGES = 300000;
constexpr int GRAPHS  = 64;
constexpr int F_IN    = 33;
constexpr int HID     = 132;
constexpr int HEADS   = 4;
constexpr int HID4    = HEADS * HID;   // 528
constexpr int OUT_DIM = 128;
constexpr int GFC     = 1024;

// ---------------- workspace layout (float units, 64-float aligned) ----------------
constexpr size_t rnd64(size_t x) { return (x + 63) & ~(size_t)63; }
constexpr size_t O_DIS   = 0;
constexpr size_t O_CNT   = O_DIS   + rnd64(N_NODES);            // int
constexpr size_t O_IDP   = O_CNT   + rnd64(N_NODES);            // int, N+1
constexpr size_t O_CSR_S = O_IDP   + rnd64(N_NODES + 1);        // int, E
constexpr size_t O_CSR_W = O_CSR_S + rnd64(N_EDGES);            // float, E
constexpr size_t O_ES    = O_CSR_W + rnd64(N_EDGES);            // float, N*4
constexpr size_t O_ED    = O_ES    + rnd64(N_NODES * 4);
constexpr size_t O_TMP   = O_ED    + rnd64(N_NODES * 4);        // float, E*4 (CSR order)
constexpr size_t O_X1    = O_TMP   + rnd64((size_t)N_EDGES * 4);// float, N*HID (x1, later x3)
constexpr size_t O_X2    = O_X1    + rnd64((size_t)N_NODES * HID);
constexpr size_t O_XC    = O_X2    + rnd64((size_t)N_NODES * HID);
constexpr size_t O_HG    = O_XC    + rnd64((size_t)N_NODES * HID); // float, N*528 (h_gcn / h_gat / zpre)
constexpr size_t O_GE    = O_HG    + rnd64((size_t)N_NODES * HID4);// unsigned, G*HID
constexpr size_t O_G     = O_GE    + rnd64(GRAPHS * HID);
constexpr size_t O_GH    = O_G     + rnd64(GRAPHS * HID);          // float, G*GFC
// total ~30M floats ~120 MB

// ---------------- CSR build ----------------
__global__ void k_count(const int* __restrict__ ei, int* __restrict__ counts) {
    int e = blockIdx.x * 256 + threadIdx.x;
    if (e < N_EDGES) atomicAdd(&counts[ei[N_EDGES + e]], 1);
}

__global__ void k_scan(const int* __restrict__ counts, int* __restrict__ indptr) {
    __shared__ int buf[1024];
    __shared__ int carry_s;
    if (threadIdx.x == 0) carry_s = 0;
    __syncthreads();
    for (int base = 0; base < N_NODES; base += 1024) {
        int i = base + threadIdx.x;
        int v = (i < N_NODES) ? counts[i] : 0;
        buf[threadIdx.x] = v;
        __syncthreads();
        for (int off = 1; off < 1024; off <<= 1) {
            int t = (threadIdx.x >= off) ? buf[threadIdx.x - off] : 0;
            __syncthreads();
            buf[threadIdx.x] += t;
            __syncthreads();
        }
        int incl = buf[threadIdx.x];
        int carry = carry_s;
        if (i < N_NODES) indptr[i] = carry + incl - v;
        __syncthreads();
        if (threadIdx.x == 1023) carry_s = carry + buf[1023];
        __syncthreads();
    }
    if (threadIdx.x == 0) indptr[N_NODES] = carry_s;
}

__global__ void k_scatter(const int* __restrict__ ei, const float* __restrict__ ew,
                          const int* __restrict__ indptr, int* __restrict__ cursor,
                          int* __restrict__ csr_src, float* __restrict__ csr_w) {
    int e = blockIdx.x * 256 + threadIdx.x;
    if (e >= N_EDGES) return;
    int src = ei[e];
    int dst = ei[N_EDGES + e];
    int pos = indptr[dst] + atomicAdd(&cursor[dst], 1);
    csr_src[pos] = src;
    csr_w[pos] = ew[e];
}

__global__ void k_deg(const int* __restrict__ indptr, const float* __restrict__ csr_w,
                      float* __restrict__ dis) {
    int i = blockIdx.x * 256 + threadIdx.x;
    if (i >= N_NODES) return;
    float d = 1.0f;  // self loop weight
    int s = indptr[i], e = indptr[i + 1];
    for (int j = s; j < e; ++j) d += csr_w[j];
    dis[i] = (d > 0.f) ? rsqrtf(fmaxf(d, 1e-12f)) : 0.f;
}

// ---------------- generic tiled SGEMM: C[M,N] = A[M,K] @ B[K,N] ----------------
__global__ __launch_bounds__(256) void k_sgemm(
    const float* __restrict__ A, const float* __restrict__ B, float* __restrict__ C,
    int M, int N, int K, int accum, const float* __restrict__ bias, int relu) {
    constexpr int BM = 64, BN = 64, BK = 16;
    __shared__ float As[BK][BM];
    __shared__ float Bs[BK][BN];
    int bm = blockIdx.x * BM, bn = blockIdx.y * BN;
    int t = threadIdx.x;
    int tx = t % 16, ty = t / 16;
    float acc[4][4] = {};
    for (int k0 = 0; k0 < K; k0 += BK) {
        #pragma unroll
        for (int i = 0; i < 4; ++i) {
            int idx = t * 4 + i;
            int m = idx / BK, kk = idx % BK;
            float v = 0.f;
            if (bm + m < M && k0 + kk < K) v = A[(size_t)(bm + m) * K + k0 + kk];
            As[kk][m] = v;
        }
        #pragma unroll
        for (int i = 0; i < 4; ++i) {
            int idx = t * 4 + i;
            int kk = idx / BN, n = idx % BN;
            float v = 0.f;
            if (k0 + kk < K && bn + n < N) v = B[(size_t)(k0 + kk) * N + bn + n];
            Bs[kk][n] = v;
        }
        __syncthreads();
        int kmax = (K - k0 < BK) ? (K - k0) : BK;
        for (int kk = 0; kk < kmax; ++kk) {
            float a[4], b[4];
            #pragma unroll
            for (int i = 0; i < 4; ++i) a[i] = As[kk][ty * 4 + i];
            #pragma unroll
            for (int i = 0; i < 4; ++i) b[i] = Bs[kk][tx * 4 + i];
            #pragma unroll
            for (int r = 0; r < 4; ++r)
                #pragma unroll
                for (int c = 0; c < 4; ++c) acc[r][c] += a[r] * b[c];
        }
        __syncthreads();
    }
    #pragma unroll
    for (int r = 0; r < 4; ++r) {
        int row = bm + ty * 4 + r;
        if (row >= M) continue;
        #pragma unroll
        for (int c = 0; c < 4; ++c) {
            int col = bn + tx * 4 + c;
            if (col >= N) continue;
            float v = acc[r][c];
            if (bias) v += bias[col];
            if (accum) v += C[(size_t)row * N + col];
            if (relu) v = fmaxf(v, 0.f);
            C[(size_t)row * N + col] = v;
        }
    }
}

// ---------------- GCN aggregate: x1 = relu(sum norm*h[src] + dis^2*h[i] + b) ----------------
__global__ __launch_bounds__(64) void k_gcn_agg(
    const float* __restrict__ h, const int* __restrict__ indptr,
    const int* __restrict__ csr_src, const float* __restrict__ csr_w,
    const float* __restrict__ dis, const float* __restrict__ bias,
    float* __restrict__ out) {
    const int i = blockIdx.x;
    const int t = threadIdx.x;
    const float di = dis[i];
    const int s = indptr[i], e = indptr[i + 1];
    const float* hr = h + (size_t)i * HID;
    float nself = di * di;
    float acc0 = nself * hr[t];
    float acc1 = nself * hr[64 + t];
    float acc2 = (t < 4) ? nself * hr[128 + t] : 0.f;
    for (int j = s; j < e; ++j) {
        int src = csr_src[j];
        float nb = dis[src] * csr_w[j] * di;
        const float* hs = h + (size_t)src * HID;
        acc0 += nb * hs[t];
        acc1 += nb * hs[64 + t];
        if (t < 4) acc2 += nb * hs[128 + t];
    }
    float* orow = out + (size_t)i * HID;
    orow[t]      = fmaxf(acc0 + bias[t], 0.f);
    orow[64 + t] = fmaxf(acc1 + bias[64 + t], 0.f);
    if (t < 4) orow[128 + t] = fmaxf(acc2 + bias[128 + t], 0.f);
}

// ---------------- GAT attention coefficients: es/ed [N,4] ----------------
__global__ void k_esed(const float* __restrict__ hg, const float* __restrict__ as,
                       const float* __restrict__ ad, float* __restrict__ es,
                       float* __restrict__ ed) {
    int idx = blockIdx.x * 256 + threadIdx.x;
    if (idx >= N_NODES * HEADS) return;
    int n = idx >> 2, k = idx & 3;
    const float* hr = hg + (size_t)n * HID4 + k * HID;
    float s = 0.f, d = 0.f;
    for (int c = 0; c < HID; ++c) {
        float hv = hr[c];
        s += hv * as[k * HID + c];
        d += hv * ad[k * HID + c];
    }
    es[idx] = s;
    ed[idx] = d;
}

// ---------------- GAT per-node softmax + aggregate ----------------
__global__ __launch_bounds__(64) void k_gat_node(
    const float* __restrict__ hg, const float* __restrict__ es,
    const float* __restrict__ ed, const int* __restrict__ indptr,
    const int* __restrict__ csr_src, float* __restrict__ tmp,
    const float* __restrict__ bias, float* __restrict__ out, int do_relu) {
    const int i = blockIdx.x;
    const int t = threadIdx.x;
    const int k = t & 3;
    const int s = indptr[i];
    const int deg = indptr[i + 1] - s;
    const float edk = ed[i * 4 + k];
    float eself = es[i * 4 + k] + edk;
    eself = (eself >= 0.f) ? eself : 0.2f * eself;
    float m = eself;
    for (int j0 = 0; j0 < deg; j0 += 16) {
        int j = j0 + (t >> 2);
        float e = -1e30f;
        if (j < deg) {
            int src = csr_src[s + j];
            e = es[src * 4 + k] + edk;
            e = (e >= 0.f) ? e : 0.2f * e;
            tmp[(size_t)(s + j) * 4 + k] = e;
        }
        m = fmaxf(m, e);
    }
    m = fmaxf(m, __shfl_xor(m, 4));
    m = fmaxf(m, __shfl_xor(m, 8));
    m = fmaxf(m, __shfl_xor(m, 16));
    m = fmaxf(m, __shfl_xor(m, 32));
    float dsum = 0.f;
    for (int j0 = 0; j0 < deg; j0 += 16) {
        int j = j0 + (t >> 2);
        if (j < deg) {
            float ex = expf(tmp[(size_t)(s + j) * 4 + k] - m);
            tmp[(size_t)(s + j) * 4 + k] = ex;
            dsum += ex;
        }
    }
    dsum += __shfl_xor(dsum, 4);
    dsum += __shfl_xor(dsum, 8);
    dsum += __shfl_xor(dsum, 16);
    dsum += __shfl_xor(dsum, 32);
    float exs = expf(eself - m);
    dsum += exs;
    __shared__ float s_inv[4], s_aself[4];
    if (t < 4) {
        float inv = 1.f / dsum;
        s_inv[t] = inv;
        s_aself[t] = exs * inv;
    }
    __syncthreads();
    float inv0 = s_inv[0], inv1 = s_inv[1], inv2 = s_inv[2], inv3 = s_inv[3];
    float acc0, acc1, acc2 = 0.f;
    {
        const float* hr = hg + (size_t)i * HID4;
        float a0 = s_aself[0], a1 = s_aself[1], a2 = s_aself[2], a3 = s_aself[3];
        acc0 = a0 * hr[t] + a1 * hr[HID + t] + a2 * hr[2 * HID + t] + a3 * hr[3 * HID + t];
        acc1 = a0 * hr[64 + t] + a1 * hr[HID + 64 + t] + a2 * hr[2 * HID + 64 + t] + a3 * hr[3 * HID + 64 + t];
        if (t < 4)
            acc2 = a0 * hr[128 + t] + a1 * hr[HID + 128 + t] + a2 * hr[2 * HID + 128 + t] + a3 * hr[3 * HID + 128 + t];
    }
    const float4* tmp4 = (const float4*)tmp;
    for (int j = 0; j < deg; ++j) {
        int src = csr_src[s + j];
        float4 ax = tmp4[s + j];
        float a0 = ax.x * inv0, a1 = ax.y * inv1, a2 = ax.z * inv2, a3 = ax.w * inv3;
        const float* hr = hg + (size_t)src * HID4;
        acc0 += a0 * hr[t] + a1 * hr[HID + t] + a2 * hr[2 * HID + t] + a3 * hr[3 * HID + t];
        acc1 += a0 * hr[64 + t] + a1 * hr[HID + 64 + t] + a2 * hr[2 * HID + 64 + t] + a3 * hr[3 * HID + 64 + t];
        if (t < 4)
            acc2 += a0 * hr[128 + t] + a1 * hr[HID + 128 + t] + a2 * hr[2 * HID + 128 + t] + a3 * hr[3 * HID + 128 + t];
    }
    float* orow = out + (size_t)i * HID;
    float v0 = acc0 * 0.25f + bias[t];
    float v1 = acc1 * 0.25f + bias[64 + t];
    if (do_relu) { v0 = fmaxf(v0, 0.f); v1 = fmaxf(v1, 0.f); }
    orow[t] = v0;
    orow[64 + t] = v1;
    if (t < 4) {
        float v2 = acc2 * 0.25f + bias[128 + t];
        if (do_relu) v2 = fmaxf(v2, 0.f);
        orow[128 + t] = v2;
    }
}

// ---------------- gated fusion ----------------
__global__ void k_gate(const float* __restrict__ zpre, const float* __restrict__ xc,
                       const float* __restrict__ xp, const float* __restrict__ b1,
                       const float* __restrict__ b2, const float* __restrict__ pb,
                       float* __restrict__ out) {
    int idx = blockIdx.x * 256 + threadIdx.x;
    if (idx >= N_NODES * HID) return;
    int c = idx % HID;
    float zp = zpre[idx] + b1[c] + b2[c] + pb[c];
    float z = 1.f / (1.f + expf(-zp));
    out[idx] = z * xc[idx] + (1.f - z) * xp[idx];
}

// ---------------- pooling ----------------
__global__ void k_pool(const float* __restrict__ x3, const int* __restrict__ batch,
                       unsigned* __restrict__ genc) {
    int idx = blockIdx.x * 256 + threadIdx.x;
    if (idx >= N_NODES * HID) return;
    int n = idx / HID, c = idx - n * HID;
    unsigned u = __float_as_uint(x3[idx]);
    unsigned en = (u & 0x80000000u) ? ~u : (u | 0x80000000u);
    atomicMax(&genc[batch[n] * HID + c], en);
}

__global__ void k_decode(const unsigned* __restrict__ genc, float* __restrict__ g) {
    int idx = blockIdx.x * 256 + threadIdx.x;
    if (idx >= GRAPHS * HID) return;
    unsigned en = genc[idx];
    unsigned u = (en & 0x80000000u) ? (en & 0x7fffffffu) : ~en;
    g[idx] = __uint_as_float(u);
}

// ---------------- head layer 2 (fp32 out) ----------------
__global__ void k_head2(const float* __restrict__ gh, const float* __restrict__ W,
                        const float* __restrict__ b, float* __restrict__ out) {
    int idx = blockIdx.x * 64 + threadIdx.x;
    if (idx >= GRAPHS * OUT_DIM) return;
    int gi = idx / OUT_DIM, o = idx % OUT_DIM;
    float acc = b[o];
    const float* hr = gh + (size_t)gi * GFC;
    for (int j = 0; j < GFC; ++j) acc += hr[j] * W[j * OUT_DIM + o];
    out[idx] = acc;
}

// ---------------- launch ----------------
extern "C" void kernel_launch(void* const* d_in, const int* in_sizes, int n_in,
                              void* d_out, int out_size, void* d_ws, size_t ws_size,
                              hipStream_t stream) {
    const float* X       = (const float*)d_in[0];
    const int*   EI      = (const int*)d_in[1];
    const float* EW      = (const float*)d_in[2];
    const int*   BATCH   = (const int*)d_in[3];
    const float* W_gcn   = (const float*)d_in[4];
    const float* b_gcn   = (const float*)d_in[5];
    const float* W_gat1  = (const float*)d_in[6];
    const float* a_src1  = (const float*)d_in[7];
    const float* a_dst1  = (const float*)d_in[8];
    const float* b_gat1  = (const float*)d_in[9];
    const float* W_gat2  = (const float*)d_in[10];
    const float* a_src2  = (const float*)d_in[11];
    const float* a_dst2  = (const float*)d_in[12];
    const float* b_gat2  = (const float*)d_in[13];
    const float* W_fc1   = (const float*)d_in[14];
    const float* b_fc1   = (const float*)d_in[15];
    const float* W_fc2   = (const float*)d_in[16];
    const float* b_fc2   = (const float*)d_in[17];
    const float* pro_bias= (const float*)d_in[18];
    const float* W_g1    = (const float*)d_in[19];
    const float* b_g1    = (const float*)d_in[20];
    const float* W_g2    = (const float*)d_in[21];
    const float* b_g2    = (const float*)d_in[22];
    float* OUT = (float*)d_out;

    float* ws = (float*)d_ws;
    float*    dis     = ws + O_DIS;
    int*      counts  = (int*)(ws + O_CNT);
    int*      indptr  = (int*)(ws + O_IDP);
    int*      csr_src = (int*)(ws + O_CSR_S);
    float*    csr_w   = ws + O_CSR_W;
    float*    es      = ws + O_ES;
    float*    ed      = ws + O_ED;
    float*    tmp     = ws + O_TMP;
    float*    x1      = ws + O_X1;   // later reused as x3
    float*    x2      = ws + O_X2;
    float*    xc      = ws + O_XC;
    float*    hg      = ws + O_HG;   // h_gcn [N,132] / h_gat [N,528] / zpre alias
    float*    zpre    = hg;          // safe: zpre only live after hg is dead
    unsigned* genc    = (unsigned*)(ws + O_GE);
    float*    g       = ws + O_G;
    float*    gh      = ws + O_GH;
    float*    x3      = x1;

    const int EB = (N_EDGES + 255) / 256;
    const int NB = (N_NODES + 255) / 256;
    const int NHB = (N_NODES * HID + 255) / 256;

    // ---- CSR build ----
    hipMemsetAsync(counts, 0, N_NODES * sizeof(int), stream);
    k_count<<<EB, 256, 0, stream>>>(EI, counts);
    k_scan<<<1, 1024, 0, stream>>>(counts, indptr);
    hipMemsetAsync(counts, 0, N_NODES * sizeof(int), stream);
    k_scatter<<<EB, 256, 0, stream>>>(EI, EW, indptr, counts, csr_src, csr_w);
    k_deg<<<NB, 256, 0, stream>>>(indptr, csr_w, dis);

    // ---- GCN ----
    {
        dim3 grid((N_NODES + 63) / 64, (HID + 63) / 64);
        k_sgemm<<<grid, 256, 0, stream>>>(X, W_gcn, hg, N_NODES, HID, F_IN, 0, nullptr, 0);
    }
    k_gcn_agg<<<N_NODES, 64, 0, stream>>>(hg, indptr, csr_src, csr_w, dis, b_gcn, x1);

    // ---- GAT layer 1 (input x1, relu, gate -> x2) ----
    {
        dim3 grid((N_NODES + 63) / 64, (HID4 + 63) / 64);
        k_sgemm<<<grid, 256, 0, stream>>>(x1, W_gat1, hg, N_NODES, HID4, HID, 0, nullptr, 0);
    }
    k_esed<<<(N_NODES * HEADS + 255) / 256, 256, 0, stream>>>(hg, a_src1, a_dst1, es, ed);
    k_gat_node<<<N_NODES, 64, 0, stream>>>(hg, es, ed, indptr, csr_src, tmp, b_gat1, xc, 1);
    {
        dim3 grid((N_NODES + 63) / 64, (HID + 63) / 64);
        k_sgemm<<<grid, 256, 0, stream>>>(xc, W_fc1, zpre, N_NODES, HID, HID, 0, nullptr, 0);
        k_sgemm<<<grid, 256, 0, stream>>>(x1, W_fc2, zpre, N_NODES, HID, HID, 1, nullptr, 0);
    }
    k_gate<<<NHB, 256, 0, stream>>>(zpre, xc, x1, b_fc1, b_fc2, pro_bias, x2);

    // ---- GAT layer 2 (input x2, no relu, gate -> x3) ----
    {
        dim3 grid((N_NODES + 63) / 64, (HID4 + 63) / 64);
        k_sgemm<<<grid, 256, 0, stream>>>(x2, W_gat2, hg, N_NODES, HID4, HID, 0, nullptr, 0);
    }
    k_esed<<<(N_NODES * HEADS + 255) / 256, 256, 0, stream>>>(hg, a_src2, a_dst2, es, ed);
    k_gat_node<<<N_NODES, 64, 0, stream>>>(hg, es, ed, indptr, csr_src, tmp, b_gat2, xc, 0);
    {
        dim3 grid((N_NODES + 63) / 64, (HID + 63) / 64);
        k_sgemm<<<grid, 256, 0, stream>>>(xc, W_fc1, zpre, N_NODES, HID, HID, 0, nullptr, 0);
        k_sgemm<<<grid, 256, 0, stream>>>(x2, W_fc2, zpre, N_NODES, HID, HID, 1, nullptr, 0);
    }
    k_gate<<<NHB, 256, 0, stream>>>(zpre, xc, x2, b_fc1, b_fc2, pro_bias, x3);

    // ---- pool + head ----
    hipMemsetAsync(genc, 0, GRAPHS * HID * sizeof(unsigned), stream);
    k_pool<<<NHB, 256, 0, stream>>>(x3, BATCH, genc);
    k_decode<<<(GRAPHS * HID + 255) / 256, 256, 0, stream>>>(genc, g);
    {
        dim3 grid((GRAPHS + 63) / 64, (GFC + 63) / 64);
        k_sgemm<<<grid, 256, 0, stream>>>(g, W_g1, gh, GRAPHS, GFC, HID, 0, b_g1, 1);
    }
    k_head2<<<(GRAPHS * OUT_DIM + 63) / 64, 64, 0, stream>>>(gh, W_g2, b_g2, OUT);
}

// Round 3
// 798.064 us; speedup vs baseline: 1.2976x; 1.2976x over previous
//
#include <hip/hip_runtime.h>

// ---------------- problem constants ----------------
constexpr int N_NODES = 30000;
constexpr int N_EDGES = 300000;
constexpr int GRAPHS  = 64;
constexpr int F_IN    = 33;
constexpr int HID     = 132;
constexpr int HEADS   = 4;
constexpr int HID4    = HEADS * HID;   // 528
constexpr int OUT_DIM = 128;
constexpr int GFC     = 1024;
constexpr int MP      = 30016;         // N_NODES padded to x64

// ---------------- workspace layout (float units, 64-float aligned) ----------------
constexpr size_t rnd64(size_t x) { return (x + 63) & ~(size_t)63; }
constexpr size_t O_DIS   = 0;
constexpr size_t O_CNT   = O_DIS   + rnd64(N_NODES);
constexpr size_t O_IDP   = O_CNT   + rnd64(N_NODES);
constexpr size_t O_CSR_S = O_IDP   + rnd64(N_NODES + 1);
constexpr size_t O_CSR_W = O_CSR_S + rnd64(N_EDGES);
constexpr size_t O_ES    = O_CSR_W + rnd64(N_EDGES);
constexpr size_t O_ED    = O_ES    + rnd64(N_NODES * 4);
constexpr size_t O_TMP   = O_ED    + rnd64(N_NODES * 4);           // float, E*4
constexpr size_t O_X1    = O_TMP   + rnd64((size_t)N_EDGES * 4);
constexpr size_t O_X2    = O_X1    + rnd64((size_t)N_NODES * HID);
constexpr size_t O_XC    = O_X2    + rnd64((size_t)N_NODES * HID);
constexpr size_t O_HG    = O_XC    + rnd64((size_t)N_NODES * HID); // float, N*528
constexpr size_t O_GE    = O_HG    + rnd64((size_t)N_NODES * HID4);
constexpr size_t O_G     = O_GE    + rnd64(GRAPHS * HID);
constexpr size_t O_GH    = O_G     + rnd64(GRAPHS * HID);          // float, G*GFC
constexpr size_t O_AB    = O_GH    + rnd64(GRAPHS * GFC);          // ushort, MP*288
constexpr size_t O_BT    = O_AB    + rnd64((size_t)MP * 288 / 2);  // ushort, 1024*160
constexpr size_t O_BTG   = O_BT    + rnd64(1024 * 160 / 2);        // ushort, 192*288
// end ~ 34.4M floats ~138 MB

// ---------------- bf16 helpers ----------------
__device__ inline unsigned short f2bf(float f) {
    unsigned u = __float_as_uint(f);
    unsigned r = (u + 0x7fffu + ((u >> 16) & 1u)) >> 16;
    return (unsigned short)r;
}

typedef __attribute__((ext_vector_type(8))) short s8b;   // 8 bf16 (4 VGPRs)
typedef __attribute__((ext_vector_type(4))) float f32x4;

// ---------------- CSR build ----------------
__global__ void k_count(const int* __restrict__ ei, int* __restrict__ counts) {
    int e = blockIdx.x * 256 + threadIdx.x;
    if (e < N_EDGES) atomicAdd(&counts[ei[N_EDGES + e]], 1);
}

__global__ void k_scan(const int* __restrict__ counts, int* __restrict__ indptr) {
    __shared__ int buf[1024];
    __shared__ int carry_s;
    if (threadIdx.x == 0) carry_s = 0;
    __syncthreads();
    for (int base = 0; base < N_NODES; base += 1024) {
        int i = base + threadIdx.x;
        int v = (i < N_NODES) ? counts[i] : 0;
        buf[threadIdx.x] = v;
        __syncthreads();
        for (int off = 1; off < 1024; off <<= 1) {
            int t = (threadIdx.x >= off) ? buf[threadIdx.x - off] : 0;
            __syncthreads();
            buf[threadIdx.x] += t;
            __syncthreads();
        }
        int incl = buf[threadIdx.x];
        int carry = carry_s;
        if (i < N_NODES) indptr[i] = carry + incl - v;
        __syncthreads();
        if (threadIdx.x == 1023) carry_s = carry + buf[1023];
        __syncthreads();
    }
    if (threadIdx.x == 0) indptr[N_NODES] = carry_s;
}

__global__ void k_scatter(const int* __restrict__ ei, const float* __restrict__ ew,
                          const int* __restrict__ indptr, int* __restrict__ cursor,
                          int* __restrict__ csr_src, float* __restrict__ csr_w) {
    int e = blockIdx.x * 256 + threadIdx.x;
    if (e >= N_EDGES) return;
    int src = ei[e];
    int dst = ei[N_EDGES + e];
    int pos = indptr[dst] + atomicAdd(&cursor[dst], 1);
    csr_src[pos] = src;
    csr_w[pos] = ew[e];
}

__global__ void k_deg(const int* __restrict__ indptr, const float* __restrict__ csr_w,
                      float* __restrict__ dis) {
    int i = blockIdx.x * 256 + threadIdx.x;
    if (i >= N_NODES) return;
    float d = 1.0f;
    int s = indptr[i], e = indptr[i + 1];
    for (int j = s; j < e; ++j) d += csr_w[j];
    dis[i] = (d > 0.f) ? rsqrtf(fmaxf(d, 1e-12f)) : 0.f;
}

// ---------------- fp32 -> bf16 conversion kernels ----------------
__global__ void k_cvtA(const float* __restrict__ src, unsigned short* __restrict__ dst,
                       int M, int K, int Kp) {
    int idx = blockIdx.x * 256 + threadIdx.x;
    if (idx >= M * Kp) return;
    int r = idx / Kp, k = idx - r * Kp;
    dst[idx] = (k < K) ? f2bf(src[(size_t)r * K + k]) : (unsigned short)0;
}

// concat [s1 | s2], each M x HID, into [M, Kp]
__global__ void k_cvtA2(const float* __restrict__ s1, const float* __restrict__ s2,
                        unsigned short* __restrict__ dst, int M, int Kp) {
    int idx = blockIdx.x * 256 + threadIdx.x;
    if (idx >= M * Kp) return;
    int r = idx / Kp, k = idx - r * Kp;
    unsigned short v = 0;
    if (k < HID) v = f2bf(s1[(size_t)r * HID + k]);
    else if (k < 2 * HID) v = f2bf(s2[(size_t)r * HID + (k - HID)]);
    dst[idx] = v;
}

// B [K,N] fp32 -> Bt [Np,Kp] bf16 (transposed, zero-padded)
__global__ void k_cvtBt(const float* __restrict__ B, unsigned short* __restrict__ Bt,
                        int K, int N, int Np, int Kp) {
    int idx = blockIdx.x * 256 + threadIdx.x;
    if (idx >= Np * Kp) return;
    int n = idx / Kp, k = idx - n * Kp;
    Bt[idx] = (k < K && n < N) ? f2bf(B[(size_t)k * N + n]) : (unsigned short)0;
}

// [W_fc1; W_fc2] each HIDxHID -> Bt [192, 288]
__global__ void k_cvtBt2(const float* __restrict__ B1, const float* __restrict__ B2,
                         unsigned short* __restrict__ Bt) {
    constexpr int Np = 192, Kp = 288;
    int idx = blockIdx.x * 256 + threadIdx.x;
    if (idx >= Np * Kp) return;
    int n = idx / Kp, k = idx - n * Kp;
    unsigned short v = 0;
    if (n < HID) {
        if (k < HID) v = f2bf(B1[(size_t)k * HID + n]);
        else if (k < 2 * HID) v = f2bf(B2[(size_t)(k - HID) * HID + n]);
    }
    Bt[idx] = v;
}

// ---------------- MFMA bf16 GEMM: C[M,N] = A[*,Kp] @ Bt[Np,Kp]^T ----------------
// gate==0: C = acc (+bias)(+relu).  gate==1: z=sigmoid(acc+bias+b2+pb); C=z*xc+(1-z)*xp.
__global__ __launch_bounds__(256) void k_mfma_gemm(
    const unsigned short* __restrict__ A, const unsigned short* __restrict__ Bt,
    float* __restrict__ C, int M, int N, int Kp,
    const float* __restrict__ bias, int relu, int gate,
    const float* __restrict__ b2, const float* __restrict__ pb,
    const float* __restrict__ xc, const float* __restrict__ xp) {
    const int bm = blockIdx.x * 64;
    const int bn = blockIdx.y * 64;
    const int w = threadIdx.x >> 6;
    const int lane = threadIdx.x & 63;
    const int m16 = lane & 15;
    const int quad = lane >> 4;
    const unsigned short* Ab = A + (size_t)(bm + m16) * Kp + quad * 8;
    const unsigned short* Bb = Bt + (size_t)(bn + w * 16 + m16) * Kp + quad * 8;
    f32x4 acc[4];
    #pragma unroll
    for (int r = 0; r < 4; ++r) acc[r] = (f32x4){0.f, 0.f, 0.f, 0.f};
    for (int k0 = 0; k0 < Kp; k0 += 32) {
        s8b b = *(const s8b*)(Bb + k0);
        s8b a0 = *(const s8b*)(Ab + k0);
        s8b a1 = *(const s8b*)(Ab + (size_t)16 * Kp + k0);
        s8b a2 = *(const s8b*)(Ab + (size_t)32 * Kp + k0);
        s8b a3 = *(const s8b*)(Ab + (size_t)48 * Kp + k0);
        acc[0] = __builtin_amdgcn_mfma_f32_16x16x32_bf16(a0, b, acc[0], 0, 0, 0);
        acc[1] = __builtin_amdgcn_mfma_f32_16x16x32_bf16(a1, b, acc[1], 0, 0, 0);
        acc[2] = __builtin_amdgcn_mfma_f32_16x16x32_bf16(a2, b, acc[2], 0, 0, 0);
        acc[3] = __builtin_amdgcn_mfma_f32_16x16x32_bf16(a3, b, acc[3], 0, 0, 0);
    }
    const int col = bn + w * 16 + m16;
    if (col >= N) return;
    float bsum = 0.f;
    if (gate) bsum = bias[col] + b2[col] + pb[col];
    else if (bias) bsum = bias[col];
    #pragma unroll
    for (int r = 0; r < 4; ++r) {
        #pragma unroll
        for (int j = 0; j < 4; ++j) {
            int row = bm + r * 16 + quad * 4 + j;
            if (row >= M) continue;
            size_t idx = (size_t)row * N + col;
            float v = acc[r][j] + bsum;
            if (gate) {
                float z = 1.f / (1.f + expf(-v));
                C[idx] = z * xc[idx] + (1.f - z) * xp[idx];
            } else {
                if (relu) v = fmaxf(v, 0.f);
                C[idx] = v;
            }
        }
    }
}

// ---------------- GCN aggregate ----------------
__global__ __launch_bounds__(64) void k_gcn_agg(
    const float* __restrict__ h, const int* __restrict__ indptr,
    const int* __restrict__ csr_src, const float* __restrict__ csr_w,
    const float* __restrict__ dis, const float* __restrict__ bias,
    float* __restrict__ out) {
    const int i = blockIdx.x;
    const int t = threadIdx.x;
    const float di = dis[i];
    const int s = indptr[i], e = indptr[i + 1];
    const float* hr = h + (size_t)i * HID;
    float nself = di * di;
    float acc0 = nself * hr[t];
    float acc1 = nself * hr[64 + t];
    float acc2 = (t < 4) ? nself * hr[128 + t] : 0.f;
    for (int j = s; j < e; ++j) {
        int src = csr_src[j];
        float nb = dis[src] * csr_w[j] * di;
        const float* hs = h + (size_t)src * HID;
        acc0 += nb * hs[t];
        acc1 += nb * hs[64 + t];
        if (t < 4) acc2 += nb * hs[128 + t];
    }
    float* orow = out + (size_t)i * HID;
    orow[t]      = fmaxf(acc0 + bias[t], 0.f);
    orow[64 + t] = fmaxf(acc1 + bias[64 + t], 0.f);
    if (t < 4) orow[128 + t] = fmaxf(acc2 + bias[128 + t], 0.f);
}

// ---------------- GAT attention coefficients ----------------
__global__ void k_esed(const float* __restrict__ hg, const float* __restrict__ as,
                       const float* __restrict__ ad, float* __restrict__ es,
                       float* __restrict__ ed) {
    int idx = blockIdx.x * 256 + threadIdx.x;
    if (idx >= N_NODES * HEADS) return;
    int n = idx >> 2, k = idx & 3;
    const float* hr = hg + (size_t)n * HID4 + k * HID;
    float s = 0.f, d = 0.f;
    for (int c = 0; c < HID; ++c) {
        float hv = hr[c];
        s += hv * as[k * HID + c];
        d += hv * ad[k * HID + c];
    }
    es[idx] = s;
    ed[idx] = d;
}

// ---------------- GAT per-node softmax + aggregate ----------------
__global__ __launch_bounds__(64) void k_gat_node(
    const float* __restrict__ hg, const float* __restrict__ es,
    const float* __restrict__ ed, const int* __restrict__ indptr,
    const int* __restrict__ csr_src, float* __restrict__ tmp,
    const float* __restrict__ bias, float* __restrict__ out, int do_relu) {
    const int i = blockIdx.x;
    const int t = threadIdx.x;
    const int k = t & 3;
    const int s = indptr[i];
    const int deg = indptr[i + 1] - s;
    const float edk = ed[i * 4 + k];
    float eself = es[i * 4 + k] + edk;
    eself = (eself >= 0.f) ? eself : 0.2f * eself;
    float m = eself;
    for (int j0 = 0; j0 < deg; j0 += 16) {
        int j = j0 + (t >> 2);
        float e = -1e30f;
        if (j < deg) {
            int src = csr_src[s + j];
            e = es[src * 4 + k] + edk;
            e = (e >= 0.f) ? e : 0.2f * e;
            tmp[(size_t)(s + j) * 4 + k] = e;
        }
        m = fmaxf(m, e);
    }
    m = fmaxf(m, __shfl_xor(m, 4));
    m = fmaxf(m, __shfl_xor(m, 8));
    m = fmaxf(m, __shfl_xor(m, 16));
    m = fmaxf(m, __shfl_xor(m, 32));
    float dsum = 0.f;
    for (int j0 = 0; j0 < deg; j0 += 16) {
        int j = j0 + (t >> 2);
        if (j < deg) {
            float ex = expf(tmp[(size_t)(s + j) * 4 + k] - m);
            tmp[(size_t)(s + j) * 4 + k] = ex;
            dsum += ex;
        }
    }
    dsum += __shfl_xor(dsum, 4);
    dsum += __shfl_xor(dsum, 8);
    dsum += __shfl_xor(dsum, 16);
    dsum += __shfl_xor(dsum, 32);
    float exs = expf(eself - m);
    dsum += exs;
    __shared__ float s_inv[4], s_aself[4];
    if (t < 4) {
        float inv = 1.f / dsum;
        s_inv[t] = inv;
        s_aself[t] = exs * inv;
    }
    __syncthreads();
    float inv0 = s_inv[0], inv1 = s_inv[1], inv2 = s_inv[2], inv3 = s_inv[3];
    float acc0, acc1, acc2 = 0.f;
    {
        const float* hr = hg + (size_t)i * HID4;
        float a0 = s_aself[0], a1 = s_aself[1], a2 = s_aself[2], a3 = s_aself[3];
        acc0 = a0 * hr[t] + a1 * hr[HID + t] + a2 * hr[2 * HID + t] + a3 * hr[3 * HID + t];
        acc1 = a0 * hr[64 + t] + a1 * hr[HID + 64 + t] + a2 * hr[2 * HID + 64 + t] + a3 * hr[3 * HID + 64 + t];
        if (t < 4)
            acc2 = a0 * hr[128 + t] + a1 * hr[HID + 128 + t] + a2 * hr[2 * HID + 128 + t] + a3 * hr[3 * HID + 128 + t];
    }
    const float4* tmp4 = (const float4*)tmp;
    for (int j = 0; j < deg; ++j) {
        int src = csr_src[s + j];
        float4 ax = tmp4[s + j];
        float a0 = ax.x * inv0, a1 = ax.y * inv1, a2 = ax.z * inv2, a3 = ax.w * inv3;
        const float* hr = hg + (size_t)src * HID4;
        acc0 += a0 * hr[t] + a1 * hr[HID + t] + a2 * hr[2 * HID + t] + a3 * hr[3 * HID + t];
        acc1 += a0 * hr[64 + t] + a1 * hr[HID + 64 + t] + a2 * hr[2 * HID + 64 + t] + a3 * hr[3 * HID + 64 + t];
        if (t < 4)
            acc2 += a0 * hr[128 + t] + a1 * hr[HID + 128 + t] + a2 * hr[2 * HID + 128 + t] + a3 * hr[3 * HID + 128 + t];
    }
    float* orow = out + (size_t)i * HID;
    float v0 = acc0 * 0.25f + bias[t];
    float v1 = acc1 * 0.25f + bias[64 + t];
    if (do_relu) { v0 = fmaxf(v0, 0.f); v1 = fmaxf(v1, 0.f); }
    orow[t] = v0;
    orow[64 + t] = v1;
    if (t < 4) {
        float v2 = acc2 * 0.25f + bias[128 + t];
        if (do_relu) v2 = fmaxf(v2, 0.f);
        orow[128 + t] = v2;
    }
}

// ---------------- pooling ----------------
__global__ void k_pool(const float* __restrict__ x3, const int* __restrict__ batch,
                       unsigned* __restrict__ genc) {
    int idx = blockIdx.x * 256 + threadIdx.x;
    if (idx >= N_NODES * HID) return;
    int n = idx / HID, c = idx - n * HID;
    unsigned u = __float_as_uint(x3[idx]);
    unsigned en = (u & 0x80000000u) ? ~u : (u | 0x80000000u);
    atomicMax(&genc[batch[n] * HID + c], en);
}

__global__ void k_decode(const unsigned* __restrict__ genc, float* __restrict__ g) {
    int idx = blockIdx.x * 256 + threadIdx.x;
    if (idx >= GRAPHS * HID) return;
    unsigned en = genc[idx];
    unsigned u = (en & 0x80000000u) ? (en & 0x7fffffffu) : ~en;
    g[idx] = __uint_as_float(u);
}

// ---------------- head layer 2 (fp32 out) ----------------
__global__ void k_head2(const float* __restrict__ gh, const float* __restrict__ W,
                        const float* __restrict__ b, float* __restrict__ out) {
    int idx = blockIdx.x * 64 + threadIdx.x;
    if (idx >= GRAPHS * OUT_DIM) return;
    int gi = idx / OUT_DIM, o = idx % OUT_DIM;
    float acc = b[o];
    const float* hr = gh + (size_t)gi * GFC;
    for (int j = 0; j < GFC; ++j) acc += hr[j] * W[j * OUT_DIM + o];
    out[idx] = acc;
}

// ---------------- launch ----------------
extern "C" void kernel_launch(void* const* d_in, const int* in_sizes, int n_in,
                              void* d_out, int out_size, void* d_ws, size_t ws_size,
                              hipStream_t stream) {
    const float* X       = (const float*)d_in[0];
    const int*   EI      = (const int*)d_in[1];
    const float* EW      = (const float*)d_in[2];
    const int*   BATCH   = (const int*)d_in[3];
    const float* W_gcn   = (const float*)d_in[4];
    const float* b_gcn   = (const float*)d_in[5];
    const float* W_gat1  = (const float*)d_in[6];
    const float* a_src1  = (const float*)d_in[7];
    const float* a_dst1  = (const float*)d_in[8];
    const float* b_gat1  = (const float*)d_in[9];
    const float* W_gat2  = (const float*)d_in[10];
    const float* a_src2  = (const float*)d_in[11];
    const float* a_dst2  = (const float*)d_in[12];
    const float* b_gat2  = (const float*)d_in[13];
    const float* W_fc1   = (const float*)d_in[14];
    const float* b_fc1   = (const float*)d_in[15];
    const float* W_fc2   = (const float*)d_in[16];
    const float* b_fc2   = (const float*)d_in[17];
    const float* pro_bias= (const float*)d_in[18];
    const float* W_g1    = (const float*)d_in[19];
    const float* b_g1    = (const float*)d_in[20];
    const float* W_g2    = (const float*)d_in[21];
    const float* b_g2    = (const float*)d_in[22];
    float* OUT = (float*)d_out;

    float* ws = (float*)d_ws;
    float*          dis     = ws + O_DIS;
    int*            counts  = (int*)(ws + O_CNT);
    int*            indptr  = (int*)(ws + O_IDP);
    int*            csr_src = (int*)(ws + O_CSR_S);
    float*          csr_w   = ws + O_CSR_W;
    float*          es      = ws + O_ES;
    float*          ed      = ws + O_ED;
    float*          tmp     = ws + O_TMP;
    float*          x1      = ws + O_X1;
    float*          x2      = ws + O_X2;
    float*          xc      = ws + O_XC;
    float*          hg      = ws + O_HG;
    unsigned*       genc    = (unsigned*)(ws + O_GE);
    float*          g       = ws + O_G;
    float*          gh      = ws + O_GH;
    unsigned short* AB      = (unsigned short*)(ws + O_AB);
    unsigned short* BT      = (unsigned short*)(ws + O_BT);
    unsigned short* BTG     = (unsigned short*)(ws + O_BTG);
    float*          x3      = x1;

    const int EB = (N_EDGES + 255) / 256;
    const int NB = (N_NODES + 255) / 256;
    const int NHB = (N_NODES * HID + 255) / 256;

    // ---- CSR build ----
    hipMemsetAsync(counts, 0, N_NODES * sizeof(int), stream);
    k_count<<<EB, 256, 0, stream>>>(EI, counts);
    k_scan<<<1, 1024, 0, stream>>>(counts, indptr);
    hipMemsetAsync(counts, 0, N_NODES * sizeof(int), stream);
    k_scatter<<<EB, 256, 0, stream>>>(EI, EW, indptr, counts, csr_src, csr_w);
    k_deg<<<NB, 256, 0, stream>>>(indptr, csr_w, dis);

    // ---- shared gate weights (used by both layers) ----
    k_cvtBt2<<<(192 * 288 + 255) / 256, 256, 0, stream>>>(W_fc1, W_fc2, BTG);

    // ---- GCN: h = X @ W_gcn (MFMA), then aggregate ----
    k_cvtA<<<(N_NODES * 64 + 255) / 256, 256, 0, stream>>>(X, AB, N_NODES, F_IN, 64);
    k_cvtBt<<<(192 * 64 + 255) / 256, 256, 0, stream>>>(W_gcn, BT, F_IN, HID, 192, 64);
    {
        dim3 grid(MP / 64, 3);
        k_mfma_gemm<<<grid, 256, 0, stream>>>(AB, BT, hg, N_NODES, HID, 64,
                                              nullptr, 0, 0, nullptr, nullptr, nullptr, nullptr);
    }
    k_gcn_agg<<<N_NODES, 64, 0, stream>>>(hg, indptr, csr_src, csr_w, dis, b_gcn, x1);

    // ---- GAT layer 1 ----
    k_cvtA<<<(N_NODES * 160 + 255) / 256, 256, 0, stream>>>(x1, AB, N_NODES, HID, 160);
    k_cvtBt<<<(576 * 160 + 255) / 256, 256, 0, stream>>>(W_gat1, BT, HID, HID4, 576, 160);
    {
        dim3 grid(MP / 64, 9);
        k_mfma_gemm<<<grid, 256, 0, stream>>>(AB, BT, hg, N_NODES, HID4, 160,
                                              nullptr, 0, 0, nullptr, nullptr, nullptr, nullptr);
    }
    k_esed<<<(N_NODES * HEADS + 255) / 256, 256, 0, stream>>>(hg, a_src1, a_dst1, es, ed);
    k_gat_node<<<N_NODES, 64, 0, stream>>>(hg, es, ed, indptr, csr_src, tmp, b_gat1, xc, 1);
    // gate 1: x2 = z*xc + (1-z)*x1, z=sigmoid([xc|x1]@[Wfc1;Wfc2] + biases)
    k_cvtA2<<<(N_NODES * 288 + 255) / 256, 256, 0, stream>>>(xc, x1, AB, N_NODES, 288);
    {
        dim3 grid(MP / 64, 3);
        k_mfma_gemm<<<grid, 256, 0, stream>>>(AB, BTG, x2, N_NODES, HID, 288,
                                              b_fc1, 0, 1, b_fc2, pro_bias, xc, x1);
    }

    // ---- GAT layer 2 ----
    k_cvtA<<<(N_NODES * 160 + 255) / 256, 256, 0, stream>>>(x2, AB, N_NODES, HID, 160);
    k_cvtBt<<<(576 * 160 + 255) / 256, 256, 0, stream>>>(W_gat2, BT, HID, HID4, 576, 160);
    {
        dim3 grid(MP / 64, 9);
        k_mfma_gemm<<<grid, 256, 0, stream>>>(AB, BT, hg, N_NODES, HID4, 160,
                                              nullptr, 0, 0, nullptr, nullptr, nullptr, nullptr);
    }
    k_esed<<<(N_NODES * HEADS + 255) / 256, 256, 0, stream>>>(hg, a_src2, a_dst2, es, ed);
    k_gat_node<<<N_NODES, 64, 0, stream>>>(hg, es, ed, indptr, csr_src, tmp, b_gat2, xc, 0);
    // gate 2: x3 = z*xc + (1-z)*x2
    k_cvtA2<<<(N_NODES * 288 + 255) / 256, 256, 0, stream>>>(xc, x2, AB, N_NODES, 288);
    {
        dim3 grid(MP / 64, 3);
        k_mfma_gemm<<<grid, 256, 0, stream>>>(AB, BTG, x3, N_NODES, HID, 288,
                                              b_fc1, 0, 1, b_fc2, pro_bias, xc, x2);
    }

    // ---- pool + head ----
    hipMemsetAsync(genc, 0, GRAPHS * HID * sizeof(unsigned), stream);
    k_pool<<<NHB, 256, 0, stream>>>(x3, BATCH, genc);
    k_decode<<<(GRAPHS * HID + 255) / 256, 256, 0, stream>>>(genc, g);
    k_cvtA<<<(GRAPHS * 160 + 255) / 256, 256, 0, stream>>>(g, AB, GRAPHS, HID, 160);
    k_cvtBt<<<(1024 * 160 + 255) / 256, 256, 0, stream>>>(W_g1, BT, HID, GFC, 1024, 160);
    {
        dim3 grid(1, 16);
        k_mfma_gemm<<<grid, 256, 0, stream>>>(AB, BT, gh, GRAPHS, GFC, 160,
                                              b_g1, 1, 0, nullptr, nullptr, nullptr, nullptr);
    }
    k_head2<<<(GRAPHS * OUT_DIM + 63) / 64, 64, 0, stream>>>(gh, W_g2, b_g2, OUT);
}

// Round 4
// 659.817 us; speedup vs baseline: 1.5695x; 1.2095x over previous
//
#include <hip/hip_runtime.h>

// ---------------- problem constants ----------------
constexpr int N_NODES = 30000;
constexpr int N_EDGES = 300000;
constexpr int GRAPHS  = 64;
constexpr int F_IN    = 33;
constexpr int HID     = 132;
constexpr int HEADS   = 4;
constexpr int HID4    = HEADS * HID;   // 528
constexpr int OUT_DIM = 128;
constexpr int GFC     = 1024;
constexpr int MP      = 30016;         // N_NODES padded to x64

typedef unsigned int u32;
typedef unsigned short u16;

// ---------------- workspace layout (float units, 64-float aligned) ----------------
constexpr size_t rnd64(size_t x) { return (x + 63) & ~(size_t)63; }
constexpr size_t O_DIS   = 0;
constexpr size_t O_CNT   = O_DIS   + rnd64(N_NODES);
constexpr size_t O_IDP   = O_CNT   + rnd64(N_NODES);
constexpr size_t O_CSR_S = O_IDP   + rnd64(N_NODES + 1);
constexpr size_t O_CSR_W = O_CSR_S + rnd64(N_EDGES);
constexpr size_t O_ES    = O_CSR_W + rnd64(N_EDGES);
constexpr size_t O_ED    = O_ES    + rnd64(N_NODES * 4);
constexpr size_t O_TMP   = O_ED    + rnd64(N_NODES * 4);             // float, E*4
constexpr size_t O_X1    = O_TMP   + rnd64((size_t)N_EDGES * 4);
constexpr size_t O_X2    = O_X1    + rnd64((size_t)N_NODES * HID);
constexpr size_t O_XC    = O_X2    + rnd64((size_t)N_NODES * HID);
constexpr size_t O_GE    = O_XC    + rnd64((size_t)N_NODES * HID);
constexpr size_t O_G     = O_GE    + rnd64(GRAPHS * HID);
constexpr size_t O_GH    = O_G     + rnd64(GRAPHS * HID);
constexpr size_t O_HB    = O_GH    + rnd64(GRAPHS * GFC);            // u16, N*132
constexpr size_t O_HGB   = O_HB    + rnd64((size_t)N_NODES * HID / 2);   // u16, N*528
constexpr size_t O_ABF   = O_HGB   + rnd64((size_t)N_NODES * HID4 / 2);  // u16, MP*160
constexpr size_t O_ABG   = O_ABF   + rnd64((size_t)MP * 160 / 2);        // u16, MP*288
constexpr size_t O_BT    = O_ABG   + rnd64((size_t)MP * 288 / 2);        // u16, 1024*160
constexpr size_t O_BTG   = O_BT    + rnd64(1024 * 160 / 2);              // u16, 192*288
// end ~ 30.8M floats ~123 MB

// ---------------- bf16 helpers ----------------
__device__ inline u16 f2bf(float f) {
    u32 u = __float_as_uint(f);
    return (u16)((u + 0x7fffu + ((u >> 16) & 1u)) >> 16);
}
__device__ inline float bflo(u32 w) { return __uint_as_float(w << 16); }
__device__ inline float bfhi(u32 w) { return __uint_as_float(w & 0xffff0000u); }

typedef __attribute__((ext_vector_type(8))) short s8b;
typedef __attribute__((ext_vector_type(4))) float f32x4;

// ---------------- CSR build ----------------
__global__ void k_count(const int* __restrict__ ei, int* __restrict__ counts) {
    int e = blockIdx.x * 256 + threadIdx.x;
    if (e < N_EDGES) atomicAdd(&counts[ei[N_EDGES + e]], 1);
}

__global__ void k_scan(const int* __restrict__ counts, int* __restrict__ indptr) {
    __shared__ int buf[1024];
    __shared__ int carry_s;
    if (threadIdx.x == 0) carry_s = 0;
    __syncthreads();
    for (int base = 0; base < N_NODES; base += 1024) {
        int i = base + threadIdx.x;
        int v = (i < N_NODES) ? counts[i] : 0;
        buf[threadIdx.x] = v;
        __syncthreads();
        for (int off = 1; off < 1024; off <<= 1) {
            int t = (threadIdx.x >= off) ? buf[threadIdx.x - off] : 0;
            __syncthreads();
            buf[threadIdx.x] += t;
            __syncthreads();
        }
        int incl = buf[threadIdx.x];
        int carry = carry_s;
        if (i < N_NODES) indptr[i] = carry + incl - v;
        __syncthreads();
        if (threadIdx.x == 1023) carry_s = carry + buf[1023];
        __syncthreads();
    }
    if (threadIdx.x == 0) indptr[N_NODES] = carry_s;
}

__global__ void k_scatter(const int* __restrict__ ei, const float* __restrict__ ew,
                          const int* __restrict__ indptr, int* __restrict__ cursor,
                          int* __restrict__ csr_src, float* __restrict__ csr_w) {
    int e = blockIdx.x * 256 + threadIdx.x;
    if (e >= N_EDGES) return;
    int src = ei[e];
    int dst = ei[N_EDGES + e];
    int pos = indptr[dst] + atomicAdd(&cursor[dst], 1);
    csr_src[pos] = src;
    csr_w[pos] = ew[e];
}

__global__ void k_deg(const int* __restrict__ indptr, const float* __restrict__ csr_w,
                      float* __restrict__ dis) {
    int i = blockIdx.x * 256 + threadIdx.x;
    if (i >= N_NODES) return;
    float d = 1.0f;
    int s = indptr[i], e = indptr[i + 1];
    for (int j = s; j < e; ++j) d += csr_w[j];
    dis[i] = (d > 0.f) ? rsqrtf(fmaxf(d, 1e-12f)) : 0.f;
}

// ---------------- fp32 -> bf16 conversion kernels ----------------
__global__ void k_cvtA(const float* __restrict__ src, u16* __restrict__ dst,
                       int M, int K, int Kp) {
    int idx = blockIdx.x * 256 + threadIdx.x;
    if (idx >= M * Kp) return;
    int r = idx / Kp, k = idx - r * Kp;
    dst[idx] = (k < K) ? f2bf(src[(size_t)r * K + k]) : (u16)0;
}

__global__ void k_cvtBt(const float* __restrict__ B, u16* __restrict__ Bt,
                        int K, int N, int Np, int Kp) {
    int idx = blockIdx.x * 256 + threadIdx.x;
    if (idx >= Np * Kp) return;
    int n = idx / Kp, k = idx - n * Kp;
    Bt[idx] = (k < K && n < N) ? f2bf(B[(size_t)k * N + n]) : (u16)0;
}

__global__ void k_cvtBt2(const float* __restrict__ B1, const float* __restrict__ B2,
                         u16* __restrict__ Bt) {
    constexpr int Np = 192, Kp = 288;
    int idx = blockIdx.x * 256 + threadIdx.x;
    if (idx >= Np * Kp) return;
    int n = idx / Kp, k = idx - n * Kp;
    u16 v = 0;
    if (n < HID) {
        if (k < HID) v = f2bf(B1[(size_t)k * HID + n]);
        else if (k < 2 * HID) v = f2bf(B2[(size_t)(k - HID) * HID + n]);
    }
    Bt[idx] = v;
}

// x2 fp32 -> bf16 pairs into ABG[row*288 + 132 .. 263]
__global__ void k_cvtHalf(const float* __restrict__ x, u16* __restrict__ abg) {
    int idx = blockIdx.x * 256 + threadIdx.x;
    if (idx >= N_NODES * 66) return;
    int r = idx / 66, p = idx - r * 66;
    float2 v = ((const float2*)(x + (size_t)r * HID))[p];
    u32 pk = (u32)f2bf(v.x) | ((u32)f2bf(v.y) << 16);
    ((u32*)(abg + (size_t)r * 288))[66 + p] = pk;
}

// ---------------- MFMA bf16 GEMM: C/Cb[M,N] = A[*,Kp] @ Bt[Np,Kp]^T ----------------
__global__ __launch_bounds__(256) void k_mfma_gemm(
    const u16* __restrict__ A, const u16* __restrict__ Bt,
    float* __restrict__ C, u16* __restrict__ Cb, int ldcb, int padN,
    int M, int N, int Kp,
    const float* __restrict__ bias, int relu, int gate,
    const float* __restrict__ b2, const float* __restrict__ pb,
    const float* __restrict__ xc, const float* __restrict__ xp) {
    const int bm = blockIdx.x * 64;
    const int bn = blockIdx.y * 64;
    const int w = threadIdx.x >> 6;
    const int lane = threadIdx.x & 63;
    const int m16 = lane & 15;
    const int quad = lane >> 4;
    const u16* Ab = A + (size_t)(bm + m16) * Kp + quad * 8;
    const u16* Bb = Bt + (size_t)(bn + w * 16 + m16) * Kp + quad * 8;
    f32x4 acc[4];
    #pragma unroll
    for (int r = 0; r < 4; ++r) acc[r] = (f32x4){0.f, 0.f, 0.f, 0.f};
    for (int k0 = 0; k0 < Kp; k0 += 32) {
        s8b b = *(const s8b*)(Bb + k0);
        s8b a0 = *(const s8b*)(Ab + k0);
        s8b a1 = *(const s8b*)(Ab + (size_t)16 * Kp + k0);
        s8b a2 = *(const s8b*)(Ab + (size_t)32 * Kp + k0);
        s8b a3 = *(const s8b*)(Ab + (size_t)48 * Kp + k0);
        acc[0] = __builtin_amdgcn_mfma_f32_16x16x32_bf16(a0, b, acc[0], 0, 0, 0);
        acc[1] = __builtin_amdgcn_mfma_f32_16x16x32_bf16(a1, b, acc[1], 0, 0, 0);
        acc[2] = __builtin_amdgcn_mfma_f32_16x16x32_bf16(a2, b, acc[2], 0, 0, 0);
        acc[3] = __builtin_amdgcn_mfma_f32_16x16x32_bf16(a3, b, acc[3], 0, 0, 0);
    }
    const int col = bn + w * 16 + m16;
    const bool colok = col < N;
    float bsum = 0.f;
    if (colok) {
        if (gate) bsum = bias[col] + b2[col] + pb[col];
        else if (bias) bsum = bias[col];
    }
    #pragma unroll
    for (int r = 0; r < 4; ++r) {
        #pragma unroll
        for (int j = 0; j < 4; ++j) {
            int row = bm + r * 16 + quad * 4 + j;
            if (row >= M) continue;
            if (colok) {
                float v = acc[r][j] + bsum;
                float res;
                if (gate) {
                    float z = 1.f / (1.f + expf(-v));
                    size_t ix = (size_t)row * N + col;
                    res = z * xc[ix] + (1.f - z) * xp[ix];
                } else {
                    if (relu) v = fmaxf(v, 0.f);
                    res = v;
                }
                if (C)  C[(size_t)row * N + col] = res;
                if (Cb) Cb[(size_t)row * ldcb + col] = f2bf(res);
            } else if (Cb && col < padN) {
                Cb[(size_t)row * ldcb + col] = 0;
            }
        }
    }
}

// ---------------- GCN aggregate (bf16 gather, dual-write) ----------------
__global__ __launch_bounds__(64) void k_gcn_agg(
    const u16* __restrict__ hb, const int* __restrict__ indptr,
    const int* __restrict__ csr_src, const float* __restrict__ csr_w,
    const float* __restrict__ dis, const float* __restrict__ bias,
    float* __restrict__ x1, u16* __restrict__ abf, u16* __restrict__ abg) {
    const int i = blockIdx.x;
    const int t = threadIdx.x;
    const float di = dis[i];
    const int s = indptr[i], e = indptr[i + 1];
    const float nself = di * di;
    const u32* ru = (const u32*)(hb + (size_t)i * HID);
    u32 w = ru[t];
    float aLo = nself * bflo(w), aHi = nself * bfhi(w);
    float bLo = 0.f, bHi = 0.f;
    if (t < 2) { u32 w2 = ru[64 + t]; bLo = nself * bflo(w2); bHi = nself * bfhi(w2); }
    for (int j = s; j < e; ++j) {
        int src = csr_src[j];
        float nb = dis[src] * csr_w[j] * di;
        const u32* su = (const u32*)(hb + (size_t)src * HID);
        u32 ws = su[t];
        aLo += nb * bflo(ws);
        aHi += nb * bfhi(ws);
        if (t < 2) { u32 w2 = su[64 + t]; bLo += nb * bflo(w2); bHi += nb * bfhi(w2); }
    }
    float v0 = fmaxf(aLo + bias[2 * t], 0.f);
    float v1 = fmaxf(aHi + bias[2 * t + 1], 0.f);
    ((float2*)(x1 + (size_t)i * HID))[t] = make_float2(v0, v1);
    u32* fa = (u32*)(abf + (size_t)i * 160);
    u32* ga = (u32*)(abg + (size_t)i * 288);
    fa[t] = (u32)f2bf(v0) | ((u32)f2bf(v1) << 16);
    ga[66 + t] = fa[t] = (u32)f2bf(v0) | ((u32)f2bf(v1) << 16);
    if (t < 2) {
        float v2 = fmaxf(bLo + bias[128 + 2 * t], 0.f);
        float v3 = fmaxf(bHi + bias[129 + 2 * t], 0.f);
        ((float2*)(x1 + (size_t)i * HID))[64 + t] = make_float2(v2, v3);
        u32 pk = (u32)f2bf(v2) | ((u32)f2bf(v3) << 16);
        fa[64 + t] = pk;
        ga[130 + t] = pk;
    }
    if (t >= 2 && t < 16) fa[64 + t] = 0;   // zero pad cols 132..159
}

// ---------------- GAT attention coefficients (bf16 h) ----------------
__global__ void k_esed(const u16* __restrict__ hgb, const float* __restrict__ as,
                       const float* __restrict__ ad, float* __restrict__ es,
                       float* __restrict__ ed) {
    int idx = blockIdx.x * 256 + threadIdx.x;
    if (idx >= N_NODES * HEADS) return;
    int n = idx >> 2, k = idx & 3;
    const u32* hr = (const u32*)(hgb + (size_t)n * HID4 + k * HID);
    const float* ak = as + k * HID;
    const float* dk = ad + k * HID;
    float s = 0.f, d = 0.f;
    for (int c2 = 0; c2 < 66; ++c2) {
        u32 w = hr[c2];
        float lo = bflo(w), hi = bfhi(w);
        s += lo * ak[2 * c2] + hi * ak[2 * c2 + 1];
        d += lo * dk[2 * c2] + hi * dk[2 * c2 + 1];
    }
    es[idx] = s;
    ed[idx] = d;
}

// ---------------- GAT per-node softmax + aggregate (bf16 gather) ----------------
__global__ __launch_bounds__(64) void k_gat_node(
    const u16* __restrict__ hgb, const float* __restrict__ es,
    const float* __restrict__ ed, const int* __restrict__ indptr,
    const int* __restrict__ csr_src, float* __restrict__ tmp,
    const float* __restrict__ bias, float* __restrict__ xcout,
    u16* __restrict__ abg, int do_relu) {
    const int i = blockIdx.x;
    const int t = threadIdx.x;
    const int k = t & 3;
    const int s = indptr[i];
    const int deg = indptr[i + 1] - s;
    const float edk = ed[i * 4 + k];
    float eself = es[i * 4 + k] + edk;
    eself = (eself >= 0.f) ? eself : 0.2f * eself;
    float m = eself;
    for (int j0 = 0; j0 < deg; j0 += 16) {
        int j = j0 + (t >> 2);
        float e = -1e30f;
        if (j < deg) {
            int src = csr_src[s + j];
            e = es[src * 4 + k] + edk;
            e = (e >= 0.f) ? e : 0.2f * e;
            tmp[(size_t)(s + j) * 4 + k] = e;
        }
        m = fmaxf(m, e);
    }
    m = fmaxf(m, __shfl_xor(m, 4));
    m = fmaxf(m, __shfl_xor(m, 8));
    m = fmaxf(m, __shfl_xor(m, 16));
    m = fmaxf(m, __shfl_xor(m, 32));
    float dsum = 0.f;
    for (int j0 = 0; j0 < deg; j0 += 16) {
        int j = j0 + (t >> 2);
        if (j < deg) {
            float ex = expf(tmp[(size_t)(s + j) * 4 + k] - m);
            tmp[(size_t)(s + j) * 4 + k] = ex;
            dsum += ex;
        }
    }
    dsum += __shfl_xor(dsum, 4);
    dsum += __shfl_xor(dsum, 8);
    dsum += __shfl_xor(dsum, 16);
    dsum += __shfl_xor(dsum, 32);
    float exs = expf(eself - m);
    dsum += exs;
    __shared__ float s_inv[4], s_aself[4];
    if (t < 4) {
        float inv = 1.f / dsum;
        s_inv[t] = inv;
        s_aself[t] = exs * inv;
    }
    __syncthreads();
    const float inv0 = s_inv[0], inv1 = s_inv[1], inv2 = s_inv[2], inv3 = s_inv[3];
    float accLo, accHi, acc2Lo = 0.f, acc2Hi = 0.f;
    {
        const u32* ru = (const u32*)(hgb + (size_t)i * HID4);
        float a0 = s_aself[0], a1 = s_aself[1], a2 = s_aself[2], a3 = s_aself[3];
        u32 w0 = ru[t], w1 = ru[66 + t], w2 = ru[132 + t], w3 = ru[198 + t];
        accLo = a0 * bflo(w0) + a1 * bflo(w1) + a2 * bflo(w2) + a3 * bflo(w3);
        accHi = a0 * bfhi(w0) + a1 * bfhi(w1) + a2 * bfhi(w2) + a3 * bfhi(w3);
        if (t < 2) {
            u32 y0 = ru[64 + t], y1 = ru[130 + t], y2 = ru[196 + t], y3 = ru[262 + t];
            acc2Lo = a0 * bflo(y0) + a1 * bflo(y1) + a2 * bflo(y2) + a3 * bflo(y3);
            acc2Hi = a0 * bfhi(y0) + a1 * bfhi(y1) + a2 * bfhi(y2) + a3 * bfhi(y3);
        }
    }
    const float4* tmp4 = (const float4*)tmp;
    for (int j = 0; j < deg; ++j) {
        int src = csr_src[s + j];
        float4 ax = tmp4[s + j];
        float a0 = ax.x * inv0, a1 = ax.y * inv1, a2 = ax.z * inv2, a3 = ax.w * inv3;
        const u32* su = (const u32*)(hgb + (size_t)src * HID4);
        u32 w0 = su[t], w1 = su[66 + t], w2 = su[132 + t], w3 = su[198 + t];
        accLo += a0 * bflo(w0) + a1 * bflo(w1) + a2 * bflo(w2) + a3 * bflo(w3);
        accHi += a0 * bfhi(w0) + a1 * bfhi(w1) + a2 * bfhi(w2) + a3 * bfhi(w3);
        if (t < 2) {
            u32 y0 = su[64 + t], y1 = su[130 + t], y2 = su[196 + t], y3 = su[262 + t];
            acc2Lo += a0 * bflo(y0) + a1 * bflo(y1) + a2 * bflo(y2) + a3 * bflo(y3);
            acc2Hi += a0 * bfhi(y0) + a1 * bfhi(y1) + a2 * bfhi(y2) + a3 * bfhi(y3);
        }
    }
    float v0 = accLo * 0.25f + bias[2 * t];
    float v1 = accHi * 0.25f + bias[2 * t + 1];
    if (do_relu) { v0 = fmaxf(v0, 0.f); v1 = fmaxf(v1, 0.f); }
    ((float2*)(xcout + (size_t)i * HID))[t] = make_float2(v0, v1);
    u32* ga = (u32*)(abg + (size_t)i * 288);
    ga[t] = (u32)f2bf(v0) | ((u32)f2bf(v1) << 16);
    if (t < 2) {
        float v2 = acc2Lo * 0.25f + bias[128 + 2 * t];
        float v3 = acc2Hi * 0.25f + bias[129 + 2 * t];
        if (do_relu) { v2 = fmaxf(v2, 0.f); v3 = fmaxf(v3, 0.f); }
        ((float2*)(xcout + (size_t)i * HID))[64 + t] = make_float2(v2, v3);
        ga[64 + t] = (u32)f2bf(v2) | ((u32)f2bf(v3) << 16);
    }
}

// ---------------- pooling ----------------
__global__ void k_pool(const float* __restrict__ x3, const int* __restrict__ batch,
                       unsigned* __restrict__ genc) {
    int idx = blockIdx.x * 256 + threadIdx.x;
    if (idx >= N_NODES * HID) return;
    int n = idx / HID, c = idx - n * HID;
    unsigned u = __float_as_uint(x3[idx]);
    unsigned en = (u & 0x80000000u) ? ~u : (u | 0x80000000u);
    atomicMax(&genc[batch[n] * HID + c], en);
}

__global__ void k_decode(const unsigned* __restrict__ genc, float* __restrict__ g) {
    int idx = blockIdx.x * 256 + threadIdx.x;
    if (idx >= GRAPHS * HID) return;
    unsigned en = genc[idx];
    unsigned u = (en & 0x80000000u) ? (en & 0x7fffffffu) : ~en;
    g[idx] = __uint_as_float(u);
}

// ---------------- head layer 2 (fp32 out) ----------------
__global__ void k_head2(const float* __restrict__ gh, const float* __restrict__ W,
                        const float* __restrict__ b, float* __restrict__ out) {
    int idx = blockIdx.x * 64 + threadIdx.x;
    if (idx >= GRAPHS * OUT_DIM) return;
    int gi = idx / OUT_DIM, o = idx % OUT_DIM;
    float acc = b[o];
    const float* hr = gh + (size_t)gi * GFC;
    for (int j = 0; j < GFC; ++j) acc += hr[j] * W[j * OUT_DIM + o];
    out[idx] = acc;
}

// ---------------- launch ----------------
extern "C" void kernel_launch(void* const* d_in, const int* in_sizes, int n_in,
                              void* d_out, int out_size, void* d_ws, size_t ws_size,
                              hipStream_t stream) {
    const float* X       = (const float*)d_in[0];
    const int*   EI      = (const int*)d_in[1];
    const float* EW      = (const float*)d_in[2];
    const int*   BATCH   = (const int*)d_in[3];
    const float* W_gcn   = (const float*)d_in[4];
    const float* b_gcn   = (const float*)d_in[5];
    const float* W_gat1  = (const float*)d_in[6];
    const float* a_src1  = (const float*)d_in[7];
    const float* a_dst1  = (const float*)d_in[8];
    const float* b_gat1  = (const float*)d_in[9];
    const float* W_gat2  = (const float*)d_in[10];
    const float* a_src2  = (const float*)d_in[11];
    const float* a_dst2  = (const float*)d_in[12];
    const float* b_gat2  = (const float*)d_in[13];
    const float* W_fc1   = (const float*)d_in[14];
    const float* b_fc1   = (const float*)d_in[15];
    const float* W_fc2   = (const float*)d_in[16];
    const float* b_fc2   = (const float*)d_in[17];
    const float* pro_bias= (const float*)d_in[18];
    const float* W_g1    = (const float*)d_in[19];
    const float* b_g1    = (const float*)d_in[20];
    const float* W_g2    = (const float*)d_in[21];
    const float* b_g2    = (const float*)d_in[22];
    float* OUT = (float*)d_out;

    float* ws = (float*)d_ws;
    float*    dis     = ws + O_DIS;
    int*      counts  = (int*)(ws + O_CNT);
    int*      indptr  = (int*)(ws + O_IDP);
    int*      csr_src = (int*)(ws + O_CSR_S);
    float*    csr_w   = ws + O_CSR_W;
    float*    es      = ws + O_ES;
    float*    ed      = ws + O_ED;
    float*    tmp     = ws + O_TMP;
    float*    x1      = ws + O_X1;
    float*    x2      = ws + O_X2;
    float*    xc      = ws + O_XC;
    unsigned* genc    = (unsigned*)(ws + O_GE);
    float*    g       = ws + O_G;
    float*    gh      = ws + O_GH;
    u16*      hb      = (u16*)(ws + O_HB);
    u16*      hgb     = (u16*)(ws + O_HGB);
    u16*      ABF     = (u16*)(ws + O_ABF);
    u16*      ABG     = (u16*)(ws + O_ABG);
    u16*      BT      = (u16*)(ws + O_BT);
    u16*      BTG     = (u16*)(ws + O_BTG);
    float*    x3      = x1;

    const int EB = (N_EDGES + 255) / 256;
    const int NB = (N_NODES + 255) / 256;
    const int NHB = (N_NODES * HID + 255) / 256;

    // ---- CSR build ----
    hipMemsetAsync(counts, 0, N_NODES * sizeof(int), stream);
    k_count<<<EB, 256, 0, stream>>>(EI, counts);
    k_scan<<<1, 1024, 0, stream>>>(counts, indptr);
    hipMemsetAsync(counts, 0, N_NODES * sizeof(int), stream);
    k_scatter<<<EB, 256, 0, stream>>>(EI, EW, indptr, counts, csr_src, csr_w);
    k_deg<<<NB, 256, 0, stream>>>(indptr, csr_w, dis);

    // ---- shared gate weights ----
    k_cvtBt2<<<(192 * 288 + 255) / 256, 256, 0, stream>>>(W_fc1, W_fc2, BTG);

    // ---- GCN: h_b = bf16(X @ W_gcn), then aggregate ----
    k_cvtA<<<(N_NODES * 64 + 255) / 256, 256, 0, stream>>>(X, ABF, N_NODES, F_IN, 64);
    k_cvtBt<<<(192 * 64 + 255) / 256, 256, 0, stream>>>(W_gcn, BT, F_IN, HID, 192, 64);
    {
        dim3 grid(MP / 64, 3);
        k_mfma_gemm<<<grid, 256, 0, stream>>>(ABF, BT, nullptr, hb, HID, HID,
                                              N_NODES, HID, 64,
                                              nullptr, 0, 0, nullptr, nullptr, nullptr, nullptr);
    }
    k_gcn_agg<<<N_NODES, 64, 0, stream>>>(hb, indptr, csr_src, csr_w, dis, b_gcn,
                                          x1, ABF, ABG);

    // ---- GAT layer 1 ----
    k_cvtBt<<<(576 * 160 + 255) / 256, 256, 0, stream>>>(W_gat1, BT, HID, HID4, 576, 160);
    {
        dim3 grid(MP / 64, 9);
        k_mfma_gemm<<<grid, 256, 0, stream>>>(ABF, BT, nullptr, hgb, HID4, HID4,
                                              N_NODES, HID4, 160,
                                              nullptr, 0, 0, nullptr, nullptr, nullptr, nullptr);
    }
    k_esed<<<(N_NODES * HEADS + 255) / 256, 256, 0, stream>>>(hgb, a_src1, a_dst1, es, ed);
    k_gat_node<<<N_NODES, 64, 0, stream>>>(hgb, es, ed, indptr, csr_src, tmp, b_gat1,
                                           xc, ABG, 1);
    // gate 1: x2 = z*xc + (1-z)*x1; also write x2 bf16 into ABF (GAT2 A)
    {
        dim3 grid(MP / 64, 3);
        k_mfma_gemm<<<grid, 256, 0, stream>>>(ABG, BTG, x2, ABF, 160, 160,
                                              N_NODES, HID, 288,
                                              b_fc1, 0, 1, b_fc2, pro_bias, xc, x1);
    }
    k_cvtHalf<<<(N_NODES * 66 + 255) / 256, 256, 0, stream>>>(x2, ABG);

    // ---- GAT layer 2 ----
    k_cvtBt<<<(576 * 160 + 255) / 256, 256, 0, stream>>>(W_gat2, BT, HID, HID4, 576, 160);
    {
        dim3 grid(MP / 64, 9);
        k_mfma_gemm<<<grid, 256, 0, stream>>>(ABF, BT, nullptr, hgb, HID4, HID4,
                                              N_NODES, HID4, 160,
                                              nullptr, 0, 0, nullptr, nullptr, nullptr, nullptr);
    }
    k_esed<<<(N_NODES * HEADS + 255) / 256, 256, 0, stream>>>(hgb, a_src2, a_dst2, es, ed);
    k_gat_node<<<N_NODES, 64, 0, stream>>>(hgb, es, ed, indptr, csr_src, tmp, b_gat2,
                                           xc, ABG, 0);
    // gate 2: x3 = z*xc + (1-z)*x2 (fp32 only)
    {
        dim3 grid(MP / 64, 3);
        k_mfma_gemm<<<grid, 256, 0, stream>>>(ABG, BTG, x3, nullptr, 0, 0,
                                              N_NODES, HID, 288,
                                              b_fc1, 0, 1, b_fc2, pro_bias, xc, x2);
    }

    // ---- pool + head ----
    hipMemsetAsync(genc, 0, GRAPHS * HID * sizeof(unsigned), stream);
    k_pool<<<NHB, 256, 0, stream>>>(x3, BATCH, genc);
    k_decode<<<(GRAPHS * HID + 255) / 256, 256, 0, stream>>>(genc, g);
    k_cvtA<<<(GRAPHS * 160 + 255) / 256, 256, 0, stream>>>(g, ABF, GRAPHS, HID, 160);
    k_cvtBt<<<(1024 * 160 + 255) / 256, 256, 0, stream>>>(W_g1, BT, HID, GFC, 1024, 160);
    {
        dim3 grid(1, 16);
        k_mfma_gemm<<<grid, 256, 0, stream>>>(ABF, BT, gh, nullptr, 0, 0,
                                              GRAPHS, GFC, 160,
                                              b_g1, 1, 0, nullptr, nullptr, nullptr, nullptr);
    }
    k_head2<<<(GRAPHS * OUT_DIM + 63) / 64, 64, 0, stream>>>(gh, W_g2, b_g2, OUT);
}

// Round 5
// 619.423 us; speedup vs baseline: 1.6719x; 1.0652x over previous
//
#include <hip/hip_runtime.h>

// ---------------- problem constants ----------------
constexpr int N_NODES = 30000;
constexpr int N_EDGES = 300000;
constexpr int GRAPHS  = 64;
constexpr int F_IN    = 33;
constexpr int HID     = 132;
constexpr int HEADS   = 4;
constexpr int HID4    = HEADS * HID;   // 528
constexpr int OUT_DIM = 128;
constexpr int GFC     = 1024;
constexpr int MP      = 30016;         // N_NODES padded to x64

typedef unsigned int u32;
typedef unsigned short u16;

// ---------------- workspace layout (float units, 64-float aligned) ----------------
constexpr size_t rnd64(size_t x) { return (x + 63) & ~(size_t)63; }
constexpr size_t O_DIS   = 0;
constexpr size_t O_CNT   = O_DIS   + rnd64(N_NODES);
constexpr size_t O_IDP   = O_CNT   + rnd64(N_NODES);
constexpr size_t O_CSR_S = O_IDP   + rnd64(N_NODES + 1);
constexpr size_t O_CSR_W = O_CSR_S + rnd64(N_EDGES);
constexpr size_t O_ES    = O_CSR_W + rnd64(N_EDGES);
constexpr size_t O_ED    = O_ES    + rnd64(N_NODES * 4);
constexpr size_t O_TMP   = O_ED    + rnd64(N_NODES * 4);             // float, E*4
constexpr size_t O_X1    = O_TMP   + rnd64((size_t)N_EDGES * 4);
constexpr size_t O_X2    = O_X1    + rnd64((size_t)N_NODES * HID);
constexpr size_t O_XC    = O_X2    + rnd64((size_t)N_NODES * HID);
// u16 region (offsets in u16 units from U base)
constexpr size_t O_U     = O_XC    + rnd64((size_t)N_NODES * HID);
constexpr size_t U_HB    = 0;                                        // [N,132]
constexpr size_t U_HGB   = U_HB   + rnd64((size_t)N_NODES * HID);    // [N,528] permuted
constexpr size_t U_ABF   = U_HGB  + rnd64((size_t)N_NODES * HID4);   // [MP,160]
constexpr size_t U_ABG   = U_ABF  + rnd64((size_t)MP * 160);         // [MP,288]
constexpr size_t U_BTG   = U_ABG  + rnd64((size_t)MP * 288);         // [192,288]
constexpr size_t U_BTGCN = U_BTG  + rnd64(192 * 288);                // [192,64]
constexpr size_t U_BT1   = U_BTGCN+ rnd64(192 * 64);                 // [576,160]
constexpr size_t U_BT2   = U_BT1  + rnd64(576 * 160);                // [576,160]
constexpr size_t U_BTS1  = U_BT2  + rnd64(576 * 160);                // [1024,160]
constexpr size_t U_BTS2  = U_BTS1 + rnd64(1024 * 160);               // [128,1024]
constexpr size_t U_GB    = U_BTS2 + rnd64(128 * 1024);               // [64,160]
constexpr size_t U_GHB   = U_GB   + rnd64(64 * 160);                 // [64,1024]
constexpr size_t U_END   = U_GHB  + rnd64(64 * 1024);
// total ≈ O_U*4 + U_END*2 ≈ 100 MB

// ---------------- bf16 helpers ----------------
__device__ inline u16 f2bf(float f) {
    u32 u = __float_as_uint(f);
    return (u16)((u + 0x7fffu + ((u >> 16) & 1u)) >> 16);
}
__device__ inline u32 pk2(float a, float b) { return (u32)f2bf(a) | ((u32)f2bf(b) << 16); }
__device__ inline float bflo(u32 w) { return __uint_as_float(w << 16); }
__device__ inline float bfhi(u32 w) { return __uint_as_float(w & 0xffff0000u); }

typedef __attribute__((ext_vector_type(8))) short s8b;
typedef __attribute__((ext_vector_type(4))) float f32x4;

// ---------------- CSR build ----------------
__global__ void k_count(const int* __restrict__ ei, int* __restrict__ counts) {
    int e = blockIdx.x * 256 + threadIdx.x;
    if (e < N_EDGES) atomicAdd(&counts[ei[N_EDGES + e]], 1);
}

__global__ __launch_bounds__(1024) void k_scan(const int* __restrict__ counts,
                                               int* __restrict__ indptr) {
    __shared__ int wsum[16];
    __shared__ int carry_s;
    const int tid = threadIdx.x, lane = tid & 63, w = tid >> 6;
    if (tid == 0) carry_s = 0;
    __syncthreads();
    for (int base = 0; base < N_NODES; base += 1024) {
        int i = base + tid;
        int v = (i < N_NODES) ? counts[i] : 0;
        int x = v;
        #pragma unroll
        for (int off = 1; off < 64; off <<= 1) {
            int y = __shfl_up(x, off);
            if (lane >= off) x += y;
        }
        if (lane == 63) wsum[w] = x;
        __syncthreads();
        if (w == 0) {
            int s = (lane < 16) ? wsum[lane] : 0;
            #pragma unroll
            for (int off = 1; off < 16; off <<= 1) {
                int y = __shfl_up(s, off);
                if (lane >= off) s += y;
            }
            if (lane < 16) wsum[lane] = s;
        }
        __syncthreads();
        int carry = carry_s;
        int incl = x + ((w > 0) ? wsum[w - 1] : 0);
        if (i < N_NODES) indptr[i] = carry + incl - v;
        __syncthreads();
        if (tid == 1023) carry_s = carry + wsum[15];
        __syncthreads();
    }
    if (threadIdx.x == 0) indptr[N_NODES] = carry_s;
}

__global__ void k_scatter(const int* __restrict__ ei, const float* __restrict__ ew,
                          const int* __restrict__ indptr, int* __restrict__ cursor,
                          int* __restrict__ csr_src, float* __restrict__ csr_w) {
    int e = blockIdx.x * 256 + threadIdx.x;
    if (e >= N_EDGES) return;
    int src = ei[e];
    int dst = ei[N_EDGES + e];
    int pos = indptr[dst] + atomicAdd(&cursor[dst], 1);
    csr_src[pos] = src;
    csr_w[pos] = ew[e];
}

__global__ void k_deg(const int* __restrict__ indptr, const float* __restrict__ csr_w,
                      float* __restrict__ dis) {
    int i = blockIdx.x * 256 + threadIdx.x;
    if (i >= N_NODES) return;
    float d = 1.0f;
    int s = indptr[i], e = indptr[i + 1];
    for (int j = s; j < e; ++j) d += csr_w[j];
    dis[i] = (d > 0.f) ? rsqrtf(fmaxf(d, 1e-12f)) : 0.f;
}

// ---------------- merged weight conversion ----------------
constexpr int S0 = 192 * 288;    // BTG  (gate [Wfc1;Wfc2])
constexpr int S1 = 192 * 64;     // BTGCN
constexpr int S2 = 576 * 160;    // BT1
constexpr int S3 = 576 * 160;    // BT2
constexpr int S4 = 1024 * 160;   // BTS1 (W_g1)
constexpr int S5 = 128 * 1024;   // BTS2 (W_g2)
constexpr int SW_TOT = S0 + S1 + S2 + S3 + S4 + S5;

__global__ void k_cvtW(const float* __restrict__ Wfc1, const float* __restrict__ Wfc2,
                       const float* __restrict__ Wgcn, const float* __restrict__ Wgat1,
                       const float* __restrict__ Wgat2, const float* __restrict__ Wg1,
                       const float* __restrict__ Wg2,
                       u16* __restrict__ BTG, u16* __restrict__ BTGCN,
                       u16* __restrict__ BT1, u16* __restrict__ BT2,
                       u16* __restrict__ BTS1, u16* __restrict__ BTS2) {
    int idx = blockIdx.x * 256 + threadIdx.x;
    if (idx < S0) {
        int n = idx / 288, k = idx - n * 288;
        u16 v = 0;
        if (n < HID) {
            if (k < HID) v = f2bf(Wfc1[(size_t)k * HID + n]);
            else if (k < 2 * HID) v = f2bf(Wfc2[(size_t)(k - HID) * HID + n]);
        }
        BTG[idx] = v;
        return;
    }
    idx -= S0;
    if (idx < S1) {
        int n = idx / 64, k = idx - n * 64;
        BTGCN[idx] = (k < F_IN && n < HID) ? f2bf(Wgcn[(size_t)k * HID + n]) : (u16)0;
        return;
    }
    idx -= S1;
    if (idx < S2) {
        int n = idx / 160, k = idx - n * 160;
        BT1[idx] = (k < HID && n < HID4) ? f2bf(Wgat1[(size_t)k * HID4 + n]) : (u16)0;
        return;
    }
    idx -= S2;
    if (idx < S3) {
        int n = idx / 160, k = idx - n * 160;
        BT2[idx] = (k < HID && n < HID4) ? f2bf(Wgat2[(size_t)k * HID4 + n]) : (u16)0;
        return;
    }
    idx -= S3;
    if (idx < S4) {
        int n = idx / 160, k = idx - n * 160;
        BTS1[idx] = (k < HID) ? f2bf(Wg1[(size_t)k * GFC + n]) : (u16)0;
        return;
    }
    idx -= S4;
    if (idx < S5) {
        int n = idx / 1024, k = idx - n * 1024;
        BTS2[idx] = f2bf(Wg2[(size_t)k * OUT_DIM + n]);
    }
}

__global__ void k_cvtA(const float* __restrict__ src, u16* __restrict__ dst,
                       int M, int K, int Kp) {
    int idx = blockIdx.x * 256 + threadIdx.x;
    if (idx >= M * Kp) return;
    int r = idx / Kp, k = idx - r * Kp;
    dst[idx] = (k < K) ? f2bf(src[(size_t)r * K + k]) : (u16)0;
}

// ---------------- MFMA bf16 GEMM: out = A[*,Kp] @ Bt[Np,Kp]^T ----------------
// perm: Cb written in [row][c2][head] interleaved layout (for GAT h).
// Cb2: optional second bf16 copy at column offset coff2 (for gate1 -> ABG).
__global__ __launch_bounds__(256) void k_mfma_gemm(
    const u16* __restrict__ A, const u16* __restrict__ Bt,
    float* __restrict__ C, u16* __restrict__ Cb, int ldcb, int padN, int perm,
    u16* __restrict__ Cb2, int ldcb2, int coff2,
    int M, int N, int Kp,
    const float* __restrict__ bias, int relu, int gate,
    const float* __restrict__ b2, const float* __restrict__ pb,
    const float* __restrict__ xcg, const float* __restrict__ xpg) {
    const int bm = blockIdx.x * 64;
    const int bn = blockIdx.y * 64;
    const int w = threadIdx.x >> 6;
    const int lane = threadIdx.x & 63;
    const int m16 = lane & 15;
    const int quad = lane >> 4;
    const u16* Ab = A + (size_t)(bm + m16) * Kp + quad * 8;
    const u16* Bb = Bt + (size_t)(bn + w * 16 + m16) * Kp + quad * 8;
    f32x4 acc[4];
    #pragma unroll
    for (int r = 0; r < 4; ++r) acc[r] = (f32x4){0.f, 0.f, 0.f, 0.f};
    for (int k0 = 0; k0 < Kp; k0 += 32) {
        s8b b = *(const s8b*)(Bb + k0);
        s8b a0 = *(const s8b*)(Ab + k0);
        s8b a1 = *(const s8b*)(Ab + (size_t)16 * Kp + k0);
        s8b a2 = *(const s8b*)(Ab + (size_t)32 * Kp + k0);
        s8b a3 = *(const s8b*)(Ab + (size_t)48 * Kp + k0);
        acc[0] = __builtin_amdgcn_mfma_f32_16x16x32_bf16(a0, b, acc[0], 0, 0, 0);
        acc[1] = __builtin_amdgcn_mfma_f32_16x16x32_bf16(a1, b, acc[1], 0, 0, 0);
        acc[2] = __builtin_amdgcn_mfma_f32_16x16x32_bf16(a2, b, acc[2], 0, 0, 0);
        acc[3] = __builtin_amdgcn_mfma_f32_16x16x32_bf16(a3, b, acc[3], 0, 0, 0);
    }
    const int col = bn + w * 16 + m16;
    const bool colok = col < N;
    int pcol = 0;
    if (perm && colok) {
        int kk = col / HID, cc = col - kk * HID;
        pcol = ((cc >> 1) << 3) + (kk << 1) + (cc & 1);
    }
    float bsum = 0.f;
    if (colok) {
        if (gate) bsum = bias[col] + b2[col] + pb[col];
        else if (bias) bsum = bias[col];
    }
    #pragma unroll
    for (int r = 0; r < 4; ++r) {
        #pragma unroll
        for (int j = 0; j < 4; ++j) {
            int row = bm + r * 16 + quad * 4 + j;
            if (row >= M) continue;
            if (colok) {
                float v = acc[r][j] + bsum;
                float res;
                if (gate) {
                    float z = 1.f / (1.f + expf(-v));
                    size_t ix = (size_t)row * N + col;
                    res = z * xcg[ix] + (1.f - z) * xpg[ix];
                } else {
                    if (relu) v = fmaxf(v, 0.f);
                    res = v;
                }
                if (C) C[(size_t)row * N + col] = res;
                if (Cb) {
                    if (perm) Cb[(size_t)row * HID4 + pcol] = f2bf(res);
                    else      Cb[(size_t)row * ldcb + col] = f2bf(res);
                }
                if (Cb2) Cb2[(size_t)row * ldcb2 + coff2 + col] = f2bf(res);
            } else if (Cb && !perm && col < padN) {
                Cb[(size_t)row * ldcb + col] = 0;
            }
        }
    }
}

// ---------------- GCN aggregate (bf16 gather, dual-write) ----------------
__global__ __launch_bounds__(64) void k_gcn_agg(
    const u16* __restrict__ hb, const int* __restrict__ indptr,
    const int* __restrict__ csr_src, const float* __restrict__ csr_w,
    const float* __restrict__ dis, const float* __restrict__ bias,
    float* __restrict__ x1, u16* __restrict__ abf, u16* __restrict__ abg) {
    const int i = blockIdx.x;
    const int t = threadIdx.x;
    const float di = dis[i];
    const int s = indptr[i], e = indptr[i + 1];
    const float nself = di * di;
    const u32* ru = (const u32*)(hb + (size_t)i * HID);
    u32 w = ru[t];
    float aLo = nself * bflo(w), aHi = nself * bfhi(w);
    float bLo = 0.f, bHi = 0.f;
    if (t < 2) { u32 w2 = ru[64 + t]; bLo = nself * bflo(w2); bHi = nself * bfhi(w2); }
    for (int j = s; j < e; ++j) {
        int src = csr_src[j];
        float nb = dis[src] * csr_w[j] * di;
        const u32* su = (const u32*)(hb + (size_t)src * HID);
        u32 ws = su[t];
        aLo += nb * bflo(ws);
        aHi += nb * bfhi(ws);
        if (t < 2) { u32 w2 = su[64 + t]; bLo += nb * bflo(w2); bHi += nb * bfhi(w2); }
    }
    float v0 = fmaxf(aLo + bias[2 * t], 0.f);
    float v1 = fmaxf(aHi + bias[2 * t + 1], 0.f);
    ((float2*)(x1 + (size_t)i * HID))[t] = make_float2(v0, v1);
    u32* fa = (u32*)(abf + (size_t)i * 160);
    u32* ga = (u32*)(abg + (size_t)i * 288);
    u32 p = pk2(v0, v1);
    fa[t] = p;
    ga[66 + t] = p;
    if (t < 2) {
        float v2 = fmaxf(bLo + bias[128 + 2 * t], 0.f);
        float v3 = fmaxf(bHi + bias[129 + 2 * t], 0.f);
        ((float2*)(x1 + (size_t)i * HID))[64 + t] = make_float2(v2, v3);
        u32 pk = pk2(v2, v3);
        fa[64 + t] = pk;
        ga[130 + t] = pk;
    }
    if (t >= 2 && t < 16) fa[64 + t] = 0;   // zero pad cols 132..159
}

// ---------------- GAT attention coefficients (permuted hgb, wave/node) ------
__global__ __launch_bounds__(64) void k_esed(
    const u16* __restrict__ hgb, const float* __restrict__ as,
    const float* __restrict__ ad, float* __restrict__ es, float* __restrict__ ed) {
    const int n = blockIdx.x, t = threadIdx.x;
    const int k = t & 3;
    const u32* hr = (const u32*)(hgb + (size_t)n * HID4);
    float s = 0.f, d = 0.f;
    #pragma unroll
    for (int i = 0; i < 5; ++i) {
        int idx = t + 64 * i;          // word = c2*4 + k, (idx&3)==k always
        if (idx < 264) {
            int c2 = idx >> 2;
            u32 w = hr[idx];
            float lo = bflo(w), hi = bfhi(w);
            s += lo * as[k * HID + 2 * c2] + hi * as[k * HID + 2 * c2 + 1];
            d += lo * ad[k * HID + 2 * c2] + hi * ad[k * HID + 2 * c2 + 1];
        }
    }
    s += __shfl_xor(s, 4);  s += __shfl_xor(s, 8);
    s += __shfl_xor(s, 16); s += __shfl_xor(s, 32);
    d += __shfl_xor(d, 4);  d += __shfl_xor(d, 8);
    d += __shfl_xor(d, 16); d += __shfl_xor(d, 32);
    if (t < 4) { es[n * 4 + t] = s; ed[n * 4 + t] = d; }
}

// ---------------- GAT per-node softmax + aggregate (dwordx4 gather) ---------
__global__ __launch_bounds__(64) void k_gat_node(
    const u16* __restrict__ hgb, const float* __restrict__ es,
    const float* __restrict__ ed, const int* __restrict__ indptr,
    const int* __restrict__ csr_src, float* __restrict__ tmp,
    const float* __restrict__ bias, float* __restrict__ xcout,
    u16* __restrict__ abg, int do_relu) {
    const int i = blockIdx.x;
    const int t = threadIdx.x;
    const int k = t & 3;
    const int s = indptr[i];
    const int deg = indptr[i + 1] - s;
    const float edk = ed[i * 4 + k];
    float eself = es[i * 4 + k] + edk;
    eself = (eself >= 0.f) ? eself : 0.2f * eself;
    float m = eself;
    for (int j0 = 0; j0 < deg; j0 += 16) {
        int j = j0 + (t >> 2);
        float e = -1e30f;
        if (j < deg) {
            int src = csr_src[s + j];
            e = es[src * 4 + k] + edk;
            e = (e >= 0.f) ? e : 0.2f * e;
            tmp[(size_t)(s + j) * 4 + k] = e;
        }
        m = fmaxf(m, e);
    }
    m = fmaxf(m, __shfl_xor(m, 4));
    m = fmaxf(m, __shfl_xor(m, 8));
    m = fmaxf(m, __shfl_xor(m, 16));
    m = fmaxf(m, __shfl_xor(m, 32));
    float dsum = 0.f;
    for (int j0 = 0; j0 < deg; j0 += 16) {
        int j = j0 + (t >> 2);
        if (j < deg) {
            float ex = expf(tmp[(size_t)(s + j) * 4 + k] - m);
            tmp[(size_t)(s + j) * 4 + k] = ex;
            dsum += ex;
        }
    }
    dsum += __shfl_xor(dsum, 4);
    dsum += __shfl_xor(dsum, 8);
    dsum += __shfl_xor(dsum, 16);
    dsum += __shfl_xor(dsum, 32);
    float exs = expf(eself - m);
    dsum += exs;
    __shared__ float s_inv[4], s_aself[4];
    if (t < 4) {
        float inv = 1.f / dsum;
        s_inv[t] = inv;
        s_aself[t] = exs * inv;
    }
    __syncthreads();
    const float inv0 = s_inv[0], inv1 = s_inv[1], inv2 = s_inv[2], inv3 = s_inv[3];
    float accLo, accHi, acc2Lo = 0.f, acc2Hi = 0.f;
    {
        const uint4* ru = (const uint4*)(hgb + (size_t)i * HID4);
        float a0 = s_aself[0], a1 = s_aself[1], a2 = s_aself[2], a3 = s_aself[3];
        uint4 w = ru[t];
        accLo = a0 * bflo(w.x) + a1 * bflo(w.y) + a2 * bflo(w.z) + a3 * bflo(w.w);
        accHi = a0 * bfhi(w.x) + a1 * bfhi(w.y) + a2 * bfhi(w.z) + a3 * bfhi(w.w);
        if (t < 2) {
            uint4 y = ru[64 + t];
            acc2Lo = a0 * bflo(y.x) + a1 * bflo(y.y) + a2 * bflo(y.z) + a3 * bflo(y.w);
            acc2Hi = a0 * bfhi(y.x) + a1 * bfhi(y.y) + a2 * bfhi(y.z) + a3 * bfhi(y.w);
        }
    }
    const float4* tmp4 = (const float4*)tmp;
    for (int j = 0; j < deg; ++j) {
        int src = csr_src[s + j];
        float4 ax = tmp4[s + j];
        float a0 = ax.x * inv0, a1 = ax.y * inv1, a2 = ax.z * inv2, a3 = ax.w * inv3;
        const uint4* su = (const uint4*)(hgb + (size_t)src * HID4);
        uint4 w = su[t];
        accLo += a0 * bflo(w.x) + a1 * bflo(w.y) + a2 * bflo(w.z) + a3 * bflo(w.w);
        accHi += a0 * bfhi(w.x) + a1 * bfhi(w.y) + a2 * bfhi(w.z) + a3 * bfhi(w.w);
        if (t < 2) {
            uint4 y = su[64 + t];
            acc2Lo += a0 * bflo(y.x) + a1 * bflo(y.y) + a2 * bflo(y.z) + a3 * bflo(y.w);
            acc2Hi += a0 * bfhi(y.x) + a1 * bfhi(y.y) + a2 * bfhi(y.z) + a3 * bfhi(y.w);
        }
    }
    float v0 = accLo * 0.25f + bias[2 * t];
    float v1 = accHi * 0.25f + bias[2 * t + 1];
    if (do_relu) { v0 = fmaxf(v0, 0.f); v1 = fmaxf(v1, 0.f); }
    ((float2*)(xcout + (size_t)i * HID))[t] = make_float2(v0, v1);
    u32* ga = (u32*)(abg + (size_t)i * 288);
    ga[t] = pk2(v0, v1);
    if (t < 2) {
        float v2 = acc2Lo * 0.25f + bias[128 + 2 * t];
        float v3 = acc2Hi * 0.25f + bias[129 + 2 * t];
        if (do_relu) { v2 = fmaxf(v2, 0.f); v3 = fmaxf(v3, 0.f); }
        ((float2*)(xcout + (size_t)i * HID))[64 + t] = make_float2(v2, v3);
        ga[64 + t] = pk2(v2, v3);
    }
}

// ---------------- pooling: analytic per-graph max, no atomics ----------------
__global__ __launch_bounds__(256) void k_pool(const float* __restrict__ x3,
                                              u16* __restrict__ gb) {
    __shared__ float sm[4][132];
    const int g = blockIdx.x;
    const int tid = threadIdx.x, t = tid & 63, w = tid >> 6;
    const int n0 = (g * N_NODES + GRAPHS - 1) / GRAPHS;
    const int n1 = ((g + 1) * N_NODES + GRAPHS - 1) / GRAPHS;
    float m0 = -3.4e38f, m1 = -3.4e38f, m2 = -3.4e38f, m3 = -3.4e38f;
    for (int n = n0 + w; n < n1; n += 4) {
        const float2* r = (const float2*)(x3 + (size_t)n * HID);
        float2 v = r[t];
        m0 = fmaxf(m0, v.x); m1 = fmaxf(m1, v.y);
        if (t < 2) { float2 u = r[64 + t]; m2 = fmaxf(m2, u.x); m3 = fmaxf(m3, u.y); }
    }
    sm[w][2 * t] = m0; sm[w][2 * t + 1] = m1;
    if (t < 2) { sm[w][128 + 2 * t] = m2; sm[w][129 + 2 * t] = m3; }
    __syncthreads();
    if (w == 0) {
        float a0 = fmaxf(fmaxf(sm[0][2*t], sm[1][2*t]), fmaxf(sm[2][2*t], sm[3][2*t]));
        float a1 = fmaxf(fmaxf(sm[0][2*t+1], sm[1][2*t+1]), fmaxf(sm[2][2*t+1], sm[3][2*t+1]));
        u32* fa = (u32*)(gb + (size_t)g * 160);
        fa[t] = pk2(a0, a1);
        if (t < 2) {
            float a2 = fmaxf(fmaxf(sm[0][128+2*t], sm[1][128+2*t]), fmaxf(sm[2][128+2*t], sm[3][128+2*t]));
            float a3 = fmaxf(fmaxf(sm[0][129+2*t], sm[1][129+2*t]), fmaxf(sm[2][129+2*t], sm[3][129+2*t]));
            fa[64 + t] = pk2(a2, a3);
        }
        if (t >= 2 && t < 16) fa[64 + t] = 0;
    }
}

// ---------------- launch ----------------
extern "C" void kernel_launch(void* const* d_in, const int* in_sizes, int n_in,
                              void* d_out, int out_size, void* d_ws, size_t ws_size,
                              hipStream_t stream) {
    const float* X       = (const float*)d_in[0];
    const int*   EI      = (const int*)d_in[1];
    const float* EW      = (const float*)d_in[2];
    const float* W_gcn   = (const float*)d_in[4];
    const float* b_gcn   = (const float*)d_in[5];
    const float* W_gat1  = (const float*)d_in[6];
    const float* a_src1  = (const float*)d_in[7];
    const float* a_dst1  = (const float*)d_in[8];
    const float* b_gat1  = (const float*)d_in[9];
    const float* W_gat2  = (const float*)d_in[10];
    const float* a_src2  = (const float*)d_in[11];
    const float* a_dst2  = (const float*)d_in[12];
    const float* b_gat2  = (const float*)d_in[13];
    const float* W_fc1   = (const float*)d_in[14];
    const float* b_fc1   = (const float*)d_in[15];
    const float* W_fc2   = (const float*)d_in[16];
    const float* b_fc2   = (const float*)d_in[17];
    const float* pro_bias= (const float*)d_in[18];
    const float* W_g1    = (const float*)d_in[19];
    const float* b_g1    = (const float*)d_in[20];
    const float* W_g2    = (const float*)d_in[21];
    const float* b_g2    = (const float*)d_in[22];
    float* OUT = (float*)d_out;

    float* ws = (float*)d_ws;
    float*    dis     = ws + O_DIS;
    int*      counts  = (int*)(ws + O_CNT);
    int*      indptr  = (int*)(ws + O_IDP);
    int*      csr_src = (int*)(ws + O_CSR_S);
    float*    csr_w   = ws + O_CSR_W;
    float*    es      = ws + O_ES;
    float*    ed      = ws + O_ED;
    float*    tmp     = ws + O_TMP;
    float*    x1      = ws + O_X1;
    float*    x2      = ws + O_X2;
    float*    xc      = ws + O_XC;
    u16*      U       = (u16*)(ws + O_U);
    u16*      hb      = U + U_HB;
    u16*      hgb     = U + U_HGB;
    u16*      ABF     = U + U_ABF;
    u16*      ABG     = U + U_ABG;
    u16*      BTG     = U + U_BTG;
    u16*      BTGCN   = U + U_BTGCN;
    u16*      BT1     = U + U_BT1;
    u16*      BT2     = U + U_BT2;
    u16*      BTS1    = U + U_BTS1;
    u16*      BTS2    = U + U_BTS2;
    u16*      GB      = U + U_GB;
    u16*      GHB     = U + U_GHB;
    float*    x3      = x1;

    const int EB = (N_EDGES + 255) / 256;
    const int NB = (N_NODES + 255) / 256;

    // ---- CSR build ----
    hipMemsetAsync(counts, 0, N_NODES * sizeof(int), stream);
    k_count<<<EB, 256, 0, stream>>>(EI, counts);
    k_scan<<<1, 1024, 0, stream>>>(counts, indptr);
    hipMemsetAsync(counts, 0, N_NODES * sizeof(int), stream);
    k_scatter<<<EB, 256, 0, stream>>>(EI, EW, indptr, counts, csr_src, csr_w);
    k_deg<<<NB, 256, 0, stream>>>(indptr, csr_w, dis);

    // ---- all weight conversions in one dispatch ----
    k_cvtW<<<(SW_TOT + 255) / 256, 256, 0, stream>>>(
        W_fc1, W_fc2, W_gcn, W_gat1, W_gat2, W_g1, W_g2,
        BTG, BTGCN, BT1, BT2, BTS1, BTS2);

    // ---- GCN ----
    k_cvtA<<<(N_NODES * 64 + 255) / 256, 256, 0, stream>>>(X, ABF, N_NODES, F_IN, 64);
    {
        dim3 grid(MP / 64, 3);
        k_mfma_gemm<<<grid, 256, 0, stream>>>(ABF, BTGCN, nullptr, hb, HID, HID, 0,
                                              nullptr, 0, 0, N_NODES, HID, 64,
                                              nullptr, 0, 0, nullptr, nullptr, nullptr, nullptr);
    }
    k_gcn_agg<<<N_NODES, 64, 0, stream>>>(hb, indptr, csr_src, csr_w, dis, b_gcn,
                                          x1, ABF, ABG);

    // ---- GAT layer 1 ----
    {
        dim3 grid(MP / 64, 9);
        k_mfma_gemm<<<grid, 256, 0, stream>>>(ABF, BT1, nullptr, hgb, 0, 0, 1,
                                              nullptr, 0, 0, N_NODES, HID4, 160,
                                              nullptr, 0, 0, nullptr, nullptr, nullptr, nullptr);
    }
    k_esed<<<N_NODES, 64, 0, stream>>>(hgb, a_src1, a_dst1, es, ed);
    k_gat_node<<<N_NODES, 64, 0, stream>>>(hgb, es, ed, indptr, csr_src, tmp, b_gat1,
                                           xc, ABG, 1);
    // gate 1: x2 fp32 + bf16 into ABF (GAT2 A) + bf16 into ABG cols 132.. (gate2 xp)
    {
        dim3 grid(MP / 64, 3);
        k_mfma_gemm<<<grid, 256, 0, stream>>>(ABG, BTG, x2, ABF, 160, 160, 0,
                                              ABG, 288, 132, N_NODES, HID, 288,
                                              b_fc1, 0, 1, b_fc2, pro_bias, xc, x1);
    }

    // ---- GAT layer 2 ----
    {
        dim3 grid(MP / 64, 9);
        k_mfma_gemm<<<grid, 256, 0, stream>>>(ABF, BT2, nullptr, hgb, 0, 0, 1,
                                              nullptr, 0, 0, N_NODES, HID4, 160,
                                              nullptr, 0, 0, nullptr, nullptr, nullptr, nullptr);
    }
    k_esed<<<N_NODES, 64, 0, stream>>>(hgb, a_src2, a_dst2, es, ed);
    k_gat_node<<<N_NODES, 64, 0, stream>>>(hgb, es, ed, indptr, csr_src, tmp, b_gat2,
                                           xc, ABG, 0);
    // gate 2: x3 fp32 only
    {
        dim3 grid(MP / 64, 3);
        k_mfma_gemm<<<grid, 256, 0, stream>>>(ABG, BTG, x3, nullptr, 0, 0, 0,
                                              nullptr, 0, 0, N_NODES, HID, 288,
                                              b_fc1, 0, 1, b_fc2, pro_bias, xc, x2);
    }

    // ---- pool + head (all MFMA) ----
    k_pool<<<GRAPHS, 256, 0, stream>>>(x3, GB);
    {
        dim3 grid(1, 16);
        k_mfma_gemm<<<grid, 256, 0, stream>>>(GB, BTS1, nullptr, GHB, GFC, GFC, 0,
                                              nullptr, 0, 0, GRAPHS, GFC, 160,
                                              b_g1, 1, 0, nullptr, nullptr, nullptr, nullptr);
    }
    {
        dim3 grid(1, 2);
        k_mfma_gemm<<<grid, 256, 0, stream>>>(GHB, BTS2, OUT, nullptr, 0, 0, 0,
                                              nullptr, 0, 0, GRAPHS, OUT_DIM, 1024,
                                              b_g2, 0, 0, nullptr, nullptr, nullptr, nullptr);
    }
}

// Round 6
// 589.515 us; speedup vs baseline: 1.7567x; 1.0507x over previous
//
#include <hip/hip_runtime.h>

// ---------------- problem constants ----------------
constexpr int N_NODES = 30000;
constexpr int N_EDGES = 300000;
constexpr int GRAPHS  = 64;
constexpr int F_IN    = 33;
constexpr int HID     = 132;
constexpr int HEADS   = 4;
constexpr int HID4    = HEADS * HID;   // 528
constexpr int OUT_DIM = 128;
constexpr int GFC     = 1024;
constexpr int MP      = 30016;         // N_NODES padded to x64
constexpr int CAP     = 128;           // max in-degree on LDS fast path

typedef unsigned int u32;
typedef unsigned short u16;

// ---------------- workspace layout (float units, 64-float aligned) ----------------
constexpr size_t rnd64(size_t x) { return (x + 63) & ~(size_t)63; }
constexpr size_t O_DIS   = 0;
constexpr size_t O_CNT   = O_DIS   + rnd64(N_NODES);
constexpr size_t O_IDP   = O_CNT   + rnd64(N_NODES);
constexpr size_t O_CSR_S = O_IDP   + rnd64(N_NODES + 1);
constexpr size_t O_CSR_W = O_CSR_S + rnd64(N_EDGES);
constexpr size_t O_ESD   = O_CSR_W + rnd64(N_EDGES);                 // float, N*8 (es[4],ed[4])
constexpr size_t O_TMP   = O_ESD   + rnd64((size_t)N_NODES * 8);     // float, E*4 (fallback)
constexpr size_t O_X1    = O_TMP   + rnd64((size_t)N_EDGES * 4);
constexpr size_t O_X2    = O_X1    + rnd64((size_t)N_NODES * HID);
constexpr size_t O_XC    = O_X2    + rnd64((size_t)N_NODES * HID);
// u16 region (offsets in u16 units from U base)
constexpr size_t O_U     = O_XC    + rnd64((size_t)N_NODES * HID);
constexpr size_t U_HB    = 0;                                        // [N,132]
constexpr size_t U_HGB   = U_HB   + rnd64((size_t)N_NODES * HID);    // [N,528] permuted
constexpr size_t U_ABF   = U_HGB  + rnd64((size_t)N_NODES * HID4);   // [MP,160]
constexpr size_t U_ABG   = U_ABF  + rnd64((size_t)MP * 160);         // [MP,288]
constexpr size_t U_BTG   = U_ABG  + rnd64((size_t)MP * 288);         // [192,288]
constexpr size_t U_BTGCN = U_BTG  + rnd64(192 * 288);                // [192,64]
constexpr size_t U_BT1   = U_BTGCN+ rnd64(192 * 64);                 // [576,160] (+wes rows 528..535)
constexpr size_t U_BT2   = U_BT1  + rnd64(576 * 160);                // [576,160]
constexpr size_t U_BTS1  = U_BT2  + rnd64(576 * 160);                // [1024,160]
constexpr size_t U_BTS2  = U_BTS1 + rnd64(1024 * 160);               // [128,1024]
constexpr size_t U_GB    = U_BTS2 + rnd64(128 * 1024);               // [64,160]
constexpr size_t U_GHB   = U_GB   + rnd64(64 * 160);                 // [64,1024]

// ---------------- bf16 helpers ----------------
__device__ inline u16 f2bf(float f) {
    u32 u = __float_as_uint(f);
    return (u16)((u + 0x7fffu + ((u >> 16) & 1u)) >> 16);
}
__device__ inline u32 pk2(float a, float b) { return (u32)f2bf(a) | ((u32)f2bf(b) << 16); }
__device__ inline float bflo(u32 w) { return __uint_as_float(w << 16); }
__device__ inline float bfhi(u32 w) { return __uint_as_float(w & 0xffff0000u); }

typedef __attribute__((ext_vector_type(8))) short s8b;
typedef __attribute__((ext_vector_type(4))) float f32x4;

// ---------------- CSR build ----------------
__global__ void k_count(const int* __restrict__ ei, int* __restrict__ counts) {
    int e = blockIdx.x * 256 + threadIdx.x;
    if (e < N_EDGES) atomicAdd(&counts[ei[N_EDGES + e]], 1);
}

__global__ __launch_bounds__(1024) void k_scan(const int* __restrict__ counts,
                                               int* __restrict__ indptr) {
    __shared__ int wsum[16];
    __shared__ int carry_s;
    const int tid = threadIdx.x, lane = tid & 63, w = tid >> 6;
    if (tid == 0) carry_s = 0;
    __syncthreads();
    for (int base = 0; base < N_NODES; base += 1024) {
        int i = base + tid;
        int v = (i < N_NODES) ? counts[i] : 0;
        int x = v;
        #pragma unroll
        for (int off = 1; off < 64; off <<= 1) {
            int y = __shfl_up(x, off);
            if (lane >= off) x += y;
        }
        if (lane == 63) wsum[w] = x;
        __syncthreads();
        if (w == 0) {
            int s = (lane < 16) ? wsum[lane] : 0;
            #pragma unroll
            for (int off = 1; off < 16; off <<= 1) {
                int y = __shfl_up(s, off);
                if (lane >= off) s += y;
            }
            if (lane < 16) wsum[lane] = s;
        }
        __syncthreads();
        int carry = carry_s;
        int incl = x + ((w > 0) ? wsum[w - 1] : 0);
        if (i < N_NODES) indptr[i] = carry + incl - v;
        __syncthreads();
        if (tid == 1023) carry_s = carry + wsum[15];
        __syncthreads();
    }
    if (threadIdx.x == 0) indptr[N_NODES] = carry_s;
}

__global__ void k_scatter(const int* __restrict__ ei, const float* __restrict__ ew,
                          const int* __restrict__ indptr, int* __restrict__ cursor,
                          int* __restrict__ csr_src, float* __restrict__ csr_w) {
    int e = blockIdx.x * 256 + threadIdx.x;
    if (e >= N_EDGES) return;
    int src = ei[e];
    int dst = ei[N_EDGES + e];
    int pos = indptr[dst] + atomicAdd(&cursor[dst], 1);
    csr_src[pos] = src;
    csr_w[pos] = ew[e];
}

__global__ void k_deg(const int* __restrict__ indptr, const float* __restrict__ csr_w,
                      float* __restrict__ dis) {
    int i = blockIdx.x * 256 + threadIdx.x;
    if (i >= N_NODES) return;
    float d = 1.0f;
    int s = indptr[i], e = indptr[i + 1];
    for (int j = s; j < e; ++j) d += csr_w[j];
    dis[i] = (d > 0.f) ? rsqrtf(fmaxf(d, 1e-12f)) : 0.f;
}

// ---------------- merged weight + X conversion ----------------
constexpr int S0 = 192 * 288;    // BTG  (gate [Wfc1;Wfc2])
constexpr int S1 = 192 * 64;     // BTGCN
constexpr int S2 = 576 * 160;    // BT1
constexpr int S3 = 576 * 160;    // BT2
constexpr int S4 = 1024 * 160;   // BTS1 (W_g1)
constexpr int S5 = 128 * 1024;   // BTS2 (W_g2)
constexpr int S6 = N_NODES * 64; // X -> ABF
constexpr int SW_TOT = S0 + S1 + S2 + S3 + S4 + S5 + S6;

__global__ void k_cvtW(const float* __restrict__ Wfc1, const float* __restrict__ Wfc2,
                       const float* __restrict__ Wgcn, const float* __restrict__ Wgat1,
                       const float* __restrict__ Wgat2, const float* __restrict__ Wg1,
                       const float* __restrict__ Wg2, const float* __restrict__ X,
                       u16* __restrict__ BTG, u16* __restrict__ BTGCN,
                       u16* __restrict__ BT1, u16* __restrict__ BT2,
                       u16* __restrict__ BTS1, u16* __restrict__ BTS2,
                       u16* __restrict__ ABF) {
    int idx = blockIdx.x * 256 + threadIdx.x;
    if (idx < S0) {
        int n = idx / 288, k = idx - n * 288;
        u16 v = 0;
        if (n < HID) {
            if (k < HID) v = f2bf(Wfc1[(size_t)k * HID + n]);
            else if (k < 2 * HID) v = f2bf(Wfc2[(size_t)(k - HID) * HID + n]);
        }
        BTG[idx] = v;
        return;
    }
    idx -= S0;
    if (idx < S1) {
        int n = idx / 64, k = idx - n * 64;
        BTGCN[idx] = (k < F_IN && n < HID) ? f2bf(Wgcn[(size_t)k * HID + n]) : (u16)0;
        return;
    }
    idx -= S1;
    if (idx < S2) {
        int n = idx / 160, k = idx - n * 160;
        BT1[idx] = (k < HID && n < HID4) ? f2bf(Wgat1[(size_t)k * HID4 + n]) : (u16)0;
        return;
    }
    idx -= S2;
    if (idx < S3) {
        int n = idx / 160, k = idx - n * 160;
        BT2[idx] = (k < HID && n < HID4) ? f2bf(Wgat2[(size_t)k * HID4 + n]) : (u16)0;
        return;
    }
    idx -= S3;
    if (idx < S4) {
        int n = idx / 160, k = idx - n * 160;
        BTS1[idx] = (k < HID) ? f2bf(Wg1[(size_t)k * GFC + n]) : (u16)0;
        return;
    }
    idx -= S4;
    if (idx < S5) {
        int n = idx / 1024, k = idx - n * 1024;
        BTS2[idx] = f2bf(Wg2[(size_t)k * OUT_DIM + n]);
        return;
    }
    idx -= S5;
    if (idx < S6) {
        int r = idx / 64, k = idx - r * 64;
        ABF[idx] = (k < F_IN) ? f2bf(X[(size_t)r * F_IN + k]) : (u16)0;
    }
}

// ---------------- composite attention weights: BT rows 528..535 ----------------
// es^k = x1 . (W[:,k*132:..] @ a_src[k]) ; ed likewise. 2 layers x 8 cols x 160 k-len.
__global__ void k_wes(const float* __restrict__ W1, const float* __restrict__ as1,
                      const float* __restrict__ ad1, const float* __restrict__ W2,
                      const float* __restrict__ as2, const float* __restrict__ ad2,
                      u16* __restrict__ BT1, u16* __restrict__ BT2) {
    int idx = blockIdx.x * 256 + threadIdx.x;
    if (idx >= 2 * 8 * 160) return;
    int l = idx / 1280; idx -= l * 1280;
    int q = idx / 160;  int c = idx - q * 160;
    int k = q & 3;
    const float* W = l ? W2 : W1;
    const float* a = (q < 4) ? (l ? as2 : as1) : (l ? ad2 : ad1);
    float sum = 0.f;
    if (c < HID) {
        const float* wr = W + (size_t)c * HID4 + k * HID;
        const float* ar = a + k * HID;
        for (int cc = 0; cc < HID; ++cc) sum += wr[cc] * ar[cc];
    }
    u16* BT = l ? BT2 : BT1;
    BT[(size_t)(528 + q) * 160 + c] = f2bf(sum);
}

// ---------------- MFMA bf16 GEMM: out = A[*,Kp] @ Bt[Np,Kp]^T ----------------
// perm: cols<528 -> permuted bf16 [row][c2][head] into Cb; cols 528..535 -> fp32 into C (esd).
// Cb2: optional second bf16 copy at column offset coff2.
__global__ __launch_bounds__(256) void k_mfma_gemm(
    const u16* __restrict__ A, const u16* __restrict__ Bt,
    float* __restrict__ C, u16* __restrict__ Cb, int ldcb, int padN, int perm,
    u16* __restrict__ Cb2, int ldcb2, int coff2,
    int M, int N, int Kp,
    const float* __restrict__ bias, int relu, int gate,
    const float* __restrict__ b2, const float* __restrict__ pb,
    const float* __restrict__ xcg, const float* __restrict__ xpg) {
    const int bm = blockIdx.x * 64;
    const int bn = blockIdx.y * 64;
    const int w = threadIdx.x >> 6;
    const int lane = threadIdx.x & 63;
    const int m16 = lane & 15;
    const int quad = lane >> 4;
    const u16* Ab = A + (size_t)(bm + m16) * Kp + quad * 8;
    const u16* Bb = Bt + (size_t)(bn + w * 16 + m16) * Kp + quad * 8;
    f32x4 acc[4];
    #pragma unroll
    for (int r = 0; r < 4; ++r) acc[r] = (f32x4){0.f, 0.f, 0.f, 0.f};
    for (int k0 = 0; k0 < Kp; k0 += 32) {
        s8b b = *(const s8b*)(Bb + k0);
        s8b a0 = *(const s8b*)(Ab + k0);
        s8b a1 = *(const s8b*)(Ab + (size_t)16 * Kp + k0);
        s8b a2 = *(const s8b*)(Ab + (size_t)32 * Kp + k0);
        s8b a3 = *(const s8b*)(Ab + (size_t)48 * Kp + k0);
        acc[0] = __builtin_amdgcn_mfma_f32_16x16x32_bf16(a0, b, acc[0], 0, 0, 0);
        acc[1] = __builtin_amdgcn_mfma_f32_16x16x32_bf16(a1, b, acc[1], 0, 0, 0);
        acc[2] = __builtin_amdgcn_mfma_f32_16x16x32_bf16(a2, b, acc[2], 0, 0, 0);
        acc[3] = __builtin_amdgcn_mfma_f32_16x16x32_bf16(a3, b, acc[3], 0, 0, 0);
    }
    const int col = bn + w * 16 + m16;
    const bool colok = col < N;
    int pcol = 0;
    if (perm && col < HID4) {
        int kk = col / HID, cc = col - kk * HID;
        pcol = ((cc >> 1) << 3) + (kk << 1) + (cc & 1);
    }
    float bsum = 0.f;
    if (colok && !perm) {
        if (gate) bsum = bias[col] + b2[col] + pb[col];
        else if (bias) bsum = bias[col];
    }
    #pragma unroll
    for (int r = 0; r < 4; ++r) {
        #pragma unroll
        for (int j = 0; j < 4; ++j) {
            int row = bm + r * 16 + quad * 4 + j;
            if (row >= M) continue;
            if (colok) {
                float v = acc[r][j] + bsum;
                if (perm) {
                    if (col < HID4) Cb[(size_t)row * HID4 + pcol] = f2bf(v);
                    else            C[(size_t)row * 8 + (col - HID4)] = v;
                    continue;
                }
                float res;
                if (gate) {
                    float z = 1.f / (1.f + expf(-v));
                    size_t ix = (size_t)row * N + col;
                    res = z * xcg[ix] + (1.f - z) * xpg[ix];
                } else {
                    if (relu) v = fmaxf(v, 0.f);
                    res = v;
                }
                if (C) C[(size_t)row * N + col] = res;
                if (Cb) Cb[(size_t)row * ldcb + col] = f2bf(res);
                if (Cb2) Cb2[(size_t)row * ldcb2 + coff2 + col] = f2bf(res);
            } else if (Cb && !perm && col < padN) {
                Cb[(size_t)row * ldcb + col] = 0;
            }
        }
    }
}

// ---------------- GCN aggregate (bf16 gather, dual-write, 4 waves/block) ----
__global__ __launch_bounds__(256) void k_gcn_agg(
    const u16* __restrict__ hb, const int* __restrict__ indptr,
    const int* __restrict__ csr_src, const float* __restrict__ csr_w,
    const float* __restrict__ dis, const float* __restrict__ bias,
    float* __restrict__ x1, u16* __restrict__ abf, u16* __restrict__ abg) {
    const int w = threadIdx.x >> 6, t = threadIdx.x & 63;
    const int i = blockIdx.x * 4 + w;
    const float di = dis[i];
    const int s = indptr[i], e = indptr[i + 1];
    const float nself = di * di;
    const u32* ru = (const u32*)(hb + (size_t)i * HID);
    u32 wv = ru[t];
    float aLo = nself * bflo(wv), aHi = nself * bfhi(wv);
    float bLo = 0.f, bHi = 0.f;
    if (t < 2) { u32 w2 = ru[64 + t]; bLo = nself * bflo(w2); bHi = nself * bfhi(w2); }
    for (int j = s; j < e; ++j) {
        int src = csr_src[j];
        float nb = dis[src] * csr_w[j] * di;
        const u32* su = (const u32*)(hb + (size_t)src * HID);
        u32 ws = su[t];
        aLo += nb * bflo(ws);
        aHi += nb * bfhi(ws);
        if (t < 2) { u32 w2 = su[64 + t]; bLo += nb * bflo(w2); bHi += nb * bfhi(w2); }
    }
    float v0 = fmaxf(aLo + bias[2 * t], 0.f);
    float v1 = fmaxf(aHi + bias[2 * t + 1], 0.f);
    ((float2*)(x1 + (size_t)i * HID))[t] = make_float2(v0, v1);
    u32* fa = (u32*)(abf + (size_t)i * 160);
    u32* ga = (u32*)(abg + (size_t)i * 288);
    u32 p = pk2(v0, v1);
    fa[t] = p;
    ga[66 + t] = p;
    if (t < 2) {
        float v2 = fmaxf(bLo + bias[128 + 2 * t], 0.f);
        float v3 = fmaxf(bHi + bias[129 + 2 * t], 0.f);
        ((float2*)(x1 + (size_t)i * HID))[64 + t] = make_float2(v2, v3);
        u32 pk = pk2(v2, v3);
        fa[64 + t] = pk;
        ga[130 + t] = pk;
    }
    if (t >= 2 && t < 16) fa[64 + t] = 0;   // zero pad cols 132..159
}

// ---------------- GAT softmax + aggregate (4 waves/block, LDS alpha) --------
__global__ __launch_bounds__(256) void k_gat_node(
    const u16* __restrict__ hgb, const float* __restrict__ esd,
    const int* __restrict__ indptr, const int* __restrict__ csr_src,
    float* __restrict__ tmp, const float* __restrict__ bias,
    float* __restrict__ xcout, u16* __restrict__ abg, int do_relu) {
    __shared__ __align__(16) float al[4][CAP * 4];
    __shared__ int srcl[4][CAP];
    const int w = threadIdx.x >> 6, t = threadIdx.x & 63;
    const int i = blockIdx.x * 4 + w;
    const int k = t & 3;
    const int s = indptr[i];
    const int deg = indptr[i + 1] - s;
    const bool fast = (deg <= CAP);
    const float edk = esd[i * 8 + 4 + k];
    float eself = esd[i * 8 + k] + edk;
    eself = (eself >= 0.f) ? eself : 0.2f * eself;
    float m = eself;
    for (int j0 = 0; j0 < deg; j0 += 16) {
        int j = j0 + (t >> 2);
        float e = -1e30f;
        if (j < deg) {
            int src = csr_src[s + j];
            e = esd[src * 8 + k] + edk;
            e = (e >= 0.f) ? e : 0.2f * e;
            if (fast) { al[w][j * 4 + k] = e; if (k == 0) srcl[w][j] = src; }
            else tmp[(size_t)(s + j) * 4 + k] = e;
        }
        m = fmaxf(m, e);
    }
    m = fmaxf(m, __shfl_xor(m, 4));
    m = fmaxf(m, __shfl_xor(m, 8));
    m = fmaxf(m, __shfl_xor(m, 16));
    m = fmaxf(m, __shfl_xor(m, 32));
    float dsum = 0.f;
    for (int j0 = 0; j0 < deg; j0 += 16) {
        int j = j0 + (t >> 2);
        if (j < deg) {
            if (fast) {
                float ex = expf(al[w][j * 4 + k] - m);
                al[w][j * 4 + k] = ex;
                dsum += ex;
            } else {
                float ex = expf(tmp[(size_t)(s + j) * 4 + k] - m);
                tmp[(size_t)(s + j) * 4 + k] = ex;
                dsum += ex;
            }
        }
    }
    dsum += __shfl_xor(dsum, 4);
    dsum += __shfl_xor(dsum, 8);
    dsum += __shfl_xor(dsum, 16);
    dsum += __shfl_xor(dsum, 32);
    float exs = expf(eself - m);
    dsum += exs;
    float inv = 1.f / dsum;
    float aself = exs * inv;
    float a0 = __shfl(aself, 0), a1 = __shfl(aself, 1);
    float a2 = __shfl(aself, 2), a3 = __shfl(aself, 3);
    if (fast) {
        for (int idx = t; idx < deg * 4; idx += 64) al[w][idx] *= inv;  // idx&3 == k
    }
    // self contribution
    const uint4* ru = (const uint4*)(hgb + (size_t)i * HID4);
    float accLo, accHi, acc2Lo = 0.f, acc2Hi = 0.f;
    {
        uint4 v = ru[t];
        accLo = a0 * bflo(v.x) + a1 * bflo(v.y) + a2 * bflo(v.z) + a3 * bflo(v.w);
        accHi = a0 * bfhi(v.x) + a1 * bfhi(v.y) + a2 * bfhi(v.z) + a3 * bfhi(v.w);
        if (t < 2) {
            uint4 y = ru[64 + t];
            acc2Lo = a0 * bflo(y.x) + a1 * bflo(y.y) + a2 * bflo(y.z) + a3 * bflo(y.w);
            acc2Hi = a0 * bfhi(y.x) + a1 * bfhi(y.y) + a2 * bfhi(y.z) + a3 * bfhi(y.w);
        }
    }
    if (fast) {
        int j = 0;
        for (; j + 1 < deg; j += 2) {
            int s0 = srcl[w][j], s1 = srcl[w][j + 1];
            const uint4* su0 = (const uint4*)(hgb + (size_t)s0 * HID4);
            const uint4* su1 = (const uint4*)(hgb + (size_t)s1 * HID4);
            uint4 w0 = su0[t], w1 = su1[t];
            float4 x0 = *(const float4*)&al[w][j * 4];
            float4 x1v = *(const float4*)&al[w][j * 4 + 4];
            accLo += x0.x * bflo(w0.x) + x0.y * bflo(w0.y) + x0.z * bflo(w0.z) + x0.w * bflo(w0.w);
            accHi += x0.x * bfhi(w0.x) + x0.y * bfhi(w0.y) + x0.z * bfhi(w0.z) + x0.w * bfhi(w0.w);
            accLo += x1v.x * bflo(w1.x) + x1v.y * bflo(w1.y) + x1v.z * bflo(w1.z) + x1v.w * bflo(w1.w);
            accHi += x1v.x * bfhi(w1.x) + x1v.y * bfhi(w1.y) + x1v.z * bfhi(w1.z) + x1v.w * bfhi(w1.w);
            if (t < 2) {
                uint4 y0 = su0[64 + t], y1 = su1[64 + t];
                acc2Lo += x0.x * bflo(y0.x) + x0.y * bflo(y0.y) + x0.z * bflo(y0.z) + x0.w * bflo(y0.w);
                acc2Hi += x0.x * bfhi(y0.x) + x0.y * bfhi(y0.y) + x0.z * bfhi(y0.z) + x0.w * bfhi(y0.w);
                acc2Lo += x1v.x * bflo(y1.x) + x1v.y * bflo(y1.y) + x1v.z * bflo(y1.z) + x1v.w * bflo(y1.w);
                acc2Hi += x1v.x * bfhi(y1.x) + x1v.y * bfhi(y1.y) + x1v.z * bfhi(y1.z) + x1v.w * bfhi(y1.w);
            }
        }
        if (j < deg) {
            int s0 = srcl[w][j];
            const uint4* su0 = (const uint4*)(hgb + (size_t)s0 * HID4);
            uint4 w0 = su0[t];
            float4 x0 = *(const float4*)&al[w][j * 4];
            accLo += x0.x * bflo(w0.x) + x0.y * bflo(w0.y) + x0.z * bflo(w0.z) + x0.w * bflo(w0.w);
            accHi += x0.x * bfhi(w0.x) + x0.y * bfhi(w0.y) + x0.z * bfhi(w0.z) + x0.w * bfhi(w0.w);
            if (t < 2) {
                uint4 y0 = su0[64 + t];
                acc2Lo += x0.x * bflo(y0.x) + x0.y * bflo(y0.y) + x0.z * bflo(y0.z) + x0.w * bflo(y0.w);
                acc2Hi += x0.x * bfhi(y0.x) + x0.y * bfhi(y0.y) + x0.z * bfhi(y0.z) + x0.w * bfhi(y0.w);
            }
        }
    } else {
        float inv0 = __shfl(inv, 0), inv1 = __shfl(inv, 1);
        float inv2 = __shfl(inv, 2), inv3 = __shfl(inv, 3);
        const float4* tmp4 = (const float4*)tmp;
        for (int j = 0; j < deg; ++j) {
            int src = csr_src[s + j];
            float4 ax = tmp4[s + j];
            float b0 = ax.x * inv0, b1 = ax.y * inv1, b2 = ax.z * inv2, b3 = ax.w * inv3;
            const uint4* su = (const uint4*)(hgb + (size_t)src * HID4);
            uint4 wv = su[t];
            accLo += b0 * bflo(wv.x) + b1 * bflo(wv.y) + b2 * bflo(wv.z) + b3 * bflo(wv.w);
            accHi += b0 * bfhi(wv.x) + b1 * bfhi(wv.y) + b2 * bfhi(wv.z) + b3 * bfhi(wv.w);
            if (t < 2) {
                uint4 y = su[64 + t];
                acc2Lo += b0 * bflo(y.x) + b1 * bflo(y.y) + b2 * bflo(y.z) + b3 * bflo(y.w);
                acc2Hi += b0 * bfhi(y.x) + b1 * bfhi(y.y) + b2 * bfhi(y.z) + b3 * bfhi(y.w);
            }
        }
    }
    float v0 = accLo * 0.25f + bias[2 * t];
    float v1 = accHi * 0.25f + bias[2 * t + 1];
    if (do_relu) { v0 = fmaxf(v0, 0.f); v1 = fmaxf(v1, 0.f); }
    ((float2*)(xcout + (size_t)i * HID))[t] = make_float2(v0, v1);
    u32* ga = (u32*)(abg + (size_t)i * 288);
    ga[t] = pk2(v0, v1);
    if (t < 2) {
        float v2 = acc2Lo * 0.25f + bias[128 + 2 * t];
        float v3 = acc2Hi * 0.25f + bias[129 + 2 * t];
        if (do_relu) { v2 = fmaxf(v2, 0.f); v3 = fmaxf(v3, 0.f); }
        ((float2*)(xcout + (size_t)i * HID))[64 + t] = make_float2(v2, v3);
        ga[64 + t] = pk2(v2, v3);
    }
}

// ---------------- pooling: analytic per-graph max, no atomics ----------------
__global__ __launch_bounds__(256) void k_pool(const float* __restrict__ x3,
                                              u16* __restrict__ gb) {
    __shared__ float sm[4][132];
    const int g = blockIdx.x;
    const int tid = threadIdx.x, t = tid & 63, w = tid >> 6;
    const int n0 = (g * N_NODES + GRAPHS - 1) / GRAPHS;
    const int n1 = ((g + 1) * N_NODES + GRAPHS - 1) / GRAPHS;
    float m0 = -3.4e38f, m1 = -3.4e38f, m2 = -3.4e38f, m3 = -3.4e38f;
    for (int n = n0 + w; n < n1; n += 4) {
        const float2* r = (const float2*)(x3 + (size_t)n * HID);
        float2 v = r[t];
        m0 = fmaxf(m0, v.x); m1 = fmaxf(m1, v.y);
        if (t < 2) { float2 u = r[64 + t]; m2 = fmaxf(m2, u.x); m3 = fmaxf(m3, u.y); }
    }
    sm[w][2 * t] = m0; sm[w][2 * t + 1] = m1;
    if (t < 2) { sm[w][128 + 2 * t] = m2; sm[w][129 + 2 * t] = m3; }
    __syncthreads();
    if (w == 0) {
        float a0 = fmaxf(fmaxf(sm[0][2*t], sm[1][2*t]), fmaxf(sm[2][2*t], sm[3][2*t]));
        float a1 = fmaxf(fmaxf(sm[0][2*t+1], sm[1][2*t+1]), fmaxf(sm[2][2*t+1], sm[3][2*t+1]));
        u32* fa = (u32*)(gb + (size_t)g * 160);
        fa[t] = pk2(a0, a1);
        if (t < 2) {
            float a2 = fmaxf(fmaxf(sm[0][128+2*t], sm[1][128+2*t]), fmaxf(sm[2][128+2*t], sm[3][128+2*t]));
            float a3 = fmaxf(fmaxf(sm[0][129+2*t], sm[1][129+2*t]), fmaxf(sm[2][129+2*t], sm[3][129+2*t]));
            fa[64 + t] = pk2(a2, a3);
        }
        if (t >= 2 && t < 16) fa[64 + t] = 0;
    }
}

// ---------------- launch ----------------
extern "C" void kernel_launch(void* const* d_in, const int* in_sizes, int n_in,
                              void* d_out, int out_size, void* d_ws, size_t ws_size,
                              hipStream_t stream) {
    const float* X       = (const float*)d_in[0];
    const int*   EI      = (const int*)d_in[1];
    const float* EW      = (const float*)d_in[2];
    const float* W_gcn   = (const float*)d_in[4];
    const float* b_gcn   = (const float*)d_in[5];
    const float* W_gat1  = (const float*)d_in[6];
    const float* a_src1  = (const float*)d_in[7];
    const float* a_dst1  = (const float*)d_in[8];
    const float* b_gat1  = (const float*)d_in[9];
    const float* W_gat2  = (const float*)d_in[10];
    const float* a_src2  = (const float*)d_in[11];
    const float* a_dst2  = (const float*)d_in[12];
    const float* b_gat2  = (const float*)d_in[13];
    const float* W_fc1   = (const float*)d_in[14];
    const float* b_fc1   = (const float*)d_in[15];
    const float* W_fc2   = (const float*)d_in[16];
    const float* b_fc2   = (const float*)d_in[17];
    const float* pro_bias= (const float*)d_in[18];
    const float* W_g1    = (const float*)d_in[19];
    const float* b_g1    = (const float*)d_in[20];
    const float* W_g2    = (const float*)d_in[21];
    const float* b_g2    = (const float*)d_in[22];
    float* OUT = (float*)d_out;

    float* ws = (float*)d_ws;
    float*    dis     = ws + O_DIS;
    int*      counts  = (int*)(ws + O_CNT);
    int*      indptr  = (int*)(ws + O_IDP);
    int*      csr_src = (int*)(ws + O_CSR_S);
    float*    csr_w   = ws + O_CSR_W;
    float*    esd     = ws + O_ESD;
    float*    tmp     = ws + O_TMP;
    float*    x1      = ws + O_X1;
    float*    x2      = ws + O_X2;
    float*    xc      = ws + O_XC;
    u16*      U       = (u16*)(ws + O_U);
    u16*      hb      = U + U_HB;
    u16*      hgb     = U + U_HGB;
    u16*      ABF     = U + U_ABF;
    u16*      ABG     = U + U_ABG;
    u16*      BTG     = U + U_BTG;
    u16*      BTGCN   = U + U_BTGCN;
    u16*      BT1     = U + U_BT1;
    u16*      BT2     = U + U_BT2;
    u16*      BTS1    = U + U_BTS1;
    u16*      BTS2    = U + U_BTS2;
    u16*      GB      = U + U_GB;
    u16*      GHB     = U + U_GHB;
    float*    x3      = x1;

    const int EB = (N_EDGES + 255) / 256;
    const int NB = (N_NODES + 255) / 256;
    const int NB4 = N_NODES / 4;   // 7500, exact

    // ---- CSR build ----
    hipMemsetAsync(counts, 0, N_NODES * sizeof(int), stream);
    k_count<<<EB, 256, 0, stream>>>(EI, counts);
    k_scan<<<1, 1024, 0, stream>>>(counts, indptr);
    hipMemsetAsync(counts, 0, N_NODES * sizeof(int), stream);
    k_scatter<<<EB, 256, 0, stream>>>(EI, EW, indptr, counts, csr_src, csr_w);
    k_deg<<<NB, 256, 0, stream>>>(indptr, csr_w, dis);

    // ---- all weight + X conversions ----
    k_cvtW<<<(SW_TOT + 255) / 256, 256, 0, stream>>>(
        W_fc1, W_fc2, W_gcn, W_gat1, W_gat2, W_g1, W_g2, X,
        BTG, BTGCN, BT1, BT2, BTS1, BTS2, ABF);
    k_wes<<<10, 256, 0, stream>>>(W_gat1, a_src1, a_dst1, W_gat2, a_src2, a_dst2, BT1, BT2);

    // ---- GCN ----
    {
        dim3 grid(MP / 64, 3);
        k_mfma_gemm<<<grid, 256, 0, stream>>>(ABF, BTGCN, nullptr, hb, HID, HID, 0,
                                              nullptr, 0, 0, N_NODES, HID, 64,
                                              nullptr, 0, 0, nullptr, nullptr, nullptr, nullptr);
    }
    k_gcn_agg<<<NB4, 256, 0, stream>>>(hb, indptr, csr_src, csr_w, dis, b_gcn,
                                       x1, ABF, ABG);

    // ---- GAT layer 1 (GEMM also emits es/ed via composite cols 528..535) ----
    {
        dim3 grid(MP / 64, 9);
        k_mfma_gemm<<<grid, 256, 0, stream>>>(ABF, BT1, esd, hgb, 0, 0, 1,
                                              nullptr, 0, 0, N_NODES, 536, 160,
                                              nullptr, 0, 0, nullptr, nullptr, nullptr, nullptr);
    }
    k_gat_node<<<NB4, 256, 0, stream>>>(hgb, esd, indptr, csr_src, tmp, b_gat1,
                                        xc, ABG, 1);
    // gate 1: x2 fp32 + bf16 into ABF (GAT2 A) + bf16 into ABG cols 132.. (gate2 xp)
    {
        dim3 grid(MP / 64, 3);
        k_mfma_gemm<<<grid, 256, 0, stream>>>(ABG, BTG, x2, ABF, 160, 160, 0,
                                              ABG, 288, 132, N_NODES, HID, 288,
                                              b_fc1, 0, 1, b_fc2, pro_bias, xc, x1);
    }

    // ---- GAT layer 2 ----
    {
        dim3 grid(MP / 64, 9);
        k_mfma_gemm<<<grid, 256, 0, stream>>>(ABF, BT2, esd, hgb, 0, 0, 1,
                                              nullptr, 0, 0, N_NODES, 536, 160,
                                              nullptr, 0, 0, nullptr, nullptr, nullptr, nullptr);
    }
    k_gat_node<<<NB4, 256, 0, stream>>>(hgb, esd, indptr, csr_src, tmp, b_gat2,
                                        xc, ABG, 0);
    // gate 2: x3 fp32 only
    {
        dim3 grid(MP / 64, 3);
        k_mfma_gemm<<<grid, 256, 0, stream>>>(ABG, BTG, x3, nullptr, 0, 0, 0,
                                              nullptr, 0, 0, N_NODES, HID, 288,
                                              b_fc1, 0, 1, b_fc2, pro_bias, xc, x2);
    }

    // ---- pool + head (all MFMA) ----
    k_pool<<<GRAPHS, 256, 0, stream>>>(x3, GB);
    {
        dim3 grid(1, 16);
        k_mfma_gemm<<<grid, 256, 0, stream>>>(GB, BTS1, nullptr, GHB, GFC, GFC, 0,
                                              nullptr, 0, 0, GRAPHS, GFC, 160,
                                              b_g1, 1, 0, nullptr, nullptr, nullptr, nullptr);
    }
    {
        dim3 grid(1, 2);
        k_mfma_gemm<<<grid, 256, 0, stream>>>(GHB, BTS2, OUT, nullptr, 0, 0, 0,
                                              nullptr, 0, 0, GRAPHS, OUT_DIM, 1024,
                                              b_g2, 0, 0, nullptr, nullptr, nullptr, nullptr);
    }
}

// Round 7
// 538.382 us; speedup vs baseline: 1.9235x; 1.0950x over previous
//
#include <hip/hip_runtime.h>

// ---------------- problem constants ----------------
constexpr int N_NODES = 30000;
constexpr int N_EDGES = 300000;
constexpr int GRAPHS  = 64;
constexpr int F_IN    = 33;
constexpr int HID     = 132;
constexpr int HEADS   = 4;
constexpr int HID4    = HEADS * HID;   // 528
constexpr int OUT_DIM = 128;
constexpr int GFC     = 1024;
constexpr int MP      = 30016;         // N_NODES padded to x64
constexpr int CAP     = 128;           // max in-degree on LDS fast path
constexpr int NBLK    = 118;           // ceil(N_NODES/256)

typedef unsigned int u32;
typedef unsigned short u16;

// ---------------- workspace layout (float units, 64-float aligned) ----------------
constexpr size_t rnd64(size_t x) { return (x + 63) & ~(size_t)63; }
constexpr size_t O_DIS   = 0;
constexpr size_t O_CNT   = O_DIS   + rnd64(N_NODES);                 // int
constexpr size_t O_WDEG  = O_CNT   + rnd64(N_NODES);                 // float (memset with CNT)
constexpr size_t O_IDP   = O_WDEG  + rnd64(N_NODES);                 // int, N+1
constexpr size_t O_BSUM  = O_IDP   + rnd64(N_NODES + 1);             // int, 128
constexpr size_t O_BOFF  = O_BSUM  + rnd64(128);                     // int, 128
constexpr size_t O_CSR_S = O_BOFF  + rnd64(128);                     // int, E
constexpr size_t O_CSR_W = O_CSR_S + rnd64(N_EDGES);                 // float, E
constexpr size_t O_ESD   = O_CSR_W + rnd64(N_EDGES);                 // float, N*8
constexpr size_t O_TMP   = O_ESD   + rnd64((size_t)N_NODES * 8);     // float, E*4 (fallback)
constexpr size_t O_X3    = O_TMP   + rnd64((size_t)N_EDGES * 4);     // float, N*HID
// u16 region
constexpr size_t O_U     = O_X3    + rnd64((size_t)N_NODES * HID);
constexpr size_t U_HB    = 0;                                        // [N,132]
constexpr size_t U_HGB   = U_HB   + rnd64((size_t)N_NODES * HID);    // [N,528] permuted
constexpr size_t U_ABF   = U_HGB  + rnd64((size_t)N_NODES * HID4);   // [MP,160]
constexpr size_t U_ABG   = U_ABF  + rnd64((size_t)MP * 160);         // [MP,288]
constexpr size_t U_BTG   = U_ABG  + rnd64((size_t)MP * 288);         // [192,288]
constexpr size_t U_BTGCN = U_BTG  + rnd64(192 * 288);                // [192,64]
constexpr size_t U_BT1   = U_BTGCN+ rnd64(192 * 64);                 // [576,160]
constexpr size_t U_BT2   = U_BT1  + rnd64(576 * 160);                // [576,160]
constexpr size_t U_BTS1  = U_BT2  + rnd64(576 * 160);                // [1024,160]
constexpr size_t U_BTS2  = U_BTS1 + rnd64(1024 * 160);               // [128,1024]

// ---------------- bf16 helpers ----------------
__device__ inline u16 f2bf(float f) {
    u32 u = __float_as_uint(f);
    return (u16)((u + 0x7fffu + ((u >> 16) & 1u)) >> 16);
}
__device__ inline u32 pk2(float a, float b) { return (u32)f2bf(a) | ((u32)f2bf(b) << 16); }
__device__ inline float bflo(u32 w) { return __uint_as_float(w << 16); }
__device__ inline float bfhi(u32 w) { return __uint_as_float(w & 0xffff0000u); }
__device__ inline float bf1(u16 x) { return __uint_as_float((u32)x << 16); }

typedef __attribute__((ext_vector_type(8))) short s8b;
typedef __attribute__((ext_vector_type(4))) float f32x4;

// ---------------- CSR build ----------------
__global__ void k_count(const int* __restrict__ ei, const float* __restrict__ ew,
                        int* __restrict__ counts, float* __restrict__ wdeg) {
    int e = blockIdx.x * 256 + threadIdx.x;
    if (e < N_EDGES) {
        int dst = ei[N_EDGES + e];
        atomicAdd(&counts[dst], 1);
        atomicAdd(&wdeg[dst], ew[e]);
    }
}

__global__ __launch_bounds__(256) void k_bsum(const int* __restrict__ counts,
                                              const float* __restrict__ wdeg,
                                              int* __restrict__ bsum,
                                              float* __restrict__ dis) {
    int i = blockIdx.x * 256 + threadIdx.x;
    int v = (i < N_NODES) ? counts[i] : 0;
    if (i < N_NODES) {
        float d = 1.f + wdeg[i];
        dis[i] = (d > 0.f) ? rsqrtf(fmaxf(d, 1e-12f)) : 0.f;
    }
    int x = v;
    #pragma unroll
    for (int off = 1; off < 64; off <<= 1) x += __shfl_xor(x, off);
    __shared__ int ws4[4];
    if ((threadIdx.x & 63) == 0) ws4[threadIdx.x >> 6] = x;
    __syncthreads();
    if (threadIdx.x == 0) bsum[blockIdx.x] = ws4[0] + ws4[1] + ws4[2] + ws4[3];
}

__global__ __launch_bounds__(64) void k_scan2(const int* __restrict__ bsum,
                                              int* __restrict__ boff) {
    int t = threadIdx.x;
    int a = (2 * t < NBLK) ? bsum[2 * t] : 0;
    int b = (2 * t + 1 < NBLK) ? bsum[2 * t + 1] : 0;
    int loc = a + b, x = loc;
    #pragma unroll
    for (int off = 1; off < 64; off <<= 1) {
        int y = __shfl_up(x, off);
        if (t >= off) x += y;
    }
    int excl = x - loc;
    if (2 * t < NBLK) boff[2 * t] = excl;
    if (2 * t + 1 < NBLK) boff[2 * t + 1] = excl + a;
}

__global__ __launch_bounds__(256) void k_apply(int* __restrict__ counts,
                                               const int* __restrict__ boff,
                                               int* __restrict__ indptr) {
    int b = blockIdx.x;
    int i = b * 256 + threadIdx.x;
    int v = (i < N_NODES) ? counts[i] : 0;
    const int lane = threadIdx.x & 63, w = threadIdx.x >> 6;
    int x = v;
    #pragma unroll
    for (int off = 1; off < 64; off <<= 1) {
        int y = __shfl_up(x, off);
        if (lane >= off) x += y;
    }
    __shared__ int wsum[4];
    if (lane == 63) wsum[w] = x;
    __syncthreads();
    int add = boff[b];
    for (int k2 = 0; k2 < w; ++k2) add += wsum[k2];
    if (i < N_NODES) {
        indptr[i] = add + x - v;
        counts[i] = 0;   // becomes scatter cursor
    }
    if (i == N_NODES) indptr[N_NODES] = N_EDGES;
}

__global__ void k_scatter(const int* __restrict__ ei, const float* __restrict__ ew,
                          const int* __restrict__ indptr, int* __restrict__ cursor,
                          int* __restrict__ csr_src, float* __restrict__ csr_w) {
    int e = blockIdx.x * 256 + threadIdx.x;
    if (e >= N_EDGES) return;
    int src = ei[e];
    int dst = ei[N_EDGES + e];
    int pos = indptr[dst] + atomicAdd(&cursor[dst], 1);
    csr_src[pos] = src;
    csr_w[pos] = ew[e];
}

// ---------------- merged weight + X + composite-es conversion ----------------
constexpr int S0 = 192 * 288;    // BTG
constexpr int S1 = 192 * 64;     // BTGCN
constexpr int S2 = 576 * 160;    // BT1
constexpr int S3 = 576 * 160;    // BT2
constexpr int S4 = 1024 * 160;   // BTS1
constexpr int S5 = 128 * 1024;   // BTS2
constexpr int S6 = N_NODES * 64; // X -> ABF
constexpr int S7 = 2 * 8 * 160;  // wes composite rows
constexpr int SW_TOT = S0 + S1 + S2 + S3 + S4 + S5 + S6 + S7;

__global__ void k_cvtW(const float* __restrict__ Wfc1, const float* __restrict__ Wfc2,
                       const float* __restrict__ Wgcn, const float* __restrict__ Wgat1,
                       const float* __restrict__ Wgat2, const float* __restrict__ Wg1,
                       const float* __restrict__ Wg2, const float* __restrict__ X,
                       const float* __restrict__ as1, const float* __restrict__ ad1,
                       const float* __restrict__ as2, const float* __restrict__ ad2,
                       u16* __restrict__ BTG, u16* __restrict__ BTGCN,
                       u16* __restrict__ BT1, u16* __restrict__ BT2,
                       u16* __restrict__ BTS1, u16* __restrict__ BTS2,
                       u16* __restrict__ ABF) {
    int idx = blockIdx.x * 256 + threadIdx.x;
    if (idx < S0) {
        int n = idx / 288, k = idx - n * 288;
        u16 v = 0;
        if (n < HID) {
            if (k < HID) v = f2bf(Wfc1[(size_t)k * HID + n]);
            else if (k < 2 * HID) v = f2bf(Wfc2[(size_t)(k - HID) * HID + n]);
        }
        BTG[idx] = v;
        return;
    }
    idx -= S0;
    if (idx < S1) {
        int n = idx / 64, k = idx - n * 64;
        BTGCN[idx] = (k < F_IN && n < HID) ? f2bf(Wgcn[(size_t)k * HID + n]) : (u16)0;
        return;
    }
    idx -= S1;
    if (idx < S2) {
        int n = idx / 160, k = idx - n * 160;
        BT1[idx] = (k < HID && n < HID4) ? f2bf(Wgat1[(size_t)k * HID4 + n]) : (u16)0;
        return;
    }
    idx -= S2;
    if (idx < S3) {
        int n = idx / 160, k = idx - n * 160;
        BT2[idx] = (k < HID && n < HID4) ? f2bf(Wgat2[(size_t)k * HID4 + n]) : (u16)0;
        return;
    }
    idx -= S3;
    if (idx < S4) {
        int n = idx / 160, k = idx - n * 160;
        BTS1[idx] = (k < HID) ? f2bf(Wg1[(size_t)k * GFC + n]) : (u16)0;
        return;
    }
    idx -= S4;
    if (idx < S5) {
        int n = idx / 1024, k = idx - n * 1024;
        BTS2[idx] = f2bf(Wg2[(size_t)k * OUT_DIM + n]);
        return;
    }
    idx -= S5;
    if (idx < S6) {
        int r = idx / 64, k = idx - r * 64;
        ABF[idx] = (k < F_IN) ? f2bf(X[(size_t)r * F_IN + k]) : (u16)0;
        return;
    }
    idx -= S6;
    if (idx < S7) {
        int l = idx / 1280; idx -= l * 1280;
        int q = idx / 160;  int c = idx - q * 160;
        int k = q & 3;
        const float* W = l ? Wgat2 : Wgat1;
        const float* a = (q < 4) ? (l ? as2 : as1) : (l ? ad2 : ad1);
        float sum = 0.f;
        if (c < HID) {
            const float* wr = W + (size_t)c * HID4 + k * HID;
            const float* ar = a + k * HID;
            for (int cc = 0; cc < HID; ++cc) sum += wr[cc] * ar[cc];
        }
        u16* BT = l ? BT2 : BT1;
        BT[(size_t)(528 + q) * 160 + c] = f2bf(sum);
    }
}

// ---------------- MFMA bf16 GEMM: out = A[*,Kp] @ Bt[Np,Kp]^T ----------------
// perm: cols<528 -> permuted bf16 [row][c2][head] into Cb; cols 528..535 -> fp32 C (esd).
// gate: z=sigmoid(acc+biases); res = z*bf(A[row][col]) + (1-z)*bf(A[row][132+col]).
__global__ __launch_bounds__(256) void k_mfma_gemm(
    const u16* __restrict__ A, const u16* __restrict__ Bt,
    float* __restrict__ C, u16* __restrict__ Cb, int ldcb, int padN, int perm,
    u16* __restrict__ Cb2, int ldcb2, int coff2,
    int M, int N, int Kp,
    const float* __restrict__ bias, int relu, int gate,
    const float* __restrict__ b2, const float* __restrict__ pb) {
    const int bm = blockIdx.x * 64;
    const int bn = blockIdx.y * 64;
    const int w = threadIdx.x >> 6;
    const int lane = threadIdx.x & 63;
    const int m16 = lane & 15;
    const int quad = lane >> 4;
    const u16* Ab = A + (size_t)(bm + m16) * Kp + quad * 8;
    const u16* Bb = Bt + (size_t)(bn + w * 16 + m16) * Kp + quad * 8;
    f32x4 acc[4];
    #pragma unroll
    for (int r = 0; r < 4; ++r) acc[r] = (f32x4){0.f, 0.f, 0.f, 0.f};
    for (int k0 = 0; k0 < Kp; k0 += 32) {
        s8b b = *(const s8b*)(Bb + k0);
        s8b a0 = *(const s8b*)(Ab + k0);
        s8b a1 = *(const s8b*)(Ab + (size_t)16 * Kp + k0);
        s8b a2 = *(const s8b*)(Ab + (size_t)32 * Kp + k0);
        s8b a3 = *(const s8b*)(Ab + (size_t)48 * Kp + k0);
        acc[0] = __builtin_amdgcn_mfma_f32_16x16x32_bf16(a0, b, acc[0], 0, 0, 0);
        acc[1] = __builtin_amdgcn_mfma_f32_16x16x32_bf16(a1, b, acc[1], 0, 0, 0);
        acc[2] = __builtin_amdgcn_mfma_f32_16x16x32_bf16(a2, b, acc[2], 0, 0, 0);
        acc[3] = __builtin_amdgcn_mfma_f32_16x16x32_bf16(a3, b, acc[3], 0, 0, 0);
    }
    const int col = bn + w * 16 + m16;
    const bool colok = col < N;
    int pcol = 0;
    if (perm && col < HID4) {
        int kk = col / HID, cc = col - kk * HID;
        pcol = ((cc >> 1) << 3) + (kk << 1) + (cc & 1);
    }
    float bsum = 0.f;
    if (colok && !perm) {
        if (gate) bsum = bias[col] + b2[col] + pb[col];
        else if (bias) bsum = bias[col];
    }
    #pragma unroll
    for (int r = 0; r < 4; ++r) {
        #pragma unroll
        for (int j = 0; j < 4; ++j) {
            int row = bm + r * 16 + quad * 4 + j;
            if (row >= M) continue;
            if (colok) {
                float v = acc[r][j] + bsum;
                if (perm) {
                    if (col < HID4) Cb[(size_t)row * HID4 + pcol] = f2bf(v);
                    else            C[(size_t)row * 8 + (col - HID4)] = v;
                    continue;
                }
                float res;
                if (gate) {
                    float z = 1.f / (1.f + expf(-v));
                    float xcv = bf1(A[(size_t)row * Kp + col]);
                    float xpv = bf1(A[(size_t)row * Kp + 132 + col]);
                    res = z * xcv + (1.f - z) * xpv;
                } else {
                    if (relu) v = fmaxf(v, 0.f);
                    res = v;
                }
                if (C) C[(size_t)row * N + col] = res;
                if (Cb) Cb[(size_t)row * ldcb + col] = f2bf(res);
                if (Cb2) Cb2[(size_t)row * ldcb2 + coff2 + col] = f2bf(res);
            } else if (Cb && !perm && col < padN) {
                Cb[(size_t)row * ldcb + col] = 0;
            }
        }
    }
}

// ---------------- GCN aggregate (bf16 gather, unroll-4, bf16-only output) ----
__global__ __launch_bounds__(256) void k_gcn_agg(
    const u16* __restrict__ hb, const int* __restrict__ indptr,
    const int* __restrict__ csr_src, const float* __restrict__ csr_w,
    const float* __restrict__ dis, const float* __restrict__ bias,
    u16* __restrict__ abf, u16* __restrict__ abg) {
    const int w = threadIdx.x >> 6, t = threadIdx.x & 63;
    const int i = blockIdx.x * 4 + w;
    const float di = dis[i];
    const int s = indptr[i], e = indptr[i + 1];
    const float nself = di * di;
    const u32* ru = (const u32*)(hb + (size_t)i * HID);
    u32 wv = ru[t];
    float aLo = nself * bflo(wv), aHi = nself * bfhi(wv);
    float bLo = 0.f, bHi = 0.f;
    if (t < 2) { u32 w2 = ru[64 + t]; bLo = nself * bflo(w2); bHi = nself * bfhi(w2); }
    int j = s;
    for (; j + 3 < e; j += 4) {
        int s0 = csr_src[j], s1 = csr_src[j + 1], s2 = csr_src[j + 2], s3 = csr_src[j + 3];
        float n0 = dis[s0] * csr_w[j]     * di;
        float n1 = dis[s1] * csr_w[j + 1] * di;
        float n2 = dis[s2] * csr_w[j + 2] * di;
        float n3 = dis[s3] * csr_w[j + 3] * di;
        const u32* p0 = (const u32*)(hb + (size_t)s0 * HID);
        const u32* p1 = (const u32*)(hb + (size_t)s1 * HID);
        const u32* p2 = (const u32*)(hb + (size_t)s2 * HID);
        const u32* p3 = (const u32*)(hb + (size_t)s3 * HID);
        u32 w0 = p0[t], w1 = p1[t], w2 = p2[t], w3 = p3[t];
        aLo += n0 * bflo(w0) + n1 * bflo(w1) + n2 * bflo(w2) + n3 * bflo(w3);
        aHi += n0 * bfhi(w0) + n1 * bfhi(w1) + n2 * bfhi(w2) + n3 * bfhi(w3);
        if (t < 2) {
            u32 y0 = p0[64 + t], y1 = p1[64 + t], y2 = p2[64 + t], y3 = p3[64 + t];
            bLo += n0 * bflo(y0) + n1 * bflo(y1) + n2 * bflo(y2) + n3 * bflo(y3);
            bHi += n0 * bfhi(y0) + n1 * bfhi(y1) + n2 * bfhi(y2) + n3 * bfhi(y3);
        }
    }
    for (; j < e; ++j) {
        int src = csr_src[j];
        float nb = dis[src] * csr_w[j] * di;
        const u32* su = (const u32*)(hb + (size_t)src * HID);
        u32 ws = su[t];
        aLo += nb * bflo(ws);
        aHi += nb * bfhi(ws);
        if (t < 2) { u32 w2 = su[64 + t]; bLo += nb * bflo(w2); bHi += nb * bfhi(w2); }
    }
    float v0 = fmaxf(aLo + bias[2 * t], 0.f);
    float v1 = fmaxf(aHi + bias[2 * t + 1], 0.f);
    u32* fa = (u32*)(abf + (size_t)i * 160);
    u32* ga = (u32*)(abg + (size_t)i * 288);
    u32 p = pk2(v0, v1);
    fa[t] = p;
    ga[66 + t] = p;
    if (t < 2) {
        float v2 = fmaxf(bLo + bias[128 + 2 * t], 0.f);
        float v3 = fmaxf(bHi + bias[129 + 2 * t], 0.f);
        u32 pk = pk2(v2, v3);
        fa[64 + t] = pk;
        ga[130 + t] = pk;
    }
    if (t >= 2 && t < 16) fa[64 + t] = 0;
}

// ---------------- GAT softmax + aggregate (unroll-4 gather, bf16-only out) ---
__global__ __launch_bounds__(256) void k_gat_node(
    const u16* __restrict__ hgb, const float* __restrict__ esd,
    const int* __restrict__ indptr, const int* __restrict__ csr_src,
    float* __restrict__ tmp, const float* __restrict__ bias,
    u16* __restrict__ abg, int do_relu) {
    __shared__ __align__(16) float al[4][CAP * 4];
    __shared__ int srcl[4][CAP];
    const int w = threadIdx.x >> 6, t = threadIdx.x & 63;
    const int i = blockIdx.x * 4 + w;
    const int k = t & 3;
    const int s = indptr[i];
    const int deg = indptr[i + 1] - s;
    const bool fast = (deg <= CAP);
    const float edk = esd[i * 8 + 4 + k];
    float eself = esd[i * 8 + k] + edk;
    eself = (eself >= 0.f) ? eself : 0.2f * eself;
    float m = eself;
    for (int j0 = 0; j0 < deg; j0 += 16) {
        int j = j0 + (t >> 2);
        float e = -1e30f;
        if (j < deg) {
            int src = csr_src[s + j];
            e = esd[src * 8 + k] + edk;
            e = (e >= 0.f) ? e : 0.2f * e;
            if (fast) { al[w][j * 4 + k] = e; if (k == 0) srcl[w][j] = src; }
            else tmp[(size_t)(s + j) * 4 + k] = e;
        }
        m = fmaxf(m, e);
    }
    m = fmaxf(m, __shfl_xor(m, 4));
    m = fmaxf(m, __shfl_xor(m, 8));
    m = fmaxf(m, __shfl_xor(m, 16));
    m = fmaxf(m, __shfl_xor(m, 32));
    float dsum = 0.f;
    for (int j0 = 0; j0 < deg; j0 += 16) {
        int j = j0 + (t >> 2);
        if (j < deg) {
            if (fast) {
                float ex = expf(al[w][j * 4 + k] - m);
                al[w][j * 4 + k] = ex;
                dsum += ex;
            } else {
                float ex = expf(tmp[(size_t)(s + j) * 4 + k] - m);
                tmp[(size_t)(s + j) * 4 + k] = ex;
                dsum += ex;
            }
        }
    }
    dsum += __shfl_xor(dsum, 4);
    dsum += __shfl_xor(dsum, 8);
    dsum += __shfl_xor(dsum, 16);
    dsum += __shfl_xor(dsum, 32);
    float exs = expf(eself - m);
    dsum += exs;
    float inv = 1.f / dsum;
    float aself = exs * inv;
    float a0 = __shfl(aself, 0), a1 = __shfl(aself, 1);
    float a2 = __shfl(aself, 2), a3 = __shfl(aself, 3);
    if (fast) {
        for (int idx = t; idx < deg * 4; idx += 64) al[w][idx] *= inv;
    }
    const uint4* ru = (const uint4*)(hgb + (size_t)i * HID4);
    float accLo, accHi, acc2Lo = 0.f, acc2Hi = 0.f;
    {
        uint4 v = ru[t];
        accLo = a0 * bflo(v.x) + a1 * bflo(v.y) + a2 * bflo(v.z) + a3 * bflo(v.w);
        accHi = a0 * bfhi(v.x) + a1 * bfhi(v.y) + a2 * bfhi(v.z) + a3 * bfhi(v.w);
        if (t < 2) {
            uint4 y = ru[64 + t];
            acc2Lo = a0 * bflo(y.x) + a1 * bflo(y.y) + a2 * bflo(y.z) + a3 * bflo(y.w);
            acc2Hi = a0 * bfhi(y.x) + a1 * bfhi(y.y) + a2 * bfhi(y.z) + a3 * bfhi(y.w);
        }
    }
    if (fast) {
        int j = 0;
        for (; j + 3 < deg; j += 4) {
            int s0 = srcl[w][j], s1 = srcl[w][j + 1], s2 = srcl[w][j + 2], s3 = srcl[w][j + 3];
            const uint4* p0 = (const uint4*)(hgb + (size_t)s0 * HID4);
            const uint4* p1 = (const uint4*)(hgb + (size_t)s1 * HID4);
            const uint4* p2 = (const uint4*)(hgb + (size_t)s2 * HID4);
            const uint4* p3 = (const uint4*)(hgb + (size_t)s3 * HID4);
            uint4 w0 = p0[t], w1 = p1[t], w2 = p2[t], w3 = p3[t];
            float4 x0 = *(const float4*)&al[w][j * 4];
            float4 x1 = *(const float4*)&al[w][j * 4 + 4];
            float4 x2 = *(const float4*)&al[w][j * 4 + 8];
            float4 x3 = *(const float4*)&al[w][j * 4 + 12];
            accLo += x0.x * bflo(w0.x) + x0.y * bflo(w0.y) + x0.z * bflo(w0.z) + x0.w * bflo(w0.w);
            accHi += x0.x * bfhi(w0.x) + x0.y * bfhi(w0.y) + x0.z * bfhi(w0.z) + x0.w * bfhi(w0.w);
            accLo += x1.x * bflo(w1.x) + x1.y * bflo(w1.y) + x1.z * bflo(w1.z) + x1.w * bflo(w1.w);
            accHi += x1.x * bfhi(w1.x) + x1.y * bfhi(w1.y) + x1.z * bfhi(w1.z) + x1.w * bfhi(w1.w);
            accLo += x2.x * bflo(w2.x) + x2.y * bflo(w2.y) + x2.z * bflo(w2.z) + x2.w * bflo(w2.w);
            accHi += x2.x * bfhi(w2.x) + x2.y * bfhi(w2.y) + x2.z * bfhi(w2.z) + x2.w * bfhi(w2.w);
            accLo += x3.x * bflo(w3.x) + x3.y * bflo(w3.y) + x3.z * bflo(w3.z) + x3.w * bflo(w3.w);
            accHi += x3.x * bfhi(w3.x) + x3.y * bfhi(w3.y) + x3.z * bfhi(w3.z) + x3.w * bfhi(w3.w);
            if (t < 2) {
                uint4 y0 = p0[64 + t], y1 = p1[64 + t], y2 = p2[64 + t], y3 = p3[64 + t];
                acc2Lo += x0.x * bflo(y0.x) + x0.y * bflo(y0.y) + x0.z * bflo(y0.z) + x0.w * bflo(y0.w);
                acc2Hi += x0.x * bfhi(y0.x) + x0.y * bfhi(y0.y) + x0.z * bfhi(y0.z) + x0.w * bfhi(y0.w);
                acc2Lo += x1.x * bflo(y1.x) + x1.y * bflo(y1.y) + x1.z * bflo(y1.z) + x1.w * bflo(y1.w);
                acc2Hi += x1.x * bfhi(y1.x) + x1.y * bfhi(y1.y) + x1.z * bfhi(y1.z) + x1.w * bfhi(y1.w);
                acc2Lo += x2.x * bflo(y2.x) + x2.y * bflo(y2.y) + x2.z * bflo(y2.z) + x2.w * bflo(y2.w);
                acc2Hi += x2.x * bfhi(y2.x) + x2.y * bfhi(y2.y) + x2.z * bfhi(y2.z) + x2.w * bfhi(y2.w);
                acc2Lo += x3.x * bflo(y3.x) + x3.y * bflo(y3.y) + x3.z * bflo(y3.z) + x3.w * bflo(y3.w);
                acc2Hi += x3.x * bfhi(y3.x) + x3.y * bfhi(y3.y) + x3.z * bfhi(y3.z) + x3.w * bfhi(y3.w);
            }
        }
        for (; j < deg; ++j) {
            int s0 = srcl[w][j];
            const uint4* p0 = (const uint4*)(hgb + (size_t)s0 * HID4);
            uint4 w0 = p0[t];
            float4 x0 = *(const float4*)&al[w][j * 4];
            accLo += x0.x * bflo(w0.x) + x0.y * bflo(w0.y) + x0.z * bflo(w0.z) + x0.w * bflo(w0.w);
            accHi += x0.x * bfhi(w0.x) + x0.y * bfhi(w0.y) + x0.z * bfhi(w0.z) + x0.w * bfhi(w0.w);
            if (t < 2) {
                uint4 y0 = p0[64 + t];
                acc2Lo += x0.x * bflo(y0.x) + x0.y * bflo(y0.y) + x0.z * bflo(y0.z) + x0.w * bflo(y0.w);
                acc2Hi += x0.x * bfhi(y0.x) + x0.y * bfhi(y0.y) + x0.z * bfhi(y0.z) + x0.w * bfhi(y0.w);
            }
        }
    } else {
        float inv0 = __shfl(inv, 0), inv1 = __shfl(inv, 1);
        float inv2 = __shfl(inv, 2), inv3 = __shfl(inv, 3);
        const float4* tmp4 = (const float4*)tmp;
        for (int j = 0; j < deg; ++j) {
            int src = csr_src[s + j];
            float4 ax = tmp4[s + j];
            float b0 = ax.x * inv0, b1 = ax.y * inv1, b2 = ax.z * inv2, b3 = ax.w * inv3;
            const uint4* su = (const uint4*)(hgb + (size_t)src * HID4);
            uint4 wv = su[t];
            accLo += b0 * bflo(wv.x) + b1 * bflo(wv.y) + b2 * bflo(wv.z) + b3 * bflo(wv.w);
            accHi += b0 * bfhi(wv.x) + b1 * bfhi(wv.y) + b2 * bfhi(wv.z) + b3 * bfhi(wv.w);
            if (t < 2) {
                uint4 y = su[64 + t];
                acc2Lo += b0 * bflo(y.x) + b1 * bflo(y.y) + b2 * bflo(y.z) + b3 * bflo(y.w);
                acc2Hi += b0 * bfhi(y.x) + b1 * bfhi(y.y) + b2 * bfhi(y.z) + b3 * bfhi(y.w);
            }
        }
    }
    float v0 = accLo * 0.25f + bias[2 * t];
    float v1 = accHi * 0.25f + bias[2 * t + 1];
    if (do_relu) { v0 = fmaxf(v0, 0.f); v1 = fmaxf(v1, 0.f); }
    u32* ga = (u32*)(abg + (size_t)i * 288);
    ga[t] = pk2(v0, v1);
    if (t < 2) {
        float v2 = acc2Lo * 0.25f + bias[128 + 2 * t];
        float v3 = acc2Hi * 0.25f + bias[129 + 2 * t];
        if (do_relu) { v2 = fmaxf(v2, 0.f); v3 = fmaxf(v3, 0.f); }
        ga[64 + t] = pk2(v2, v3);
    }
}

// ---------------- fused pool + 2-layer MLP head ----------------
__global__ __launch_bounds__(256) void k_head(
    const float* __restrict__ x3, const u16* __restrict__ BTS1,
    const u16* __restrict__ BTS2, const float* __restrict__ b_g1,
    const float* __restrict__ b_g2, float* __restrict__ out) {
    __shared__ float sm[4][132];
    __shared__ u32 g_sm[66];
    __shared__ float h_sm[GFC];
    __shared__ float part[OUT_DIM];
    const int g = blockIdx.x;
    const int tid = threadIdx.x, t = tid & 63, w = tid >> 6;
    const int n0 = (g * N_NODES + GRAPHS - 1) / GRAPHS;
    const int n1 = ((g + 1) * N_NODES + GRAPHS - 1) / GRAPHS;
    float m0 = -3.4e38f, m1 = -3.4e38f, m2 = -3.4e38f, m3 = -3.4e38f;
    for (int n = n0 + w; n < n1; n += 4) {
        const float2* r = (const float2*)(x3 + (size_t)n * HID);
        float2 v = r[t];
        m0 = fmaxf(m0, v.x); m1 = fmaxf(m1, v.y);
        if (t < 2) { float2 u = r[64 + t]; m2 = fmaxf(m2, u.x); m3 = fmaxf(m3, u.y); }
    }
    sm[w][2 * t] = m0; sm[w][2 * t + 1] = m1;
    if (t < 2) { sm[w][128 + 2 * t] = m2; sm[w][129 + 2 * t] = m3; }
    __syncthreads();
    if (w == 0) {
        float a0 = fmaxf(fmaxf(sm[0][2*t], sm[1][2*t]), fmaxf(sm[2][2*t], sm[3][2*t]));
        float a1 = fmaxf(fmaxf(sm[0][2*t+1], sm[1][2*t+1]), fmaxf(sm[2][2*t+1], sm[3][2*t+1]));
        g_sm[t] = pk2(a0, a1);
        if (t < 2) {
            float a2 = fmaxf(fmaxf(sm[0][128+2*t], sm[1][128+2*t]), fmaxf(sm[2][128+2*t], sm[3][128+2*t]));
            float a3 = fmaxf(fmaxf(sm[0][129+2*t], sm[1][129+2*t]), fmaxf(sm[2][129+2*t], sm[3][129+2*t]));
            g_sm[64 + t] = pk2(a2, a3);
        }
    }
    __syncthreads();
    // h = bf16(relu(g @ Wg1 + b1)), 4 outputs/thread
    #pragma unroll
    for (int r = 0; r < 4; ++r) {
        int o = tid + 256 * r;
        const u32* wr = (const u32*)(BTS1 + (size_t)o * 160);
        float acc = 0.f;
        for (int c = 0; c < 66; ++c) {
            u32 wv = wr[c], gv = g_sm[c];
            acc += bflo(wv) * bflo(gv) + bfhi(wv) * bfhi(gv);
        }
        acc = fmaxf(acc + b_g1[o], 0.f);
        h_sm[o] = __uint_as_float((u32)f2bf(acc) << 16);
    }
    __syncthreads();
    // out = h @ Wg2 + b2, split-K over 2 half-threads
    const int o = tid & 127, half = tid >> 7;
    const u32* wr2 = (const u32*)(BTS2 + (size_t)o * 1024 + half * 512);
    const float* hh = h_sm + half * 512;
    float acc = 0.f;
    for (int c = 0; c < 256; ++c) {
        u32 wv = wr2[c];
        acc += bflo(wv) * hh[2 * c] + bfhi(wv) * hh[2 * c + 1];
    }
    if (half == 1) part[o] = acc;
    __syncthreads();
    if (half == 0) out[(size_t)g * OUT_DIM + o] = acc + part[o] + b_g2[o];
}

// ---------------- launch ----------------
extern "C" void kernel_launch(void* const* d_in, const int* in_sizes, int n_in,
                              void* d_out, int out_size, void* d_ws, size_t ws_size,
                              hipStream_t stream) {
    const float* X       = (const float*)d_in[0];
    const int*   EI      = (const int*)d_in[1];
    const float* EW      = (const float*)d_in[2];
    const float* W_gcn   = (const float*)d_in[4];
    const float* b_gcn   = (const float*)d_in[5];
    const float* W_gat1  = (const float*)d_in[6];
    const float* a_src1  = (const float*)d_in[7];
    const float* a_dst1  = (const float*)d_in[8];
    const float* b_gat1  = (const float*)d_in[9];
    const float* W_gat2  = (const float*)d_in[10];
    const float* a_src2  = (const float*)d_in[11];
    const float* a_dst2  = (const float*)d_in[12];
    const float* b_gat2  = (const float*)d_in[13];
    const float* W_fc1   = (const float*)d_in[14];
    const float* b_fc1   = (const float*)d_in[15];
    const float* W_fc2   = (const float*)d_in[16];
    const float* b_fc2   = (const float*)d_in[17];
    const float* pro_bias= (const float*)d_in[18];
    const float* W_g1    = (const float*)d_in[19];
    const float* b_g1    = (const float*)d_in[20];
    const float* W_g2    = (const float*)d_in[21];
    const float* b_g2    = (const float*)d_in[22];
    float* OUT = (float*)d_out;

    float* ws = (float*)d_ws;
    float*    dis     = ws + O_DIS;
    int*      counts  = (int*)(ws + O_CNT);
    float*    wdeg    = ws + O_WDEG;
    int*      indptr  = (int*)(ws + O_IDP);
    int*      bsum    = (int*)(ws + O_BSUM);
    int*      boff    = (int*)(ws + O_BOFF);
    int*      csr_src = (int*)(ws + O_CSR_S);
    float*    csr_w   = ws + O_CSR_W;
    float*    esd     = ws + O_ESD;
    float*    tmp     = ws + O_TMP;
    float*    x3      = ws + O_X3;
    u16*      U       = (u16*)(ws + O_U);
    u16*      hb      = U + U_HB;
    u16*      hgb     = U + U_HGB;
    u16*      ABF     = U + U_ABF;
    u16*      ABG     = U + U_ABG;
    u16*      BTG     = U + U_BTG;
    u16*      BTGCN   = U + U_BTGCN;
    u16*      BT1     = U + U_BT1;
    u16*      BT2     = U + U_BT2;
    u16*      BTS1    = U + U_BTS1;
    u16*      BTS2    = U + U_BTS2;

    const int EB = (N_EDGES + 255) / 256;
    const int NB4 = N_NODES / 4;   // 7500, exact

    // ---- CSR build (parallel scan) ----
    hipMemsetAsync(counts, 0, 2 * rnd64(N_NODES) * sizeof(int), stream);  // counts + wdeg
    k_count<<<EB, 256, 0, stream>>>(EI, EW, counts, wdeg);
    k_bsum<<<NBLK, 256, 0, stream>>>(counts, wdeg, bsum, dis);
    k_scan2<<<1, 64, 0, stream>>>(bsum, boff);
    k_apply<<<NBLK, 256, 0, stream>>>(counts, boff, indptr);
    k_scatter<<<EB, 256, 0, stream>>>(EI, EW, indptr, counts, csr_src, csr_w);

    // ---- all weight + X + composite-es conversions ----
    k_cvtW<<<(SW_TOT + 255) / 256, 256, 0, stream>>>(
        W_fc1, W_fc2, W_gcn, W_gat1, W_gat2, W_g1, W_g2, X,
        a_src1, a_dst1, a_src2, a_dst2,
        BTG, BTGCN, BT1, BT2, BTS1, BTS2, ABF);

    // ---- GCN ----
    {
        dim3 grid(MP / 64, 3);
        k_mfma_gemm<<<grid, 256, 0, stream>>>(ABF, BTGCN, nullptr, hb, HID, HID, 0,
                                              nullptr, 0, 0, N_NODES, HID, 64,
                                              nullptr, 0, 0, nullptr, nullptr);
    }
    k_gcn_agg<<<NB4, 256, 0, stream>>>(hb, indptr, csr_src, csr_w, dis, b_gcn, ABF, ABG);

    // ---- GAT layer 1 (GEMM emits permuted h + es/ed) ----
    {
        dim3 grid(MP / 64, 9);
        k_mfma_gemm<<<grid, 256, 0, stream>>>(ABF, BT1, esd, hgb, 0, 0, 1,
                                              nullptr, 0, 0, N_NODES, 536, 160,
                                              nullptr, 0, 0, nullptr, nullptr);
    }
    k_gat_node<<<NB4, 256, 0, stream>>>(hgb, esd, indptr, csr_src, tmp, b_gat1, ABG, 1);
    // gate 1: x2 bf16 -> ABF (GAT2 A) and ABG cols 132.. (gate2 xp); no fp32 out
    {
        dim3 grid(MP / 64, 3);
        k_mfma_gemm<<<grid, 256, 0, stream>>>(ABG, BTG, nullptr, ABF, 160, 160, 0,
                                              ABG, 288, 132, N_NODES, HID, 288,
                                              b_fc1, 0, 1, b_fc2, pro_bias);
    }

    // ---- GAT layer 2 ----
    {
        dim3 grid(MP / 64, 9);
        k_mfma_gemm<<<grid, 256, 0, stream>>>(ABF, BT2, esd, hgb, 0, 0, 1,
                                              nullptr, 0, 0, N_NODES, 536, 160,
                                              nullptr, 0, 0, nullptr, nullptr);
    }
    k_gat_node<<<NB4, 256, 0, stream>>>(hgb, esd, indptr, csr_src, tmp, b_gat2, ABG, 0);
    // gate 2: x3 fp32 (for pooling)
    {
        dim3 grid(MP / 64, 3);
        k_mfma_gemm<<<grid, 256, 0, stream>>>(ABG, BTG, x3, nullptr, 0, 0, 0,
                                              nullptr, 0, 0, N_NODES, HID, 288,
                                              b_fc1, 0, 1, b_fc2, pro_bias);
    }

    // ---- fused pool + MLP head ----
    k_head<<<GRAPHS, 256, 0, stream>>>(x3, BTS1, BTS2, b_g1, b_g2, OUT);
}

// Round 8
// 503.535 us; speedup vs baseline: 2.0566x; 1.0692x over previous
//
#include <hip/hip_runtime.h>

// ---------------- problem constants ----------------
constexpr int N_NODES = 30000;
constexpr int N_EDGES = 300000;
constexpr int GRAPHS  = 64;
constexpr int F_IN    = 33;
constexpr int HID     = 132;
constexpr int HEADS   = 4;
constexpr int HID4    = HEADS * HID;   // 528
constexpr int HGS     = 544;           // hgb row stride (u16) = 1088 B = 17 cache lines
constexpr int OUT_DIM = 128;
constexpr int GFC     = 1024;
constexpr int MP      = 30016;         // N_NODES padded to x64
constexpr int CAP     = 128;           // max in-degree on LDS fast path
constexpr int NBLK    = 118;           // ceil(N_NODES/256)

typedef unsigned int u32;
typedef unsigned short u16;

// ---------------- workspace layout (float units, 64-float aligned) ----------------
constexpr size_t rnd64(size_t x) { return (x + 63) & ~(size_t)63; }
constexpr size_t O_DIS   = 0;
constexpr size_t O_CNT   = O_DIS   + rnd64(N_NODES);                 // int
constexpr size_t O_WDEG  = O_CNT   + rnd64(N_NODES);                 // float (memset with CNT)
constexpr size_t O_IDP   = O_WDEG  + rnd64(N_NODES);                 // int, N+1
constexpr size_t O_BSUM  = O_IDP   + rnd64(N_NODES + 1);             // int, 128
constexpr size_t O_BOFF  = O_BSUM  + rnd64(128);                     // int, 128
constexpr size_t O_CSR_S = O_BOFF  + rnd64(128);                     // int, E
constexpr size_t O_CSR_W = O_CSR_S + rnd64(N_EDGES);                 // float, E
constexpr size_t O_ESD   = O_CSR_W + rnd64(N_EDGES);                 // float, N*8
constexpr size_t O_GE    = O_ESD   + rnd64((size_t)N_NODES * 8);     // u32, G*HID
constexpr size_t O_TMP   = O_GE    + rnd64(GRAPHS * HID);            // float, E*4 (fallback)
// u16 region
constexpr size_t O_U     = O_TMP   + rnd64((size_t)N_EDGES * 4);
constexpr size_t U_HB    = 0;                                        // [N,132]
constexpr size_t U_HGB   = U_HB   + rnd64((size_t)N_NODES * HID);    // [N,HGS] permuted
constexpr size_t U_ABF   = U_HGB  + rnd64((size_t)N_NODES * HGS);    // [MP,160]
constexpr size_t U_ABG   = U_ABF  + rnd64((size_t)MP * 160);         // [MP,288]
constexpr size_t U_BTG   = U_ABG  + rnd64((size_t)MP * 288);         // [192,288]
constexpr size_t U_BTGCN = U_BTG  + rnd64(192 * 288);                // [192,64]
constexpr size_t U_BT1   = U_BTGCN+ rnd64(192 * 64);                 // [576,160]
constexpr size_t U_BT2   = U_BT1  + rnd64(576 * 160);                // [576,160]
constexpr size_t U_BTS1  = U_BT2  + rnd64(576 * 160);                // [1024,160]
constexpr size_t U_BTS2  = U_BTS1 + rnd64(1024 * 160);               // [128,1024]

// ---------------- bf16 helpers ----------------
__device__ inline u16 f2bf(float f) {
    u32 u = __float_as_uint(f);
    return (u16)((u + 0x7fffu + ((u >> 16) & 1u)) >> 16);
}
__device__ inline u32 pk2(float a, float b) { return (u32)f2bf(a) | ((u32)f2bf(b) << 16); }
__device__ inline float bflo(u32 w) { return __uint_as_float(w << 16); }
__device__ inline float bfhi(u32 w) { return __uint_as_float(w & 0xffff0000u); }
__device__ inline float bf1(u16 x) { return __uint_as_float((u32)x << 16); }
__device__ inline u32 encf(float x) {
    u32 u = __float_as_uint(x);
    return (u & 0x80000000u) ? ~u : (u | 0x80000000u);
}
__device__ inline float decf(u32 e) {
    u32 u = (e & 0x80000000u) ? (e & 0x7fffffffu) : ~e;
    return __uint_as_float(u);
}

typedef __attribute__((ext_vector_type(8))) short s8b;
typedef __attribute__((ext_vector_type(4))) float f32x4;

// ---------------- CSR build ----------------
__global__ void k_count(const int* __restrict__ ei, const float* __restrict__ ew,
                        int* __restrict__ counts, float* __restrict__ wdeg) {
    int e = blockIdx.x * 256 + threadIdx.x;
    if (e < N_EDGES) {
        int dst = ei[N_EDGES + e];
        atomicAdd(&counts[dst], 1);
        atomicAdd(&wdeg[dst], ew[e]);
    }
}

__global__ __launch_bounds__(256) void k_bsum(const int* __restrict__ counts,
                                              const float* __restrict__ wdeg,
                                              int* __restrict__ bsum,
                                              float* __restrict__ dis) {
    int i = blockIdx.x * 256 + threadIdx.x;
    int v = (i < N_NODES) ? counts[i] : 0;
    if (i < N_NODES) {
        float d = 1.f + wdeg[i];
        dis[i] = (d > 0.f) ? rsqrtf(fmaxf(d, 1e-12f)) : 0.f;
    }
    int x = v;
    #pragma unroll
    for (int off = 1; off < 64; off <<= 1) x += __shfl_xor(x, off);
    __shared__ int ws4[4];
    if ((threadIdx.x & 63) == 0) ws4[threadIdx.x >> 6] = x;
    __syncthreads();
    if (threadIdx.x == 0) bsum[blockIdx.x] = ws4[0] + ws4[1] + ws4[2] + ws4[3];
}

__global__ __launch_bounds__(64) void k_scan2(const int* __restrict__ bsum,
                                              int* __restrict__ boff) {
    int t = threadIdx.x;
    int a = (2 * t < NBLK) ? bsum[2 * t] : 0;
    int b = (2 * t + 1 < NBLK) ? bsum[2 * t + 1] : 0;
    int loc = a + b, x = loc;
    #pragma unroll
    for (int off = 1; off < 64; off <<= 1) {
        int y = __shfl_up(x, off);
        if (t >= off) x += y;
    }
    int excl = x - loc;
    if (2 * t < NBLK) boff[2 * t] = excl;
    if (2 * t + 1 < NBLK) boff[2 * t + 1] = excl + a;
}

__global__ __launch_bounds__(256) void k_apply(int* __restrict__ counts,
                                               const int* __restrict__ boff,
                                               int* __restrict__ indptr) {
    int b = blockIdx.x;
    int i = b * 256 + threadIdx.x;
    int v = (i < N_NODES) ? counts[i] : 0;
    const int lane = threadIdx.x & 63, w = threadIdx.x >> 6;
    int x = v;
    #pragma unroll
    for (int off = 1; off < 64; off <<= 1) {
        int y = __shfl_up(x, off);
        if (lane >= off) x += y;
    }
    __shared__ int wsum[4];
    if (lane == 63) wsum[w] = x;
    __syncthreads();
    int add = boff[b];
    for (int k2 = 0; k2 < w; ++k2) add += wsum[k2];
    if (i < N_NODES) {
        indptr[i] = add + x - v;
        counts[i] = 0;   // becomes scatter cursor
    }
    if (i == N_NODES) indptr[N_NODES] = N_EDGES;
}

__global__ void k_scatter(const int* __restrict__ ei, const float* __restrict__ ew,
                          const int* __restrict__ indptr, int* __restrict__ cursor,
                          int* __restrict__ csr_src, float* __restrict__ csr_w) {
    int e = blockIdx.x * 256 + threadIdx.x;
    if (e >= N_EDGES) return;
    int src = ei[e];
    int dst = ei[N_EDGES + e];
    int pos = indptr[dst] + atomicAdd(&cursor[dst], 1);
    csr_src[pos] = src;
    csr_w[pos] = ew[e];
}

// ---------------- merged weight + X + composite-es conversion ----------------
constexpr int S0 = 192 * 288;    // BTG
constexpr int S1 = 192 * 64;     // BTGCN
constexpr int S2 = 576 * 160;    // BT1
constexpr int S3 = 576 * 160;    // BT2
constexpr int S4 = 1024 * 160;   // BTS1
constexpr int S5 = 128 * 1024;   // BTS2
constexpr int S6 = N_NODES * 64; // X -> ABF
constexpr int S7 = 2 * 8 * 160;  // wes composite rows
constexpr int SW_TOT = S0 + S1 + S2 + S3 + S4 + S5 + S6 + S7;

__global__ void k_cvtW(const float* __restrict__ Wfc1, const float* __restrict__ Wfc2,
                       const float* __restrict__ Wgcn, const float* __restrict__ Wgat1,
                       const float* __restrict__ Wgat2, const float* __restrict__ Wg1,
                       const float* __restrict__ Wg2, const float* __restrict__ X,
                       const float* __restrict__ as1, const float* __restrict__ ad1,
                       const float* __restrict__ as2, const float* __restrict__ ad2,
                       u16* __restrict__ BTG, u16* __restrict__ BTGCN,
                       u16* __restrict__ BT1, u16* __restrict__ BT2,
                       u16* __restrict__ BTS1, u16* __restrict__ BTS2,
                       u16* __restrict__ ABF) {
    int idx = blockIdx.x * 256 + threadIdx.x;
    if (idx < S0) {
        int n = idx / 288, k = idx - n * 288;
        u16 v = 0;
        if (n < HID) {
            if (k < HID) v = f2bf(Wfc1[(size_t)k * HID + n]);
            else if (k < 2 * HID) v = f2bf(Wfc2[(size_t)(k - HID) * HID + n]);
        }
        BTG[idx] = v;
        return;
    }
    idx -= S0;
    if (idx < S1) {
        int n = idx / 64, k = idx - n * 64;
        BTGCN[idx] = (k < F_IN && n < HID) ? f2bf(Wgcn[(size_t)k * HID + n]) : (u16)0;
        return;
    }
    idx -= S1;
    if (idx < S2) {
        int n = idx / 160, k = idx - n * 160;
        BT1[idx] = (k < HID && n < HID4) ? f2bf(Wgat1[(size_t)k * HID4 + n]) : (u16)0;
        return;
    }
    idx -= S2;
    if (idx < S3) {
        int n = idx / 160, k = idx - n * 160;
        BT2[idx] = (k < HID && n < HID4) ? f2bf(Wgat2[(size_t)k * HID4 + n]) : (u16)0;
        return;
    }
    idx -= S3;
    if (idx < S4) {
        int n = idx / 160, k = idx - n * 160;
        BTS1[idx] = (k < HID) ? f2bf(Wg1[(size_t)k * GFC + n]) : (u16)0;
        return;
    }
    idx -= S4;
    if (idx < S5) {
        int n = idx / 1024, k = idx - n * 1024;
        BTS2[idx] = f2bf(Wg2[(size_t)k * OUT_DIM + n]);
        return;
    }
    idx -= S5;
    if (idx < S6) {
        int r = idx / 64, k = idx - r * 64;
        ABF[idx] = (k < F_IN) ? f2bf(X[(size_t)r * F_IN + k]) : (u16)0;
        return;
    }
    idx -= S6;
    if (idx < S7) {
        int l = idx / 1280; idx -= l * 1280;
        int q = idx / 160;  int c = idx - q * 160;
        int k = q & 3;
        const float* W = l ? Wgat2 : Wgat1;
        const float* a = (q < 4) ? (l ? as2 : as1) : (l ? ad2 : ad1);
        float sum = 0.f;
        if (c < HID) {
            const float* wr = W + (size_t)c * HID4 + k * HID;
            const float* ar = a + k * HID;
            for (int cc = 0; cc < HID; ++cc) sum += wr[cc] * ar[cc];
        }
        u16* BT = l ? BT2 : BT1;
        BT[(size_t)(528 + q) * 160 + c] = f2bf(sum);
    }
}

// ---------------- MFMA bf16 GEMM: out = A[*,Kp] @ Bt[Np,Kp]^T ----------------
// perm: cols<528 -> permuted bf16 [row][c2][head] into Cb (stride HGS);
//       cols 528..535 -> fp32 C (esd).
// gate: z=sigmoid(acc+biases); res = z*bf(A[row][col]) + (1-z)*bf(A[row][132+col]).
// genc: fused per-graph max-pool of res (encoded atomicMax).
__global__ __launch_bounds__(256) void k_mfma_gemm(
    const u16* __restrict__ A, const u16* __restrict__ Bt,
    float* __restrict__ C, u16* __restrict__ Cb, int ldcb, int padN, int perm,
    u16* __restrict__ Cb2, int ldcb2, int coff2,
    int M, int N, int Kp,
    const float* __restrict__ bias, int relu, int gate,
    const float* __restrict__ b2, const float* __restrict__ pb,
    u32* __restrict__ genc) {
    const int bm = blockIdx.x * 64;
    const int bn = blockIdx.y * 64;
    const int w = threadIdx.x >> 6;
    const int lane = threadIdx.x & 63;
    const int m16 = lane & 15;
    const int quad = lane >> 4;
    const u16* Ab = A + (size_t)(bm + m16) * Kp + quad * 8;
    const u16* Bb = Bt + (size_t)(bn + w * 16 + m16) * Kp + quad * 8;
    f32x4 acc[4];
    #pragma unroll
    for (int r = 0; r < 4; ++r) acc[r] = (f32x4){0.f, 0.f, 0.f, 0.f};
    for (int k0 = 0; k0 < Kp; k0 += 32) {
        s8b b = *(const s8b*)(Bb + k0);
        s8b a0 = *(const s8b*)(Ab + k0);
        s8b a1 = *(const s8b*)(Ab + (size_t)16 * Kp + k0);
        s8b a2 = *(const s8b*)(Ab + (size_t)32 * Kp + k0);
        s8b a3 = *(const s8b*)(Ab + (size_t)48 * Kp + k0);
        acc[0] = __builtin_amdgcn_mfma_f32_16x16x32_bf16(a0, b, acc[0], 0, 0, 0);
        acc[1] = __builtin_amdgcn_mfma_f32_16x16x32_bf16(a1, b, acc[1], 0, 0, 0);
        acc[2] = __builtin_amdgcn_mfma_f32_16x16x32_bf16(a2, b, acc[2], 0, 0, 0);
        acc[3] = __builtin_amdgcn_mfma_f32_16x16x32_bf16(a3, b, acc[3], 0, 0, 0);
    }
    const int col = bn + w * 16 + m16;
    const bool colok = col < N;
    int pcol = 0;
    if (perm && col < HID4) {
        int kk = col / HID, cc = col - kk * HID;
        pcol = ((cc >> 1) << 3) + (kk << 1) + (cc & 1);
    }
    float bsum = 0.f;
    if (colok && !perm) {
        if (gate) bsum = bias[col] + b2[col] + pb[col];
        else if (bias) bsum = bias[col];
    }
    const int g0 = (bm * GRAPHS) / N_NODES;
    int gend = bm + 63; if (gend >= M) gend = M - 1;
    const int g1 = (gend * GRAPHS) / N_NODES;
    float mx0 = -3.4e38f, mx1 = -3.4e38f;
    #pragma unroll
    for (int r = 0; r < 4; ++r) {
        #pragma unroll
        for (int j = 0; j < 4; ++j) {
            int row = bm + r * 16 + quad * 4 + j;
            if (row >= M) continue;
            if (colok) {
                float v = acc[r][j] + bsum;
                if (perm) {
                    if (col < HID4) Cb[(size_t)row * HGS + pcol] = f2bf(v);
                    else            C[(size_t)row * 8 + (col - HID4)] = v;
                    continue;
                }
                float res;
                if (gate) {
                    float z = 1.f / (1.f + expf(-v));
                    float xcv = bf1(A[(size_t)row * Kp + col]);
                    float xpv = bf1(A[(size_t)row * Kp + 132 + col]);
                    res = z * xcv + (1.f - z) * xpv;
                } else {
                    if (relu) v = fmaxf(v, 0.f);
                    res = v;
                }
                if (genc) {
                    int gid = (row * GRAPHS) / N_NODES;
                    if (gid == g0) mx0 = fmaxf(mx0, res);
                    else           mx1 = fmaxf(mx1, res);
                }
                if (C) C[(size_t)row * N + col] = res;
                if (Cb) Cb[(size_t)row * ldcb + col] = f2bf(res);
                if (Cb2) Cb2[(size_t)row * ldcb2 + coff2 + col] = f2bf(res);
            } else if (Cb && !perm && col < padN) {
                Cb[(size_t)row * ldcb + col] = 0;
            }
        }
    }
    if (genc && colok) {
        mx0 = fmaxf(mx0, __shfl_xor(mx0, 16));
        mx0 = fmaxf(mx0, __shfl_xor(mx0, 32));
        if (g1 != g0) {
            mx1 = fmaxf(mx1, __shfl_xor(mx1, 16));
            mx1 = fmaxf(mx1, __shfl_xor(mx1, 32));
        }
        if (quad == 0) {
            atomicMax(&genc[g0 * HID + col], encf(mx0));
            if (g1 != g0) atomicMax(&genc[g1 * HID + col], encf(mx1));
        }
    }
}

// ---------------- GCN aggregate (bf16 gather, unroll-4, bf16-only output) ----
__global__ __launch_bounds__(256) void k_gcn_agg(
    const u16* __restrict__ hb, const int* __restrict__ indptr,
    const int* __restrict__ csr_src, const float* __restrict__ csr_w,
    const float* __restrict__ dis, const float* __restrict__ bias,
    u16* __restrict__ abf, u16* __restrict__ abg) {
    const int w = threadIdx.x >> 6, t = threadIdx.x & 63;
    const int i = blockIdx.x * 4 + w;
    const float di = dis[i];
    const int s = indptr[i], e = indptr[i + 1];
    const float nself = di * di;
    const u32* ru = (const u32*)(hb + (size_t)i * HID);
    u32 wv = ru[t];
    float aLo = nself * bflo(wv), aHi = nself * bfhi(wv);
    float bLo = 0.f, bHi = 0.f;
    if (t < 2) { u32 w2 = ru[64 + t]; bLo = nself * bflo(w2); bHi = nself * bfhi(w2); }
    int j = s;
    for (; j + 3 < e; j += 4) {
        int s0 = csr_src[j], s1 = csr_src[j + 1], s2 = csr_src[j + 2], s3 = csr_src[j + 3];
        float n0 = dis[s0] * csr_w[j]     * di;
        float n1 = dis[s1] * csr_w[j + 1] * di;
        float n2 = dis[s2] * csr_w[j + 2] * di;
        float n3 = dis[s3] * csr_w[j + 3] * di;
        const u32* p0 = (const u32*)(hb + (size_t)s0 * HID);
        const u32* p1 = (const u32*)(hb + (size_t)s1 * HID);
        const u32* p2 = (const u32*)(hb + (size_t)s2 * HID);
        const u32* p3 = (const u32*)(hb + (size_t)s3 * HID);
        u32 w0 = p0[t], w1 = p1[t], w2 = p2[t], w3 = p3[t];
        aLo += n0 * bflo(w0) + n1 * bflo(w1) + n2 * bflo(w2) + n3 * bflo(w3);
        aHi += n0 * bfhi(w0) + n1 * bfhi(w1) + n2 * bfhi(w2) + n3 * bfhi(w3);
        if (t < 2) {
            u32 y0 = p0[64 + t], y1 = p1[64 + t], y2 = p2[64 + t], y3 = p3[64 + t];
            bLo += n0 * bflo(y0) + n1 * bflo(y1) + n2 * bflo(y2) + n3 * bflo(y3);
            bHi += n0 * bfhi(y0) + n1 * bfhi(y1) + n2 * bfhi(y2) + n3 * bfhi(y3);
        }
    }
    for (; j < e; ++j) {
        int src = csr_src[j];
        float nb = dis[src] * csr_w[j] * di;
        const u32* su = (const u32*)(hb + (size_t)src * HID);
        u32 ws = su[t];
        aLo += nb * bflo(ws);
        aHi += nb * bfhi(ws);
        if (t < 2) { u32 w2 = su[64 + t]; bLo += nb * bflo(w2); bHi += nb * bfhi(w2); }
    }
    float v0 = fmaxf(aLo + bias[2 * t], 0.f);
    float v1 = fmaxf(aHi + bias[2 * t + 1], 0.f);
    u32* fa = (u32*)(abf + (size_t)i * 160);
    u32* ga = (u32*)(abg + (size_t)i * 288);
    u32 p = pk2(v0, v1);
    fa[t] = p;
    ga[66 + t] = p;
    if (t < 2) {
        float v2 = fmaxf(bLo + bias[128 + 2 * t], 0.f);
        float v3 = fmaxf(bHi + bias[129 + 2 * t], 0.f);
        u32 pk = pk2(v2, v3);
        fa[64 + t] = pk;
        ga[130 + t] = pk;
    }
    if (t >= 2 && t < 16) fa[64 + t] = 0;
}

// ---------------- GAT softmax + aggregate (unroll-4 gather, bf16-only out) ---
__global__ __launch_bounds__(256) void k_gat_node(
    const u16* __restrict__ hgb, const float* __restrict__ esd,
    const int* __restrict__ indptr, const int* __restrict__ csr_src,
    float* __restrict__ tmp, const float* __restrict__ bias,
    u16* __restrict__ abg, int do_relu) {
    __shared__ __align__(16) float al[4][CAP * 4];
    __shared__ int srcl[4][CAP];
    const int w = threadIdx.x >> 6, t = threadIdx.x & 63;
    const int i = blockIdx.x * 4 + w;
    const int k = t & 3;
    const int s = indptr[i];
    const int deg = indptr[i + 1] - s;
    const bool fast = (deg <= CAP);
    const float edk = esd[i * 8 + 4 + k];
    float eself = esd[i * 8 + k] + edk;
    eself = (eself >= 0.f) ? eself : 0.2f * eself;
    float m = eself;
    for (int j0 = 0; j0 < deg; j0 += 16) {
        int j = j0 + (t >> 2);
        float e = -1e30f;
        if (j < deg) {
            int src = csr_src[s + j];
            e = esd[src * 8 + k] + edk;
            e = (e >= 0.f) ? e : 0.2f * e;
            if (fast) { al[w][j * 4 + k] = e; if (k == 0) srcl[w][j] = src; }
            else tmp[(size_t)(s + j) * 4 + k] = e;
        }
        m = fmaxf(m, e);
    }
    m = fmaxf(m, __shfl_xor(m, 4));
    m = fmaxf(m, __shfl_xor(m, 8));
    m = fmaxf(m, __shfl_xor(m, 16));
    m = fmaxf(m, __shfl_xor(m, 32));
    float dsum = 0.f;
    for (int j0 = 0; j0 < deg; j0 += 16) {
        int j = j0 + (t >> 2);
        if (j < deg) {
            if (fast) {
                float ex = expf(al[w][j * 4 + k] - m);
                al[w][j * 4 + k] = ex;
                dsum += ex;
            } else {
                float ex = expf(tmp[(size_t)(s + j) * 4 + k] - m);
                tmp[(size_t)(s + j) * 4 + k] = ex;
                dsum += ex;
            }
        }
    }
    dsum += __shfl_xor(dsum, 4);
    dsum += __shfl_xor(dsum, 8);
    dsum += __shfl_xor(dsum, 16);
    dsum += __shfl_xor(dsum, 32);
    float exs = expf(eself - m);
    dsum += exs;
    float inv = 1.f / dsum;
    float aself = exs * inv;
    float a0 = __shfl(aself, 0), a1 = __shfl(aself, 1);
    float a2 = __shfl(aself, 2), a3 = __shfl(aself, 3);
    if (fast) {
        for (int idx = t; idx < deg * 4; idx += 64) al[w][idx] *= inv;
    }
    const uint4* ru = (const uint4*)(hgb + (size_t)i * HGS);
    float accLo, accHi, acc2Lo = 0.f, acc2Hi = 0.f;
    {
        uint4 v = ru[t];
        accLo = a0 * bflo(v.x) + a1 * bflo(v.y) + a2 * bflo(v.z) + a3 * bflo(v.w);
        accHi = a0 * bfhi(v.x) + a1 * bfhi(v.y) + a2 * bfhi(v.z) + a3 * bfhi(v.w);
        if (t < 2) {
            uint4 y = ru[64 + t];
            acc2Lo = a0 * bflo(y.x) + a1 * bflo(y.y) + a2 * bflo(y.z) + a3 * bflo(y.w);
            acc2Hi = a0 * bfhi(y.x) + a1 * bfhi(y.y) + a2 * bfhi(y.z) + a3 * bfhi(y.w);
        }
    }
    if (fast) {
        int j = 0;
        for (; j + 3 < deg; j += 4) {
            int s0 = srcl[w][j], s1 = srcl[w][j + 1], s2 = srcl[w][j + 2], s3 = srcl[w][j + 3];
            const uint4* p0 = (const uint4*)(hgb + (size_t)s0 * HGS);
            const uint4* p1 = (const uint4*)(hgb + (size_t)s1 * HGS);
            const uint4* p2 = (const uint4*)(hgb + (size_t)s2 * HGS);
            const uint4* p3 = (const uint4*)(hgb + (size_t)s3 * HGS);
            uint4 w0 = p0[t], w1 = p1[t], w2 = p2[t], w3 = p3[t];
            float4 x0 = *(const float4*)&al[w][j * 4];
            float4 x1 = *(const float4*)&al[w][j * 4 + 4];
            float4 x2 = *(const float4*)&al[w][j * 4 + 8];
            float4 x3 = *(const float4*)&al[w][j * 4 + 12];
            accLo += x0.x * bflo(w0.x) + x0.y * bflo(w0.y) + x0.z * bflo(w0.z) + x0.w * bflo(w0.w);
            accHi += x0.x * bfhi(w0.x) + x0.y * bfhi(w0.y) + x0.z * bfhi(w0.z) + x0.w * bfhi(w0.w);
            accLo += x1.x * bflo(w1.x) + x1.y * bflo(w1.y) + x1.z * bflo(w1.z) + x1.w * bflo(w1.w);
            accHi += x1.x * bfhi(w1.x) + x1.y * bfhi(w1.y) + x1.z * bfhi(w1.z) + x1.w * bfhi(w1.w);
            accLo += x2.x * bflo(w2.x) + x2.y * bflo(w2.y) + x2.z * bflo(w2.z) + x2.w * bflo(w2.w);
            accHi += x2.x * bfhi(w2.x) + x2.y * bfhi(w2.y) + x2.z * bfhi(w2.z) + x2.w * bfhi(w2.w);
            accLo += x3.x * bflo(w3.x) + x3.y * bflo(w3.y) + x3.z * bflo(w3.z) + x3.w * bflo(w3.w);
            accHi += x3.x * bfhi(w3.x) + x3.y * bfhi(w3.y) + x3.z * bfhi(w3.z) + x3.w * bfhi(w3.w);
            if (t < 2) {
                uint4 y0 = p0[64 + t], y1 = p1[64 + t], y2 = p2[64 + t], y3 = p3[64 + t];
                acc2Lo += x0.x * bflo(y0.x) + x0.y * bflo(y0.y) + x0.z * bflo(y0.z) + x0.w * bflo(y0.w);
                acc2Hi += x0.x * bfhi(y0.x) + x0.y * bfhi(y0.y) + x0.z * bfhi(y0.z) + x0.w * bfhi(y0.w);
                acc2Lo += x1.x * bflo(y1.x) + x1.y * bflo(y1.y) + x1.z * bflo(y1.z) + x1.w * bflo(y1.w);
                acc2Hi += x1.x * bfhi(y1.x) + x1.y * bfhi(y1.y) + x1.z * bfhi(y1.z) + x1.w * bfhi(y1.w);
                acc2Lo += x2.x * bflo(y2.x) + x2.y * bflo(y2.y) + x2.z * bflo(y2.z) + x2.w * bflo(y2.w);
                acc2Hi += x2.x * bfhi(y2.x) + x2.y * bfhi(y2.y) + x2.z * bfhi(y2.z) + x2.w * bfhi(y2.w);
                acc2Lo += x3.x * bflo(y3.x) + x3.y * bflo(y3.y) + x3.z * bflo(y3.z) + x3.w * bflo(y3.w);
                acc2Hi += x3.x * bfhi(y3.x) + x3.y * bfhi(y3.y) + x3.z * bfhi(y3.z) + x3.w * bfhi(y3.w);
            }
        }
        for (; j < deg; ++j) {
            int s0 = srcl[w][j];
            const uint4* p0 = (const uint4*)(hgb + (size_t)s0 * HGS);
            uint4 w0 = p0[t];
            float4 x0 = *(const float4*)&al[w][j * 4];
            accLo += x0.x * bflo(w0.x) + x0.y * bflo(w0.y) + x0.z * bflo(w0.z) + x0.w * bflo(w0.w);
            accHi += x0.x * bfhi(w0.x) + x0.y * bfhi(w0.y) + x0.z * bfhi(w0.z) + x0.w * bfhi(w0.w);
            if (t < 2) {
                uint4 y0 = p0[64 + t];
                acc2Lo += x0.x * bflo(y0.x) + x0.y * bflo(y0.y) + x0.z * bflo(y0.z) + x0.w * bflo(y0.w);
                acc2Hi += x0.x * bfhi(y0.x) + x0.y * bfhi(y0.y) + x0.z * bfhi(y0.z) + x0.w * bfhi(y0.w);
            }
        }
    } else {
        float inv0 = __shfl(inv, 0), inv1 = __shfl(inv, 1);
        float inv2 = __shfl(inv, 2), inv3 = __shfl(inv, 3);
        const float4* tmp4 = (const float4*)tmp;
        for (int j = 0; j < deg; ++j) {
            int src = csr_src[s + j];
            float4 ax = tmp4[s + j];
            float b0 = ax.x * inv0, b1 = ax.y * inv1, b2 = ax.z * inv2, b3 = ax.w * inv3;
            const uint4* su = (const uint4*)(hgb + (size_t)src * HGS);
            uint4 wv = su[t];
            accLo += b0 * bflo(wv.x) + b1 * bflo(wv.y) + b2 * bflo(wv.z) + b3 * bflo(wv.w);
            accHi += b0 * bfhi(wv.x) + b1 * bfhi(wv.y) + b2 * bfhi(wv.z) + b3 * bfhi(wv.w);
            if (t < 2) {
                uint4 y = su[64 + t];
                acc2Lo += b0 * bflo(y.x) + b1 * bflo(y.y) + b2 * bflo(y.z) + b3 * bflo(y.w);
                acc2Hi += b0 * bfhi(y.x) + b1 * bfhi(y.y) + b2 * bfhi(y.z) + b3 * bfhi(y.w);
            }
        }
    }
    float v0 = accLo * 0.25f + bias[2 * t];
    float v1 = accHi * 0.25f + bias[2 * t + 1];
    if (do_relu) { v0 = fmaxf(v0, 0.f); v1 = fmaxf(v1, 0.f); }
    u32* ga = (u32*)(abg + (size_t)i * 288);
    ga[t] = pk2(v0, v1);
    if (t < 2) {
        float v2 = acc2Lo * 0.25f + bias[128 + 2 * t];
        float v3 = acc2Hi * 0.25f + bias[129 + 2 * t];
        if (do_relu) { v2 = fmaxf(v2, 0.f); v3 = fmaxf(v3, 0.f); }
        ga[64 + t] = pk2(v2, v3);
    }
}

// ---------------- MLP head (pool already fused into gate2 GEMM) --------------
__global__ __launch_bounds__(256) void k_head(
    const u32* __restrict__ genc, const u16* __restrict__ BTS1,
    const u16* __restrict__ BTS2, const float* __restrict__ b_g1,
    const float* __restrict__ b_g2, float* __restrict__ out) {
    __shared__ u32 g_sm[66];
    __shared__ float h_sm[GFC];
    __shared__ float part[OUT_DIM];
    const int g = blockIdx.x;
    const int tid = threadIdx.x;
    if (tid < 66) {
        float a0 = decf(genc[g * HID + 2 * tid]);
        float a1 = decf(genc[g * HID + 2 * tid + 1]);
        g_sm[tid] = pk2(a0, a1);
    }
    __syncthreads();
    // h = bf16(relu(g @ Wg1 + b1)), 4 outputs/thread
    #pragma unroll
    for (int r = 0; r < 4; ++r) {
        int o = tid + 256 * r;
        const u32* wr = (const u32*)(BTS1 + (size_t)o * 160);
        float acc = 0.f;
        for (int c = 0; c < 66; ++c) {
            u32 wv = wr[c], gv = g_sm[c];
            acc += bflo(wv) * bflo(gv) + bfhi(wv) * bfhi(gv);
        }
        acc = fmaxf(acc + b_g1[o], 0.f);
        h_sm[o] = __uint_as_float((u32)f2bf(acc) << 16);
    }
    __syncthreads();
    // out = h @ Wg2 + b2, split-K over 2 half-threads
    const int o = tid & 127, half = tid >> 7;
    const u32* wr2 = (const u32*)(BTS2 + (size_t)o * 1024 + half * 512);
    const float* hh = h_sm + half * 512;
    float acc = 0.f;
    for (int c = 0; c < 256; ++c) {
        u32 wv = wr2[c];
        acc += bflo(wv) * hh[2 * c] + bfhi(wv) * hh[2 * c + 1];
    }
    if (half == 1) part[o] = acc;
    __syncthreads();
    if (half == 0) out[(size_t)g * OUT_DIM + o] = acc + part[o] + b_g2[o];
}

// ---------------- launch ----------------
extern "C" void kernel_launch(void* const* d_in, const int* in_sizes, int n_in,
                              void* d_out, int out_size, void* d_ws, size_t ws_size,
                              hipStream_t stream) {
    const float* X       = (const float*)d_in[0];
    const int*   EI      = (const int*)d_in[1];
    const float* EW      = (const float*)d_in[2];
    const float* W_gcn   = (const float*)d_in[4];
    const float* b_gcn   = (const float*)d_in[5];
    const float* W_gat1  = (const float*)d_in[6];
    const float* a_src1  = (const float*)d_in[7];
    const float* a_dst1  = (const float*)d_in[8];
    const float* b_gat1  = (const float*)d_in[9];
    const float* W_gat2  = (const float*)d_in[10];
    const float* a_src2  = (const float*)d_in[11];
    const float* a_dst2  = (const float*)d_in[12];
    const float* b_gat2  = (const float*)d_in[13];
    const float* W_fc1   = (const float*)d_in[14];
    const float* b_fc1   = (const float*)d_in[15];
    const float* W_fc2   = (const float*)d_in[16];
    const float* b_fc2   = (const float*)d_in[17];
    const float* pro_bias= (const float*)d_in[18];
    const float* W_g1    = (const float*)d_in[19];
    const float* b_g1    = (const float*)d_in[20];
    const float* W_g2    = (const float*)d_in[21];
    const float* b_g2    = (const float*)d_in[22];
    float* OUT = (float*)d_out;

    float* ws = (float*)d_ws;
    float*    dis     = ws + O_DIS;
    int*      counts  = (int*)(ws + O_CNT);
    float*    wdeg    = ws + O_WDEG;
    int*      indptr  = (int*)(ws + O_IDP);
    int*      bsum    = (int*)(ws + O_BSUM);
    int*      boff    = (int*)(ws + O_BOFF);
    int*      csr_src = (int*)(ws + O_CSR_S);
    float*    csr_w   = ws + O_CSR_W;
    float*    esd     = ws + O_ESD;
    u32*      genc    = (u32*)(ws + O_GE);
    float*    tmp     = ws + O_TMP;
    u16*      U       = (u16*)(ws + O_U);
    u16*      hb      = U + U_HB;
    u16*      hgb     = U + U_HGB;
    u16*      ABF     = U + U_ABF;
    u16*      ABG     = U + U_ABG;
    u16*      BTG     = U + U_BTG;
    u16*      BTGCN   = U + U_BTGCN;
    u16*      BT1     = U + U_BT1;
    u16*      BT2     = U + U_BT2;
    u16*      BTS1    = U + U_BTS1;
    u16*      BTS2    = U + U_BTS2;

    const int EB = (N_EDGES + 255) / 256;
    const int NB4 = N_NODES / 4;   // 7500, exact

    // ---- CSR build (parallel scan) ----
    hipMemsetAsync(counts, 0, 2 * rnd64(N_NODES) * sizeof(int), stream);  // counts + wdeg
    hipMemsetAsync(genc, 0, GRAPHS * HID * sizeof(u32), stream);
    k_count<<<EB, 256, 0, stream>>>(EI, EW, counts, wdeg);
    k_bsum<<<NBLK, 256, 0, stream>>>(counts, wdeg, bsum, dis);
    k_scan2<<<1, 64, 0, stream>>>(bsum, boff);
    k_apply<<<NBLK, 256, 0, stream>>>(counts, boff, indptr);
    k_scatter<<<EB, 256, 0, stream>>>(EI, EW, indptr, counts, csr_src, csr_w);

    // ---- all weight + X + composite-es conversions ----
    k_cvtW<<<(SW_TOT + 255) / 256, 256, 0, stream>>>(
        W_fc1, W_fc2, W_gcn, W_gat1, W_gat2, W_g1, W_g2, X,
        a_src1, a_dst1, a_src2, a_dst2,
        BTG, BTGCN, BT1, BT2, BTS1, BTS2, ABF);

    // ---- GCN ----
    {
        dim3 grid(MP / 64, 3);
        k_mfma_gemm<<<grid, 256, 0, stream>>>(ABF, BTGCN, nullptr, hb, HID, HID, 0,
                                              nullptr, 0, 0, N_NODES, HID, 64,
                                              nullptr, 0, 0, nullptr, nullptr, nullptr);
    }
    k_gcn_agg<<<NB4, 256, 0, stream>>>(hb, indptr, csr_src, csr_w, dis, b_gcn, ABF, ABG);

    // ---- GAT layer 1 (GEMM emits permuted h + es/ed) ----
    {
        dim3 grid(MP / 64, 9);
        k_mfma_gemm<<<grid, 256, 0, stream>>>(ABF, BT1, esd, hgb, 0, 0, 1,
                                              nullptr, 0, 0, N_NODES, 536, 160,
                                              nullptr, 0, 0, nullptr, nullptr, nullptr);
    }
    k_gat_node<<<NB4, 256, 0, stream>>>(hgb, esd, indptr, csr_src, tmp, b_gat1, ABG, 1);
    // gate 1: x2 bf16 -> ABF (GAT2 A) and ABG cols 132.. (gate2 xp)
    {
        dim3 grid(MP / 64, 3);
        k_mfma_gemm<<<grid, 256, 0, stream>>>(ABG, BTG, nullptr, ABF, 160, 160, 0,
                                              ABG, 288, 132, N_NODES, HID, 288,
                                              b_fc1, 0, 1, b_fc2, pro_bias, nullptr);
    }

    // ---- GAT layer 2 ----
    {
        dim3 grid(MP / 64, 9);
        k_mfma_gemm<<<grid, 256, 0, stream>>>(ABF, BT2, esd, hgb, 0, 0, 1,
                                              nullptr, 0, 0, N_NODES, 536, 160,
                                              nullptr, 0, 0, nullptr, nullptr, nullptr);
    }
    k_gat_node<<<NB4, 256, 0, stream>>>(hgb, esd, indptr, csr_src, tmp, b_gat2, ABG, 0);
    // gate 2: pooled directly into genc (no x3 materialization)
    {
        dim3 grid(MP / 64, 3);
        k_mfma_gemm<<<grid, 256, 0, stream>>>(ABG, BTG, nullptr, nullptr, 0, 0, 0,
                                              nullptr, 0, 0, N_NODES, HID, 288,
                                              b_fc1, 0, 1, b_fc2, pro_bias, genc);
    }

    // ---- MLP head ----
    k_head<<<GRAPHS, 256, 0, stream>>>(genc, BTS1, BTS2, b_g1, b_g2, OUT);
}

// Round 9
// 428.743 us; speedup vs baseline: 2.4154x; 1.1744x over previous
//
#include <hip/hip_runtime.h>

// ---------------- problem constants ----------------
constexpr int N_NODES = 30000;
constexpr int N_EDGES = 300000;
constexpr int GRAPHS  = 64;
constexpr int F_IN    = 33;
constexpr int HID     = 132;
constexpr int HID4    = 528;
constexpr int OUT_DIM = 128;
constexpr int GFC     = 1024;
constexpr int MP      = 30016;         // N_NODES padded to x64
constexpr int CAP     = 128;           // max in-degree on LDS fast path
constexpr int NBLK    = 118;           // ceil(N_NODES/256)
constexpr int YW      = 544;           // y row stride u16: 4 heads x (132+4 pad)

typedef unsigned int u32;
typedef unsigned short u16;

// ---------------- workspace layout ----------------
constexpr size_t rnd64(size_t x) { return (x + 63) & ~(size_t)63; }
constexpr size_t O_DIS   = 0;
constexpr size_t O_CNT   = O_DIS   + rnd64(N_NODES);
constexpr size_t O_WDEG  = O_CNT   + rnd64(N_NODES);
constexpr size_t O_IDP   = O_WDEG  + rnd64(N_NODES);
constexpr size_t O_BSUM  = O_IDP   + rnd64(N_NODES + 1);
constexpr size_t O_BOFF  = O_BSUM  + rnd64(128);
constexpr size_t O_CSR_S = O_BOFF  + rnd64(128);
constexpr size_t O_CSR_W = O_CSR_S + rnd64(N_EDGES);
constexpr size_t O_ESD   = O_CSR_W + rnd64(N_EDGES);                 // float, N*8
constexpr size_t O_GE    = O_ESD   + rnd64((size_t)N_NODES * 8);     // u32, G*HID
constexpr size_t O_TMP   = O_GE    + rnd64(GRAPHS * HID);            // float, E*4
// u16 region
constexpr size_t O_U     = O_TMP   + rnd64((size_t)N_EDGES * 4);
constexpr size_t U_HB    = 0;                                        // [MP,132]
constexpr size_t U_Y     = U_HB   + rnd64((size_t)MP * HID);         // [MP,YW]
constexpr size_t U_ABF   = U_Y    + rnd64((size_t)MP * YW);          // [MP,160]
constexpr size_t U_ABG   = U_ABF  + rnd64((size_t)MP * 160);         // [MP,288]
constexpr size_t U_BTG   = U_ABG  + rnd64((size_t)MP * 288);         // [192,288]
constexpr size_t U_BTGCN = U_BTG  + rnd64(192 * 288);                // [192,64]
constexpr size_t U_BTY1  = U_BTGCN+ rnd64(192 * 64);                 // [192,544]
constexpr size_t U_BTY2  = U_BTY1 + rnd64(192 * 544);                // [192,544]
constexpr size_t U_BTS1  = U_BTY2 + rnd64(192 * 544);                // [1024,160]
constexpr size_t U_BTS2  = U_BTS1 + rnd64(1024 * 160);               // [128,1024]
constexpr size_t U_BTE1  = U_BTS2 + rnd64(128 * 1024);               // [64,160]
constexpr size_t U_BTE2  = U_BTE1 + rnd64(64 * 160);                 // [64,160]

// ---------------- bf16 helpers ----------------
__device__ inline u16 f2bf(float f) {
    u32 u = __float_as_uint(f);
    return (u16)((u + 0x7fffu + ((u >> 16) & 1u)) >> 16);
}
__device__ inline u32 pk2(float a, float b) { return (u32)f2bf(a) | ((u32)f2bf(b) << 16); }
__device__ inline float bflo(u32 w) { return __uint_as_float(w << 16); }
__device__ inline float bfhi(u32 w) { return __uint_as_float(w & 0xffff0000u); }
__device__ inline float bf1(u16 x) { return __uint_as_float((u32)x << 16); }
__device__ inline u32 encf(float x) {
    u32 u = __float_as_uint(x);
    return (u & 0x80000000u) ? ~u : (u | 0x80000000u);
}
__device__ inline float decf(u32 e) {
    u32 u = (e & 0x80000000u) ? (e & 0x7fffffffu) : ~e;
    return __uint_as_float(u);
}

typedef __attribute__((ext_vector_type(8))) short s8b;
typedef __attribute__((ext_vector_type(4))) float f32x4;

// ---------------- CSR build ----------------
__global__ void k_count(const int* __restrict__ ei, const float* __restrict__ ew,
                        int* __restrict__ counts, float* __restrict__ wdeg) {
    int e = blockIdx.x * 256 + threadIdx.x;
    if (e < N_EDGES) {
        int dst = ei[N_EDGES + e];
        atomicAdd(&counts[dst], 1);
        atomicAdd(&wdeg[dst], ew[e]);
    }
}

__global__ __launch_bounds__(256) void k_bsum(const int* __restrict__ counts,
                                              const float* __restrict__ wdeg,
                                              int* __restrict__ bsum,
                                              float* __restrict__ dis) {
    int i = blockIdx.x * 256 + threadIdx.x;
    int v = (i < N_NODES) ? counts[i] : 0;
    if (i < N_NODES) {
        float d = 1.f + wdeg[i];
        dis[i] = (d > 0.f) ? rsqrtf(fmaxf(d, 1e-12f)) : 0.f;
    }
    int x = v;
    #pragma unroll
    for (int off = 1; off < 64; off <<= 1) x += __shfl_xor(x, off);
    __shared__ int ws4[4];
    if ((threadIdx.x & 63) == 0) ws4[threadIdx.x >> 6] = x;
    __syncthreads();
    if (threadIdx.x == 0) bsum[blockIdx.x] = ws4[0] + ws4[1] + ws4[2] + ws4[3];
}

__global__ __launch_bounds__(64) void k_scan2(const int* __restrict__ bsum,
                                              int* __restrict__ boff) {
    int t = threadIdx.x;
    int a = (2 * t < NBLK) ? bsum[2 * t] : 0;
    int b = (2 * t + 1 < NBLK) ? bsum[2 * t + 1] : 0;
    int loc = a + b, x = loc;
    #pragma unroll
    for (int off = 1; off < 64; off <<= 1) {
        int y = __shfl_up(x, off);
        if (t >= off) x += y;
    }
    int excl = x - loc;
    if (2 * t < NBLK) boff[2 * t] = excl;
    if (2 * t + 1 < NBLK) boff[2 * t + 1] = excl + a;
}

__global__ __launch_bounds__(256) void k_apply(int* __restrict__ counts,
                                               const int* __restrict__ boff,
                                               int* __restrict__ indptr) {
    int b = blockIdx.x;
    int i = b * 256 + threadIdx.x;
    int v = (i < N_NODES) ? counts[i] : 0;
    const int lane = threadIdx.x & 63, w = threadIdx.x >> 6;
    int x = v;
    #pragma unroll
    for (int off = 1; off < 64; off <<= 1) {
        int y = __shfl_up(x, off);
        if (lane >= off) x += y;
    }
    __shared__ int wsum[4];
    if (lane == 63) wsum[w] = x;
    __syncthreads();
    int add = boff[b];
    for (int k2 = 0; k2 < w; ++k2) add += wsum[k2];
    if (i < N_NODES) {
        indptr[i] = add + x - v;
        counts[i] = 0;
    }
    if (i == N_NODES) indptr[N_NODES] = N_EDGES;
}

__global__ void k_scatter(const int* __restrict__ ei, const float* __restrict__ ew,
                          const int* __restrict__ indptr, int* __restrict__ cursor,
                          int* __restrict__ csr_src, float* __restrict__ csr_w) {
    int e = blockIdx.x * 256 + threadIdx.x;
    if (e >= N_EDGES) return;
    int src = ei[e];
    int dst = ei[N_EDGES + e];
    int pos = indptr[dst] + atomicAdd(&cursor[dst], 1);
    csr_src[pos] = src;
    csr_w[pos] = ew[e];
}

// ---------------- merged weight + X conversion ----------------
constexpr int S0 = 192 * 288;    // BTG
constexpr int S1 = 192 * 64;     // BTGCN
constexpr int S2 = 192 * 544;    // BTY1 (0.25*Wgat1 stacked per head)
constexpr int S3 = 192 * 544;    // BTY2
constexpr int S4 = 1024 * 160;   // BTS1
constexpr int S5 = 128 * 1024;   // BTS2
constexpr int S6 = N_NODES * 64; // X -> ABF
constexpr int S7 = 2 * 64 * 160; // BTE1/BTE2 composite es/ed weights (rows 8..63 zero)
constexpr int SW_TOT = S0 + S1 + S2 + S3 + S4 + S5 + S6 + S7;

__global__ void k_cvtW(const float* __restrict__ Wfc1, const float* __restrict__ Wfc2,
                       const float* __restrict__ Wgcn, const float* __restrict__ Wgat1,
                       const float* __restrict__ Wgat2, const float* __restrict__ Wg1,
                       const float* __restrict__ Wg2, const float* __restrict__ X,
                       const float* __restrict__ as1, const float* __restrict__ ad1,
                       const float* __restrict__ as2, const float* __restrict__ ad2,
                       u16* __restrict__ BTG, u16* __restrict__ BTGCN,
                       u16* __restrict__ BTY1, u16* __restrict__ BTY2,
                       u16* __restrict__ BTS1, u16* __restrict__ BTS2,
                       u16* __restrict__ BTE1, u16* __restrict__ BTE2,
                       u16* __restrict__ ABF) {
    int idx = blockIdx.x * 256 + threadIdx.x;
    if (idx < S0) {
        int n = idx / 288, k = idx - n * 288;
        u16 v = 0;
        if (n < HID) {
            if (k < HID) v = f2bf(Wfc1[(size_t)k * HID + n]);
            else if (k < 2 * HID) v = f2bf(Wfc2[(size_t)(k - HID) * HID + n]);
        }
        BTG[idx] = v;
        return;
    }
    idx -= S0;
    if (idx < S1) {
        int n = idx / 64, k = idx - n * 64;
        BTGCN[idx] = (k < F_IN && n < HID) ? f2bf(Wgcn[(size_t)k * HID + n]) : (u16)0;
        return;
    }
    idx -= S1;
    if (idx < S2 + S3) {
        int l = (idx >= S2);
        int li = l ? (idx - S2) : idx;
        int n = li / 544, c = li - n * 544;
        int k = c / 136, j = c - k * 136;
        const float* W = l ? Wgat2 : Wgat1;
        u16 v = 0;
        if (n < HID && j < HID) v = f2bf(0.25f * W[(size_t)j * HID4 + k * HID + n]);
        (l ? BTY2 : BTY1)[li] = v;
        return;
    }
    idx -= S2 + S3;
    if (idx < S4) {
        int n = idx / 160, k = idx - n * 160;
        BTS1[idx] = (k < HID) ? f2bf(Wg1[(size_t)k * GFC + n]) : (u16)0;
        return;
    }
    idx -= S4;
    if (idx < S5) {
        int n = idx / 1024, k = idx - n * 1024;
        BTS2[idx] = f2bf(Wg2[(size_t)k * OUT_DIM + n]);
        return;
    }
    idx -= S5;
    if (idx < S6) {
        int r = idx / 64, k = idx - r * 64;
        ABF[idx] = (k < F_IN) ? f2bf(X[(size_t)r * F_IN + k]) : (u16)0;
        return;
    }
    idx -= S6;
    if (idx < S7) {
        int l = idx / (64 * 160); idx -= l * (64 * 160);
        int q = idx / 160;  int c = idx - q * 160;
        u16 v = 0;
        if (q < 8 && c < HID) {
            int k = q & 3;
            const float* W = l ? Wgat2 : Wgat1;
            const float* a = (q < 4) ? (l ? as2 : as1) : (l ? ad2 : ad1);
            const float* wr = W + (size_t)c * HID4 + k * HID;
            const float* ar = a + k * HID;
            float sum = 0.f;
            for (int cc = 0; cc < HID; ++cc) sum += wr[cc] * ar[cc];
            v = f2bf(sum);
        }
        (l ? BTE2 : BTE1)[q * 160 + c] = v;
    }
}

// ---------------- MFMA bf16 GEMM, NT column-tiles per block (A read once) ----
template <int NT>
__global__ __launch_bounds__(256) void k_gemm(
    const u16* __restrict__ A, const u16* __restrict__ Bt,
    int M, int N, int Kp,
    float* __restrict__ Cf,
    u16* __restrict__ Cb, int ldcb,
    u16* __restrict__ Cb2, int ldcb2, int coff2,
    const float* __restrict__ bias, int relu, int gate,
    const float* __restrict__ b2, const float* __restrict__ pb,
    u32* __restrict__ genc) {
    const int bm = blockIdx.x * 64;
    const int w = threadIdx.x >> 6;
    const int lane = threadIdx.x & 63;
    const int m16 = lane & 15;
    const int quad = lane >> 4;
    const u16* Ab = A + (size_t)(bm + m16) * Kp + quad * 8;
    const u16* Bb[NT];
    #pragma unroll
    for (int j = 0; j < NT; ++j)
        Bb[j] = Bt + (size_t)(j * 64 + w * 16 + m16) * Kp + quad * 8;
    f32x4 acc[NT][4];
    #pragma unroll
    for (int j = 0; j < NT; ++j)
        #pragma unroll
        for (int r = 0; r < 4; ++r) acc[j][r] = (f32x4){0.f, 0.f, 0.f, 0.f};
    for (int k0 = 0; k0 < Kp; k0 += 32) {
        s8b a0 = *(const s8b*)(Ab + k0);
        s8b a1 = *(const s8b*)(Ab + (size_t)16 * Kp + k0);
        s8b a2 = *(const s8b*)(Ab + (size_t)32 * Kp + k0);
        s8b a3 = *(const s8b*)(Ab + (size_t)48 * Kp + k0);
        #pragma unroll
        for (int j = 0; j < NT; ++j) {
            s8b b = *(const s8b*)(Bb[j] + k0);
            acc[j][0] = __builtin_amdgcn_mfma_f32_16x16x32_bf16(a0, b, acc[j][0], 0, 0, 0);
            acc[j][1] = __builtin_amdgcn_mfma_f32_16x16x32_bf16(a1, b, acc[j][1], 0, 0, 0);
            acc[j][2] = __builtin_amdgcn_mfma_f32_16x16x32_bf16(a2, b, acc[j][2], 0, 0, 0);
            acc[j][3] = __builtin_amdgcn_mfma_f32_16x16x32_bf16(a3, b, acc[j][3], 0, 0, 0);
        }
    }
    const int g0 = (bm * GRAPHS) / N_NODES;
    int gend = bm + 63; if (gend >= M) gend = M - 1;
    const int g1 = (gend * GRAPHS) / N_NODES;
    #pragma unroll
    for (int j = 0; j < NT; ++j) {
        const int col = j * 64 + w * 16 + m16;
        const bool colok = col < N;
        float bsum = 0.f;
        if (colok) {
            if (gate) bsum = bias[col] + b2[col] + pb[col];
            else if (bias) bsum = bias[col];
        }
        float mx0 = -3.4e38f, mx1 = -3.4e38f;
        #pragma unroll
        for (int r = 0; r < 4; ++r) {
            #pragma unroll
            for (int jj = 0; jj < 4; ++jj) {
                int row = bm + r * 16 + quad * 4 + jj;
                if (row >= M || !colok) continue;
                float v = acc[j][r][jj] + bsum;
                float res;
                if (gate) {
                    float z = 1.f / (1.f + expf(-v));
                    float xcv = bf1(A[(size_t)row * Kp + col]);
                    float xpv = bf1(A[(size_t)row * Kp + 132 + col]);
                    res = z * xcv + (1.f - z) * xpv;
                } else {
                    if (relu) v = fmaxf(v, 0.f);
                    res = v;
                }
                if (genc) {
                    int gid = (row * GRAPHS) / N_NODES;
                    if (gid == g0) mx0 = fmaxf(mx0, res);
                    else           mx1 = fmaxf(mx1, res);
                }
                if (Cf) Cf[(size_t)row * N + col] = res;
                if (Cb) Cb[(size_t)row * ldcb + col] = f2bf(res);
                if (Cb2) Cb2[(size_t)row * ldcb2 + coff2 + col] = f2bf(res);
            }
        }
        if (genc && colok) {
            mx0 = fmaxf(mx0, __shfl_xor(mx0, 16));
            mx0 = fmaxf(mx0, __shfl_xor(mx0, 32));
            if (g1 != g0) {
                mx1 = fmaxf(mx1, __shfl_xor(mx1, 16));
                mx1 = fmaxf(mx1, __shfl_xor(mx1, 32));
            }
            if (quad == 0) {
                atomicMax(&genc[g0 * HID + col], encf(mx0));
                if (g1 != g0) atomicMax(&genc[g1 * HID + col], encf(mx1));
            }
        }
    }
}

// ---------------- GCN aggregate (bf16 gather, unroll-4) ----------------
__global__ __launch_bounds__(256) void k_gcn_agg(
    const u16* __restrict__ hb, const int* __restrict__ indptr,
    const int* __restrict__ csr_src, const float* __restrict__ csr_w,
    const float* __restrict__ dis, const float* __restrict__ bias,
    u16* __restrict__ abf, u16* __restrict__ abg) {
    const int w = threadIdx.x >> 6, t = threadIdx.x & 63;
    const int i = blockIdx.x * 4 + w;
    const float di = dis[i];
    const int s = indptr[i], e = indptr[i + 1];
    const float nself = di * di;
    const u32* ru = (const u32*)(hb + (size_t)i * HID);
    u32 wv = ru[t];
    float aLo = nself * bflo(wv), aHi = nself * bfhi(wv);
    float bLo = 0.f, bHi = 0.f;
    if (t < 2) { u32 w2 = ru[64 + t]; bLo = nself * bflo(w2); bHi = nself * bfhi(w2); }
    int j = s;
    for (; j + 3 < e; j += 4) {
        int s0 = csr_src[j], s1 = csr_src[j + 1], s2 = csr_src[j + 2], s3 = csr_src[j + 3];
        float n0 = dis[s0] * csr_w[j]     * di;
        float n1 = dis[s1] * csr_w[j + 1] * di;
        float n2 = dis[s2] * csr_w[j + 2] * di;
        float n3 = dis[s3] * csr_w[j + 3] * di;
        const u32* p0 = (const u32*)(hb + (size_t)s0 * HID);
        const u32* p1 = (const u32*)(hb + (size_t)s1 * HID);
        const u32* p2 = (const u32*)(hb + (size_t)s2 * HID);
        const u32* p3 = (const u32*)(hb + (size_t)s3 * HID);
        u32 w0 = p0[t], w1 = p1[t], w2 = p2[t], w3 = p3[t];
        aLo += n0 * bflo(w0) + n1 * bflo(w1) + n2 * bflo(w2) + n3 * bflo(w3);
        aHi += n0 * bfhi(w0) + n1 * bfhi(w1) + n2 * bfhi(w2) + n3 * bfhi(w3);
        if (t < 2) {
            u32 y0 = p0[64 + t], y1 = p1[64 + t], y2 = p2[64 + t], y3 = p3[64 + t];
            bLo += n0 * bflo(y0) + n1 * bflo(y1) + n2 * bflo(y2) + n3 * bflo(y3);
            bHi += n0 * bfhi(y0) + n1 * bfhi(y1) + n2 * bfhi(y2) + n3 * bfhi(y3);
        }
    }
    for (; j < e; ++j) {
        int src = csr_src[j];
        float nb = dis[src] * csr_w[j] * di;
        const u32* su = (const u32*)(hb + (size_t)src * HID);
        u32 ws = su[t];
        aLo += nb * bflo(ws);
        aHi += nb * bfhi(ws);
        if (t < 2) { u32 w2 = su[64 + t]; bLo += nb * bflo(w2); bHi += nb * bfhi(w2); }
    }
    float v0 = fmaxf(aLo + bias[2 * t], 0.f);
    float v1 = fmaxf(aHi + bias[2 * t + 1], 0.f);
    u32* fa = (u32*)(abf + (size_t)i * 160);
    u32* ga = (u32*)(abg + (size_t)i * 288);
    u32 p = pk2(v0, v1);
    fa[t] = p;
    ga[66 + t] = p;
    if (t < 2) {
        float v2 = fmaxf(bLo + bias[128 + 2 * t], 0.f);
        float v3 = fmaxf(bHi + bias[129 + 2 * t], 0.f);
        u32 pk = pk2(v2, v3);
        fa[64 + t] = pk;
        ga[130 + t] = pk;
    }
    if (t >= 2 && t < 16) fa[64 + t] = 0;   // zero pad cols 132..159
}

// ---------------- GAT softmax + x-domain aggregate (4-head fused gather) -----
// y[dst, k, :] = alpha_self^k * x[dst] + sum_e alpha_e^k * x[src_e]   (bf16 out)
__global__ __launch_bounds__(256) void k_gat_node(
    const u16* __restrict__ xt, const float* __restrict__ esd,
    const int* __restrict__ indptr, const int* __restrict__ csr_src,
    float* __restrict__ tmp, u16* __restrict__ y) {
    __shared__ __align__(16) float al[4][CAP * 4];
    __shared__ int srcl[4][CAP];
    const int w = threadIdx.x >> 6, t = threadIdx.x & 63;
    const int i = blockIdx.x * 4 + w;
    const int k = t & 3;
    const int s = indptr[i];
    const int deg = indptr[i + 1] - s;
    const bool fast = (deg <= CAP);
    const float edk = esd[i * 8 + 4 + k];
    float eself = esd[i * 8 + k] + edk;
    eself = (eself >= 0.f) ? eself : 0.2f * eself;
    float m = eself;
    for (int j0 = 0; j0 < deg; j0 += 16) {
        int j = j0 + (t >> 2);
        float e = -1e30f;
        if (j < deg) {
            int src = csr_src[s + j];
            e = esd[src * 8 + k] + edk;
            e = (e >= 0.f) ? e : 0.2f * e;
            if (fast) { al[w][j * 4 + k] = e; if (k == 0) srcl[w][j] = src; }
            else tmp[(size_t)(s + j) * 4 + k] = e;
        }
        m = fmaxf(m, e);
    }
    m = fmaxf(m, __shfl_xor(m, 4));
    m = fmaxf(m, __shfl_xor(m, 8));
    m = fmaxf(m, __shfl_xor(m, 16));
    m = fmaxf(m, __shfl_xor(m, 32));
    float dsum = 0.f;
    for (int j0 = 0; j0 < deg; j0 += 16) {
        int j = j0 + (t >> 2);
        if (j < deg) {
            if (fast) {
                float ex = expf(al[w][j * 4 + k] - m);
                al[w][j * 4 + k] = ex;
                dsum += ex;
            } else {
                float ex = expf(tmp[(size_t)(s + j) * 4 + k] - m);
                tmp[(size_t)(s + j) * 4 + k] = ex;
                dsum += ex;
            }
        }
    }
    dsum += __shfl_xor(dsum, 4);
    dsum += __shfl_xor(dsum, 8);
    dsum += __shfl_xor(dsum, 16);
    dsum += __shfl_xor(dsum, 32);
    float exs = expf(eself - m);
    dsum += exs;
    float inv = 1.f / dsum;
    float aself = exs * inv;
    float a0 = __shfl(aself, 0), a1 = __shfl(aself, 1);
    float a2 = __shfl(aself, 2), a3 = __shfl(aself, 3);
    if (fast) {
        for (int idx = t; idx < deg * 4; idx += 64) al[w][idx] *= inv;
    }
    const u32* X = (const u32*)xt;   // row stride 80 u32 (160 u16)
    // self contribution
    float yL0, yH0, yL1, yH1, yL2, yH2, yL3, yH3;
    float zL0 = 0, zH0 = 0, zL1 = 0, zH1 = 0, zL2 = 0, zH2 = 0, zL3 = 0, zH3 = 0;
    {
        u32 v = X[(size_t)i * 80 + t];
        float lo = bflo(v), hi = bfhi(v);
        yL0 = a0 * lo; yH0 = a0 * hi;
        yL1 = a1 * lo; yH1 = a1 * hi;
        yL2 = a2 * lo; yH2 = a2 * hi;
        yL3 = a3 * lo; yH3 = a3 * hi;
        if (t < 2) {
            u32 v2 = X[(size_t)i * 80 + 64 + t];
            float l2 = bflo(v2), h2 = bfhi(v2);
            zL0 = a0 * l2; zH0 = a0 * h2;
            zL1 = a1 * l2; zH1 = a1 * h2;
            zL2 = a2 * l2; zH2 = a2 * h2;
            zL3 = a3 * l2; zH3 = a3 * h2;
        }
    }
    if (fast) {
        int j = 0;
        for (; j + 3 < deg; j += 4) {
            int s0 = srcl[w][j], s1 = srcl[w][j + 1], s2 = srcl[w][j + 2], s3 = srcl[w][j + 3];
            u32 v0 = X[(size_t)s0 * 80 + t];
            u32 v1 = X[(size_t)s1 * 80 + t];
            u32 v2 = X[(size_t)s2 * 80 + t];
            u32 v3 = X[(size_t)s3 * 80 + t];
            float4 x0 = *(const float4*)&al[w][j * 4];
            float4 x1 = *(const float4*)&al[w][j * 4 + 4];
            float4 x2 = *(const float4*)&al[w][j * 4 + 8];
            float4 x3 = *(const float4*)&al[w][j * 4 + 12];
            float l0 = bflo(v0), h0 = bfhi(v0), l1 = bflo(v1), h1 = bfhi(v1);
            float l2 = bflo(v2), h2 = bfhi(v2), l3 = bflo(v3), h3 = bfhi(v3);
            yL0 += x0.x * l0 + x1.x * l1 + x2.x * l2 + x3.x * l3;
            yH0 += x0.x * h0 + x1.x * h1 + x2.x * h2 + x3.x * h3;
            yL1 += x0.y * l0 + x1.y * l1 + x2.y * l2 + x3.y * l3;
            yH1 += x0.y * h0 + x1.y * h1 + x2.y * h2 + x3.y * h3;
            yL2 += x0.z * l0 + x1.z * l1 + x2.z * l2 + x3.z * l3;
            yH2 += x0.z * h0 + x1.z * h1 + x2.z * h2 + x3.z * h3;
            yL3 += x0.w * l0 + x1.w * l1 + x2.w * l2 + x3.w * l3;
            yH3 += x0.w * h0 + x1.w * h1 + x2.w * h2 + x3.w * h3;
            if (t < 2) {
                u32 e0 = X[(size_t)s0 * 80 + 64 + t];
                u32 e1 = X[(size_t)s1 * 80 + 64 + t];
                u32 e2 = X[(size_t)s2 * 80 + 64 + t];
                u32 e3 = X[(size_t)s3 * 80 + 64 + t];
                float el0 = bflo(e0), eh0 = bfhi(e0), el1 = bflo(e1), eh1 = bfhi(e1);
                float el2 = bflo(e2), eh2 = bfhi(e2), el3 = bflo(e3), eh3 = bfhi(e3);
                zL0 += x0.x * el0 + x1.x * el1 + x2.x * el2 + x3.x * el3;
                zH0 += x0.x * eh0 + x1.x * eh1 + x2.x * eh2 + x3.x * eh3;
                zL1 += x0.y * el0 + x1.y * el1 + x2.y * el2 + x3.y * el3;
                zH1 += x0.y * eh0 + x1.y * eh1 + x2.y * eh2 + x3.y * eh3;
                zL2 += x0.z * el0 + x1.z * el1 + x2.z * el2 + x3.z * el3;
                zH2 += x0.z * eh0 + x1.z * eh1 + x2.z * eh2 + x3.z * eh3;
                zL3 += x0.w * el0 + x1.w * el1 + x2.w * el2 + x3.w * el3;
                zH3 += x0.w * eh0 + x1.w * eh1 + x2.w * eh2 + x3.w * eh3;
            }
        }
        for (; j < deg; ++j) {
            int s0 = srcl[w][j];
            u32 v0 = X[(size_t)s0 * 80 + t];
            float4 x0 = *(const float4*)&al[w][j * 4];
            float l0 = bflo(v0), h0 = bfhi(v0);
            yL0 += x0.x * l0; yH0 += x0.x * h0;
            yL1 += x0.y * l0; yH1 += x0.y * h0;
            yL2 += x0.z * l0; yH2 += x0.z * h0;
            yL3 += x0.w * l0; yH3 += x0.w * h0;
            if (t < 2) {
                u32 e0 = X[(size_t)s0 * 80 + 64 + t];
                float el0 = bflo(e0), eh0 = bfhi(e0);
                zL0 += x0.x * el0; zH0 += x0.x * eh0;
                zL1 += x0.y * el0; zH1 += x0.y * eh0;
                zL2 += x0.z * el0; zH2 += x0.z * eh0;
                zL3 += x0.w * el0; zH3 += x0.w * eh0;
            }
        }
    } else {
        float inv0 = __shfl(inv, 0), inv1 = __shfl(inv, 1);
        float inv2 = __shfl(inv, 2), inv3 = __shfl(inv, 3);
        const float4* tmp4 = (const float4*)tmp;
        for (int j = 0; j < deg; ++j) {
            int src = csr_src[s + j];
            float4 ax = tmp4[s + j];
            float b0 = ax.x * inv0, b1 = ax.y * inv1, b2 = ax.z * inv2, b3 = ax.w * inv3;
            u32 v0 = X[(size_t)src * 80 + t];
            float l0 = bflo(v0), h0 = bfhi(v0);
            yL0 += b0 * l0; yH0 += b0 * h0;
            yL1 += b1 * l0; yH1 += b1 * h0;
            yL2 += b2 * l0; yH2 += b2 * h0;
            yL3 += b3 * l0; yH3 += b3 * h0;
            if (t < 2) {
                u32 e0 = X[(size_t)src * 80 + 64 + t];
                float el0 = bflo(e0), eh0 = bfhi(e0);
                zL0 += b0 * el0; zH0 += b0 * eh0;
                zL1 += b1 * el0; zH1 += b1 * eh0;
                zL2 += b2 * el0; zH2 += b2 * eh0;
                zL3 += b3 * el0; zH3 += b3 * eh0;
            }
        }
    }
    u32* yr = (u32*)(y + (size_t)i * YW);
    yr[t]       = pk2(yL0, yH0);
    yr[68 + t]  = pk2(yL1, yH1);
    yr[136 + t] = pk2(yL2, yH2);
    yr[204 + t] = pk2(yL3, yH3);
    if (t < 2) {
        yr[64 + t]  = pk2(zL0, zH0);
        yr[132 + t] = pk2(zL1, zH1);
        yr[200 + t] = pk2(zL2, zH2);
        yr[268 + t] = pk2(zL3, zH3);
    } else if (t < 4) {
        yr[64 + t] = 0; yr[132 + t] = 0; yr[200 + t] = 0; yr[268 + t] = 0;
    }
}

// ---------------- MLP head (pool fused into gate2 GEMM) ----------------------
__global__ __launch_bounds__(256) void k_head(
    const u32* __restrict__ genc, const u16* __restrict__ BTS1,
    const u16* __restrict__ BTS2, const float* __restrict__ b_g1,
    const float* __restrict__ b_g2, float* __restrict__ out) {
    __shared__ u32 g_sm[66];
    __shared__ float h_sm[GFC];
    __shared__ float part[OUT_DIM];
    const int g = blockIdx.x;
    const int tid = threadIdx.x;
    if (tid < 66) {
        float a0 = decf(genc[g * HID + 2 * tid]);
        float a1 = decf(genc[g * HID + 2 * tid + 1]);
        g_sm[tid] = pk2(a0, a1);
    }
    __syncthreads();
    #pragma unroll
    for (int r = 0; r < 4; ++r) {
        int o = tid + 256 * r;
        const u32* wr = (const u32*)(BTS1 + (size_t)o * 160);
        float acc = 0.f;
        for (int c = 0; c < 66; ++c) {
            u32 wv = wr[c], gv = g_sm[c];
            acc += bflo(wv) * bflo(gv) + bfhi(wv) * bfhi(gv);
        }
        acc = fmaxf(acc + b_g1[o], 0.f);
        h_sm[o] = __uint_as_float((u32)f2bf(acc) << 16);
    }
    __syncthreads();
    const int o = tid & 127, half = tid >> 7;
    const u32* wr2 = (const u32*)(BTS2 + (size_t)o * 1024 + half * 512);
    const float* hh = h_sm + half * 512;
    float acc = 0.f;
    for (int c = 0; c < 256; ++c) {
        u32 wv = wr2[c];
        acc += bflo(wv) * hh[2 * c] + bfhi(wv) * hh[2 * c + 1];
    }
    if (half == 1) part[o] = acc;
    __syncthreads();
    if (half == 0) out[(size_t)g * OUT_DIM + o] = acc + part[o] + b_g2[o];
}

// ---------------- launch ----------------
extern "C" void kernel_launch(void* const* d_in, const int* in_sizes, int n_in,
                              void* d_out, int out_size, void* d_ws, size_t ws_size,
                              hipStream_t stream) {
    const float* X       = (const float*)d_in[0];
    const int*   EI      = (const int*)d_in[1];
    const float* EW      = (const float*)d_in[2];
    const float* W_gcn   = (const float*)d_in[4];
    const float* b_gcn   = (const float*)d_in[5];
    const float* W_gat1  = (const float*)d_in[6];
    const float* a_src1  = (const float*)d_in[7];
    const float* a_dst1  = (const float*)d_in[8];
    const float* b_gat1  = (const float*)d_in[9];
    const float* W_gat2  = (const float*)d_in[10];
    const float* a_src2  = (const float*)d_in[11];
    const float* a_dst2  = (const float*)d_in[12];
    const float* b_gat2  = (const float*)d_in[13];
    const float* W_fc1   = (const float*)d_in[14];
    const float* b_fc1   = (const float*)d_in[15];
    const float* W_fc2   = (const float*)d_in[16];
    const float* b_fc2   = (const float*)d_in[17];
    const float* pro_bias= (const float*)d_in[18];
    const float* W_g1    = (const float*)d_in[19];
    const float* b_g1    = (const float*)d_in[20];
    const float* W_g2    = (const float*)d_in[21];
    const float* b_g2    = (const float*)d_in[22];
    float* OUT = (float*)d_out;

    float* ws = (float*)d_ws;
    float*    dis     = ws + O_DIS;
    int*      counts  = (int*)(ws + O_CNT);
    float*    wdeg    = ws + O_WDEG;
    int*      indptr  = (int*)(ws + O_IDP);
    int*      bsum    = (int*)(ws + O_BSUM);
    int*      boff    = (int*)(ws + O_BOFF);
    int*      csr_src = (int*)(ws + O_CSR_S);
    float*    csr_w   = ws + O_CSR_W;
    float*    esd     = ws + O_ESD;
    u32*      genc    = (u32*)(ws + O_GE);
    float*    tmp     = ws + O_TMP;
    u16*      U       = (u16*)(ws + O_U);
    u16*      hb      = U + U_HB;
    u16*      y       = U + U_Y;
    u16*      ABF     = U + U_ABF;
    u16*      ABG     = U + U_ABG;
    u16*      BTG     = U + U_BTG;
    u16*      BTGCN   = U + U_BTGCN;
    u16*      BTY1    = U + U_BTY1;
    u16*      BTY2    = U + U_BTY2;
    u16*      BTS1    = U + U_BTS1;
    u16*      BTS2    = U + U_BTS2;
    u16*      BTE1    = U + U_BTE1;
    u16*      BTE2    = U + U_BTE2;

    const int EB = (N_EDGES + 255) / 256;
    const int NB4 = N_NODES / 4;   // 7500
    const int GB_ = MP / 64;       // 469

    // ---- CSR build ----
    hipMemsetAsync(counts, 0, 2 * rnd64(N_NODES) * sizeof(int), stream);
    hipMemsetAsync(genc, 0, GRAPHS * HID * sizeof(u32), stream);
    k_count<<<EB, 256, 0, stream>>>(EI, EW, counts, wdeg);
    k_bsum<<<NBLK, 256, 0, stream>>>(counts, wdeg, bsum, dis);
    k_scan2<<<1, 64, 0, stream>>>(bsum, boff);
    k_apply<<<NBLK, 256, 0, stream>>>(counts, boff, indptr);
    k_scatter<<<EB, 256, 0, stream>>>(EI, EW, indptr, counts, csr_src, csr_w);

    // ---- weight conversions ----
    k_cvtW<<<(SW_TOT + 255) / 256, 256, 0, stream>>>(
        W_fc1, W_fc2, W_gcn, W_gat1, W_gat2, W_g1, W_g2, X,
        a_src1, a_dst1, a_src2, a_dst2,
        BTG, BTGCN, BTY1, BTY2, BTS1, BTS2, BTE1, BTE2, ABF);

    // ---- GCN ----
    k_gemm<3><<<GB_, 256, 0, stream>>>(ABF, BTGCN, N_NODES, HID, 64,
                                       nullptr, hb, HID, nullptr, 0, 0,
                                       nullptr, 0, 0, nullptr, nullptr, nullptr);
    k_gcn_agg<<<NB4, 256, 0, stream>>>(hb, indptr, csr_src, csr_w, dis, b_gcn, ABF, ABG);

    // ---- GAT layer 1 ----
    k_gemm<1><<<GB_, 256, 0, stream>>>(ABF, BTE1, N_NODES, 8, 160,
                                       esd, nullptr, 0, nullptr, 0, 0,
                                       nullptr, 0, 0, nullptr, nullptr, nullptr);
    k_gat_node<<<NB4, 256, 0, stream>>>(ABF, esd, indptr, csr_src, tmp, y);
    k_gemm<3><<<GB_, 256, 0, stream>>>(y, BTY1, N_NODES, HID, YW,
                                       nullptr, ABG, 288, nullptr, 0, 0,
                                       b_gat1, 1, 0, nullptr, nullptr, nullptr);
    // gate 1: x2 bf16 -> ABF (x-table for layer 2) + ABG cols 132.. (xp for gate2)
    k_gemm<3><<<GB_, 256, 0, stream>>>(ABG, BTG, N_NODES, HID, 288,
                                       nullptr, ABF, 160, ABG, 288, 132,
                                       b_fc1, 0, 1, b_fc2, pro_bias, nullptr);

    // ---- GAT layer 2 ----
    k_gemm<1><<<GB_, 256, 0, stream>>>(ABF, BTE2, N_NODES, 8, 160,
                                       esd, nullptr, 0, nullptr, 0, 0,
                                       nullptr, 0, 0, nullptr, nullptr, nullptr);
    k_gat_node<<<NB4, 256, 0, stream>>>(ABF, esd, indptr, csr_src, tmp, y);
    k_gemm<3><<<GB_, 256, 0, stream>>>(y, BTY2, N_NODES, HID, YW,
                                       nullptr, ABG, 288, nullptr, 0, 0,
                                       b_gat2, 0, 0, nullptr, nullptr, nullptr);
    // gate 2: pool directly into genc
    k_gemm<3><<<GB_, 256, 0, stream>>>(ABG, BTG, N_NODES, HID, 288,
                                       nullptr, nullptr, 0, nullptr, 0, 0,
                                       b_fc1, 0, 1, b_fc2, pro_bias, genc);

    // ---- MLP head ----
    k_head<<<GRAPHS, 256, 0, stream>>>(genc, BTS1, BTS2, b_g1, b_g2, OUT);
}

// Round 10
// 405.787 us; speedup vs baseline: 2.5521x; 1.0566x over previous
//
#include <hip/hip_runtime.h>

// ---------------- problem constants ----------------
constexpr int N_NODES = 30000;
constexpr int N_EDGES = 300000;
constexpr int GRAPHS  = 64;
constexpr int F_IN    = 33;
constexpr int HID     = 132;
constexpr int HID4    = 528;
constexpr int OUT_DIM = 128;
constexpr int GFC     = 1024;
constexpr int MP      = 30016;
constexpr int CAP     = 128;
constexpr int NBLK    = 118;           // ceil(N_NODES/256)
constexpr int YW      = 544;           // y row stride u16

typedef unsigned int u32;
typedef unsigned short u16;

// ---------------- workspace layout ----------------
constexpr size_t rnd64(size_t x) { return (x + 63) & ~(size_t)63; }
constexpr size_t O_DIS   = 0;
constexpr size_t O_CNT   = O_DIS   + rnd64(N_NODES);
constexpr size_t O_WDEG  = O_CNT   + rnd64(N_NODES);
constexpr size_t O_IDP   = O_WDEG  + rnd64(N_NODES);
constexpr size_t O_BSUM  = O_IDP   + rnd64(N_NODES + 1);
constexpr size_t O_CSR_S = O_BSUM  + rnd64(128);
constexpr size_t O_CSR_W = O_CSR_S + rnd64(N_EDGES);
constexpr size_t O_ESD   = O_CSR_W + rnd64(N_EDGES);                 // float, N*8
constexpr size_t O_GE    = O_ESD   + rnd64((size_t)N_NODES * 8);     // u32, G*HID
constexpr size_t O_CMP1  = O_GE    + rnd64(GRAPHS * HID);            // float, 8*132
constexpr size_t O_CMP2  = O_CMP1  + rnd64(8 * HID);
constexpr size_t O_TMP   = O_CMP2  + rnd64(8 * HID);                 // float, E*4
// u16 region
constexpr size_t O_U     = O_TMP   + rnd64((size_t)N_EDGES * 4);
constexpr size_t U_ABX   = 0;                                        // [MP,64] X bf16
constexpr size_t U_AGG   = U_ABX  + rnd64((size_t)MP * 64);          // [MP,64] aggX
constexpr size_t U_Y     = U_AGG  + rnd64((size_t)MP * 64);          // [MP,YW]
constexpr size_t U_ABF   = U_Y    + rnd64((size_t)MP * YW);          // [MP,160]
constexpr size_t U_ABG   = U_ABF  + rnd64((size_t)MP * 160);         // [MP,288]
constexpr size_t U_BTG   = U_ABG  + rnd64((size_t)MP * 288);         // [192,288]
constexpr size_t U_BTGCN = U_BTG  + rnd64(192 * 288);                // [192,64]
constexpr size_t U_BTY1  = U_BTGCN+ rnd64(192 * 64);                 // [192,544]
constexpr size_t U_BTY2  = U_BTY1 + rnd64(192 * 544);                // [192,544]
constexpr size_t U_BTS1  = U_BTY2 + rnd64(192 * 544);                // [1024,160]
constexpr size_t U_BTS2  = U_BTS1 + rnd64(1024 * 160);               // [128,1024]

// ---------------- bf16 helpers ----------------
__device__ inline u16 f2bf(float f) {
    u32 u = __float_as_uint(f);
    return (u16)((u + 0x7fffu + ((u >> 16) & 1u)) >> 16);
}
__device__ inline u32 pk2(float a, float b) { return (u32)f2bf(a) | ((u32)f2bf(b) << 16); }
__device__ inline float bflo(u32 w) { return __uint_as_float(w << 16); }
__device__ inline float bfhi(u32 w) { return __uint_as_float(w & 0xffff0000u); }
__device__ inline float bf1(u16 x) { return __uint_as_float((u32)x << 16); }
__device__ inline u32 encf(float x) {
    u32 u = __float_as_uint(x);
    return (u & 0x80000000u) ? ~u : (u | 0x80000000u);
}
__device__ inline float decf(u32 e) {
    u32 u = (e & 0x80000000u) ? (e & 0x7fffffffu) : ~e;
    return __uint_as_float(u);
}

typedef __attribute__((ext_vector_type(8))) short s8b;
typedef __attribute__((ext_vector_type(4))) float f32x4;

// ---------------- CSR build ----------------
__global__ void k_count(const int* __restrict__ ei, const float* __restrict__ ew,
                        int* __restrict__ counts, float* __restrict__ wdeg) {
    int e = blockIdx.x * 256 + threadIdx.x;
    if (e < N_EDGES) {
        int dst = ei[N_EDGES + e];
        atomicAdd(&counts[dst], 1);
        atomicAdd(&wdeg[dst], ew[e]);
    }
}

__global__ __launch_bounds__(256) void k_bsum(const int* __restrict__ counts,
                                              const float* __restrict__ wdeg,
                                              int* __restrict__ bsum,
                                              float* __restrict__ dis) {
    int i = blockIdx.x * 256 + threadIdx.x;
    int v = (i < N_NODES) ? counts[i] : 0;
    if (i < N_NODES) {
        float d = 1.f + wdeg[i];
        dis[i] = (d > 0.f) ? rsqrtf(fmaxf(d, 1e-12f)) : 0.f;
    }
    int x = v;
    #pragma unroll
    for (int off = 1; off < 64; off <<= 1) x += __shfl_xor(x, off);
    __shared__ int ws4[4];
    if ((threadIdx.x & 63) == 0) ws4[threadIdx.x >> 6] = x;
    __syncthreads();
    if (threadIdx.x == 0) bsum[blockIdx.x] = ws4[0] + ws4[1] + ws4[2] + ws4[3];
}

// indptr from counts; each block redundantly reduces bsum[0..b-1] (118 elems)
__global__ __launch_bounds__(256) void k_apply(int* __restrict__ counts,
                                               const int* __restrict__ bsum,
                                               int* __restrict__ indptr) {
    __shared__ int s1[4], s2[4];
    const int b = blockIdx.x;
    const int tid = threadIdx.x, lane = tid & 63, w = tid >> 6;
    int part = (tid < b) ? bsum[tid] : 0;      // b <= 117 < 256
    #pragma unroll
    for (int off = 1; off < 64; off <<= 1) part += __shfl_xor(part, off);
    if (lane == 0) s1[w] = part;
    int i = b * 256 + tid;
    int v = (i < N_NODES) ? counts[i] : 0;
    int x = v;
    #pragma unroll
    for (int off = 1; off < 64; off <<= 1) {
        int y = __shfl_up(x, off);
        if (lane >= off) x += y;
    }
    if (lane == 63) s2[w] = x;
    __syncthreads();
    int add = s1[0] + s1[1] + s1[2] + s1[3];
    for (int k2 = 0; k2 < w; ++k2) add += s2[k2];
    if (i < N_NODES) {
        indptr[i] = add + x - v;
        counts[i] = 0;   // becomes scatter cursor
    }
    if (i == N_NODES) indptr[N_NODES] = N_EDGES;
}

__global__ void k_scatter(const int* __restrict__ ei, const float* __restrict__ ew,
                          const int* __restrict__ indptr, int* __restrict__ cursor,
                          int* __restrict__ csr_src, float* __restrict__ csr_w) {
    int e = blockIdx.x * 256 + threadIdx.x;
    if (e >= N_EDGES) return;
    int src = ei[e];
    int dst = ei[N_EDGES + e];
    int pos = indptr[dst] + atomicAdd(&cursor[dst], 1);
    csr_src[pos] = src;
    csr_w[pos] = ew[e];
}

// ---------------- merged weight + X conversion + zeroing ----------------
constexpr int S0 = 192 * 288;    // BTG
constexpr int S1 = 192 * 64;     // BTGCN
constexpr int S2 = 192 * 544;    // BTY1
constexpr int S3 = 192 * 544;    // BTY2
constexpr int S4 = 1024 * 160;   // BTS1
constexpr int S5 = 128 * 1024;   // BTS2
constexpr int S6 = N_NODES * 64; // X -> ABX
constexpr int S7 = 2 * 8 * HID;  // comp fp32
constexpr int S8 = N_NODES + N_NODES + GRAPHS * HID;  // zero counts/wdeg/genc
constexpr int SW_TOT = S0 + S1 + S2 + S3 + S4 + S5 + S6 + S7 + S8;

__global__ void k_cvtW(const float* __restrict__ Wfc1, const float* __restrict__ Wfc2,
                       const float* __restrict__ Wgcn, const float* __restrict__ Wgat1,
                       const float* __restrict__ Wgat2, const float* __restrict__ Wg1,
                       const float* __restrict__ Wg2, const float* __restrict__ X,
                       const float* __restrict__ as1, const float* __restrict__ ad1,
                       const float* __restrict__ as2, const float* __restrict__ ad2,
                       u16* __restrict__ BTG, u16* __restrict__ BTGCN,
                       u16* __restrict__ BTY1, u16* __restrict__ BTY2,
                       u16* __restrict__ BTS1, u16* __restrict__ BTS2,
                       float* __restrict__ cmp1, float* __restrict__ cmp2,
                       u16* __restrict__ ABX,
                       u32* __restrict__ zc, u32* __restrict__ zw, u32* __restrict__ zg) {
    int idx = blockIdx.x * 256 + threadIdx.x;
    if (idx < S0) {
        int n = idx / 288, k = idx - n * 288;
        u16 v = 0;
        if (n < HID) {
            if (k < HID) v = f2bf(Wfc1[(size_t)k * HID + n]);
            else if (k < 2 * HID) v = f2bf(Wfc2[(size_t)(k - HID) * HID + n]);
        }
        BTG[idx] = v;
        return;
    }
    idx -= S0;
    if (idx < S1) {
        int n = idx / 64, k = idx - n * 64;
        BTGCN[idx] = (k < F_IN && n < HID) ? f2bf(Wgcn[(size_t)k * HID + n]) : (u16)0;
        return;
    }
    idx -= S1;
    if (idx < S2 + S3) {
        int l = (idx >= S2);
        int li = l ? (idx - S2) : idx;
        int n = li / 544, c = li - n * 544;
        int k = c / 136, j = c - k * 136;
        const float* W = l ? Wgat2 : Wgat1;
        u16 v = 0;
        if (n < HID && j < HID) v = f2bf(0.25f * W[(size_t)j * HID4 + k * HID + n]);
        (l ? BTY2 : BTY1)[li] = v;
        return;
    }
    idx -= S2 + S3;
    if (idx < S4) {
        int n = idx / 160, k = idx - n * 160;
        BTS1[idx] = (k < HID) ? f2bf(Wg1[(size_t)k * GFC + n]) : (u16)0;
        return;
    }
    idx -= S4;
    if (idx < S5) {
        int n = idx / 1024, k = idx - n * 1024;
        BTS2[idx] = f2bf(Wg2[(size_t)k * OUT_DIM + n]);
        return;
    }
    idx -= S5;
    if (idx < S6) {
        int r = idx / 64, k = idx - r * 64;
        ABX[idx] = (k < F_IN) ? f2bf(X[(size_t)r * F_IN + k]) : (u16)0;
        return;
    }
    idx -= S6;
    if (idx < S7) {
        int l = idx / (8 * HID); idx -= l * (8 * HID);
        int q = idx / HID;  int c = idx - q * HID;
        int k = q & 3;
        const float* W = l ? Wgat2 : Wgat1;
        const float* a = (q < 4) ? (l ? as2 : as1) : (l ? ad2 : ad1);
        const float* wr = W + (size_t)c * HID4 + k * HID;
        const float* ar = a + k * HID;
        float sum = 0.f;
        for (int cc = 0; cc < HID; ++cc) sum += wr[cc] * ar[cc];
        (l ? cmp2 : cmp1)[q * HID + c] = sum;
        return;
    }
    idx -= S7;
    if (idx < S8) {
        if (idx < N_NODES) zc[idx] = 0;
        else if (idx < 2 * N_NODES) zw[idx - N_NODES] = 0;
        else zg[idx - 2 * N_NODES] = 0;
    }
}

// ---------------- MFMA bf16 GEMM, NT column-tiles, optional fused esd --------
template <int NT, bool ESD>
__global__ __launch_bounds__(256) void k_gemm(
    const u16* __restrict__ A, const u16* __restrict__ Bt,
    int M, int N, int Kp,
    float* __restrict__ Cf,
    u16* __restrict__ Cb, int ldcb, int padN,
    u16* __restrict__ Cb2, int ldcb2, int coff2,
    const float* __restrict__ bias, int relu, int gate,
    const float* __restrict__ b2, const float* __restrict__ pb,
    u32* __restrict__ genc,
    const float* __restrict__ compG, float* __restrict__ esdOut) {
    __shared__ float xs[ESD ? 64 : 1][134];
    __shared__ float cmp[ESD ? 8 : 1][132];
    const int bm = blockIdx.x * 64;
    const int w = threadIdx.x >> 6;
    const int lane = threadIdx.x & 63;
    const int m16 = lane & 15;
    const int quad = lane >> 4;
    const u16* Ab = A + (size_t)(bm + m16) * Kp + quad * 8;
    const u16* Bb[NT];
    #pragma unroll
    for (int j = 0; j < NT; ++j)
        Bb[j] = Bt + (size_t)(j * 64 + w * 16 + m16) * Kp + quad * 8;
    f32x4 acc[NT][4];
    #pragma unroll
    for (int j = 0; j < NT; ++j)
        #pragma unroll
        for (int r = 0; r < 4; ++r) acc[j][r] = (f32x4){0.f, 0.f, 0.f, 0.f};
    for (int k0 = 0; k0 < Kp; k0 += 32) {
        s8b a0 = *(const s8b*)(Ab + k0);
        s8b a1 = *(const s8b*)(Ab + (size_t)16 * Kp + k0);
        s8b a2 = *(const s8b*)(Ab + (size_t)32 * Kp + k0);
        s8b a3 = *(const s8b*)(Ab + (size_t)48 * Kp + k0);
        #pragma unroll
        for (int j = 0; j < NT; ++j) {
            s8b b = *(const s8b*)(Bb[j] + k0);
            acc[j][0] = __builtin_amdgcn_mfma_f32_16x16x32_bf16(a0, b, acc[j][0], 0, 0, 0);
            acc[j][1] = __builtin_amdgcn_mfma_f32_16x16x32_bf16(a1, b, acc[j][1], 0, 0, 0);
            acc[j][2] = __builtin_amdgcn_mfma_f32_16x16x32_bf16(a2, b, acc[j][2], 0, 0, 0);
            acc[j][3] = __builtin_amdgcn_mfma_f32_16x16x32_bf16(a3, b, acc[j][3], 0, 0, 0);
        }
    }
    const int g0 = (bm * GRAPHS) / N_NODES;
    int gend = bm + 63; if (gend >= M) gend = M - 1;
    const int g1 = (gend * GRAPHS) / N_NODES;
    #pragma unroll
    for (int j = 0; j < NT; ++j) {
        const int col = j * 64 + w * 16 + m16;
        const bool colok = col < N;
        float bsum = 0.f;
        if (colok) {
            if (gate) bsum = bias[col] + b2[col] + pb[col];
            else if (bias) bsum = bias[col];
        }
        float mx0 = -3.4e38f, mx1 = -3.4e38f;
        #pragma unroll
        for (int r = 0; r < 4; ++r) {
            #pragma unroll
            for (int jj = 0; jj < 4; ++jj) {
                int row = bm + r * 16 + quad * 4 + jj;
                if (row >= M || !colok) continue;
                float v = acc[j][r][jj] + bsum;
                float res;
                if (gate) {
                    float z = 1.f / (1.f + expf(-v));
                    float xcv = bf1(A[(size_t)row * Kp + col]);
                    float xpv = bf1(A[(size_t)row * Kp + 132 + col]);
                    res = z * xcv + (1.f - z) * xpv;
                } else {
                    if (relu) v = fmaxf(v, 0.f);
                    res = v;
                }
                if constexpr (ESD) {
                    if (col < 132) xs[row - bm][col] = res;
                }
                if (genc) {
                    int gid = (row * GRAPHS) / N_NODES;
                    if (gid == g0) mx0 = fmaxf(mx0, res);
                    else           mx1 = fmaxf(mx1, res);
                }
                if (Cf) Cf[(size_t)row * N + col] = res;
                if (Cb) Cb[(size_t)row * ldcb + col] = f2bf(res);
                if (Cb2) Cb2[(size_t)row * ldcb2 + coff2 + col] = f2bf(res);
            }
        }
        if (genc && colok) {
            mx0 = fmaxf(mx0, __shfl_xor(mx0, 16));
            mx0 = fmaxf(mx0, __shfl_xor(mx0, 32));
            if (g1 != g0) {
                mx1 = fmaxf(mx1, __shfl_xor(mx1, 16));
                mx1 = fmaxf(mx1, __shfl_xor(mx1, 32));
            }
            if (quad == 0) {
                atomicMax(&genc[g0 * HID + col], encf(mx0));
                if (g1 != g0) atomicMax(&genc[g1 * HID + col], encf(mx1));
            }
        }
    }
    if constexpr (ESD) {
        for (int i2 = threadIdx.x; i2 < 8 * HID; i2 += 256)
            cmp[i2 / HID][i2 % HID] = compG[i2];
        __syncthreads();
        int row = threadIdx.x >> 2, q = threadIdx.x & 3;
        if (bm + row < M) {
            float s0 = 0.f, s1 = 0.f;
            for (int c = 0; c < HID; ++c) {
                float xv = xs[row][c];
                s0 += xv * cmp[q][c];
                s1 += xv * cmp[q + 4][c];
            }
            esdOut[(size_t)(bm + row) * 8 + q] = s0;
            esdOut[(size_t)(bm + row) * 8 + 4 + q] = s1;
        }
    }
}

// ---------------- GCN aggregate in X-domain (33 ch, 2 edges/wave-iter) -------
__global__ __launch_bounds__(256) void k_gcn_aggX(
    const u16* __restrict__ xb, const int* __restrict__ indptr,
    const int* __restrict__ csr_src, const float* __restrict__ csr_w,
    const float* __restrict__ dis, u16* __restrict__ aggx) {
    const int w = threadIdx.x >> 6, t = threadIdx.x & 63;
    const int i = blockIdx.x * 4 + w;
    const int g = t >> 5;    // edge subgroup 0/1
    const int c = t & 31;    // u32 word
    const float di = dis[i];
    const int s = indptr[i], e = indptr[i + 1];
    const u32* X32 = (const u32*)xb;
    float aLo = 0.f, aHi = 0.f;
    int j = s;
    for (; j + 3 < e; j += 4) {
        int j0 = j + g, j1 = j + 2 + g;
        int s0 = csr_src[j0], s1 = csr_src[j1];
        float n0 = dis[s0] * csr_w[j0] * di;
        float n1 = dis[s1] * csr_w[j1] * di;
        u32 v0 = X32[(size_t)s0 * 32 + c];
        u32 v1 = X32[(size_t)s1 * 32 + c];
        aLo += n0 * bflo(v0) + n1 * bflo(v1);
        aHi += n0 * bfhi(v0) + n1 * bfhi(v1);
    }
    for (; j < e; j += 2) {
        int jj = j + g;
        if (jj < e) {
            int s0 = csr_src[jj];
            float n0 = dis[s0] * csr_w[jj] * di;
            u32 v0 = X32[(size_t)s0 * 32 + c];
            aLo += n0 * bflo(v0);
            aHi += n0 * bfhi(v0);
        }
    }
    aLo += __shfl_xor(aLo, 32);
    aHi += __shfl_xor(aHi, 32);
    if (t < 32) {
        float nself = di * di;
        u32 v = X32[(size_t)i * 32 + t];
        aLo += nself * bflo(v);
        aHi += nself * bfhi(v);
        ((u32*)aggx)[(size_t)i * 32 + t] = pk2(aLo, aHi);
    }
}

// ---------------- GAT softmax + x-domain aggregate (4-head fused gather) -----
__global__ __launch_bounds__(256) void k_gat_node(
    const u16* __restrict__ xt, const float* __restrict__ esd,
    const int* __restrict__ indptr, const int* __restrict__ csr_src,
    float* __restrict__ tmp, u16* __restrict__ y) {
    __shared__ __align__(16) float al[4][CAP * 4];
    __shared__ int srcl[4][CAP];
    const int w = threadIdx.x >> 6, t = threadIdx.x & 63;
    const int i = blockIdx.x * 4 + w;
    const int k = t & 3;
    const int s = indptr[i];
    const int deg = indptr[i + 1] - s;
    const bool fast = (deg <= CAP);
    const float edk = esd[i * 8 + 4 + k];
    float eself = esd[i * 8 + k] + edk;
    eself = (eself >= 0.f) ? eself : 0.2f * eself;
    float m = eself;
    for (int j0 = 0; j0 < deg; j0 += 16) {
        int j = j0 + (t >> 2);
        float e = -1e30f;
        if (j < deg) {
            int src = csr_src[s + j];
            e = esd[src * 8 + k] + edk;
            e = (e >= 0.f) ? e : 0.2f * e;
            if (fast) { al[w][j * 4 + k] = e; if (k == 0) srcl[w][j] = src; }
            else tmp[(size_t)(s + j) * 4 + k] = e;
        }
        m = fmaxf(m, e);
    }
    m = fmaxf(m, __shfl_xor(m, 4));
    m = fmaxf(m, __shfl_xor(m, 8));
    m = fmaxf(m, __shfl_xor(m, 16));
    m = fmaxf(m, __shfl_xor(m, 32));
    float dsum = 0.f;
    for (int j0 = 0; j0 < deg; j0 += 16) {
        int j = j0 + (t >> 2);
        if (j < deg) {
            if (fast) {
                float ex = expf(al[w][j * 4 + k] - m);
                al[w][j * 4 + k] = ex;
                dsum += ex;
            } else {
                float ex = expf(tmp[(size_t)(s + j) * 4 + k] - m);
                tmp[(size_t)(s + j) * 4 + k] = ex;
                dsum += ex;
            }
        }
    }
    dsum += __shfl_xor(dsum, 4);
    dsum += __shfl_xor(dsum, 8);
    dsum += __shfl_xor(dsum, 16);
    dsum += __shfl_xor(dsum, 32);
    float exs = expf(eself - m);
    dsum += exs;
    float inv = 1.f / dsum;
    float aself = exs * inv;
    float a0 = __shfl(aself, 0), a1 = __shfl(aself, 1);
    float a2 = __shfl(aself, 2), a3 = __shfl(aself, 3);
    if (fast) {
        for (int idx = t; idx < deg * 4; idx += 64) al[w][idx] *= inv;
    }
    const u32* X = (const u32*)xt;   // row stride 80 u32
    float yL0, yH0, yL1, yH1, yL2, yH2, yL3, yH3;
    float zL0 = 0, zH0 = 0, zL1 = 0, zH1 = 0, zL2 = 0, zH2 = 0, zL3 = 0, zH3 = 0;
    {
        u32 v = X[(size_t)i * 80 + t];
        float lo = bflo(v), hi = bfhi(v);
        yL0 = a0 * lo; yH0 = a0 * hi;
        yL1 = a1 * lo; yH1 = a1 * hi;
        yL2 = a2 * lo; yH2 = a2 * hi;
        yL3 = a3 * lo; yH3 = a3 * hi;
        if (t < 2) {
            u32 v2 = X[(size_t)i * 80 + 64 + t];
            float l2 = bflo(v2), h2 = bfhi(v2);
            zL0 = a0 * l2; zH0 = a0 * h2;
            zL1 = a1 * l2; zH1 = a1 * h2;
            zL2 = a2 * l2; zH2 = a2 * h2;
            zL3 = a3 * l2; zH3 = a3 * h2;
        }
    }
    if (fast) {
        int j = 0;
        for (; j + 3 < deg; j += 4) {
            int s0 = srcl[w][j], s1 = srcl[w][j + 1], s2 = srcl[w][j + 2], s3 = srcl[w][j + 3];
            u32 v0 = X[(size_t)s0 * 80 + t];
            u32 v1 = X[(size_t)s1 * 80 + t];
            u32 v2 = X[(size_t)s2 * 80 + t];
            u32 v3 = X[(size_t)s3 * 80 + t];
            float4 x0 = *(const float4*)&al[w][j * 4];
            float4 x1 = *(const float4*)&al[w][j * 4 + 4];
            float4 x2 = *(const float4*)&al[w][j * 4 + 8];
            float4 x3 = *(const float4*)&al[w][j * 4 + 12];
            float l0 = bflo(v0), h0 = bfhi(v0), l1 = bflo(v1), h1 = bfhi(v1);
            float l2 = bflo(v2), h2 = bfhi(v2), l3 = bflo(v3), h3 = bfhi(v3);
            yL0 += x0.x * l0 + x1.x * l1 + x2.x * l2 + x3.x * l3;
            yH0 += x0.x * h0 + x1.x * h1 + x2.x * h2 + x3.x * h3;
            yL1 += x0.y * l0 + x1.y * l1 + x2.y * l2 + x3.y * l3;
            yH1 += x0.y * h0 + x1.y * h1 + x2.y * h2 + x3.y * h3;
            yL2 += x0.z * l0 + x1.z * l1 + x2.z * l2 + x3.z * l3;
            yH2 += x0.z * h0 + x1.z * h1 + x2.z * h2 + x3.z * h3;
            yL3 += x0.w * l0 + x1.w * l1 + x2.w * l2 + x3.w * l3;
            yH3 += x0.w * h0 + x1.w * h1 + x2.w * h2 + x3.w * h3;
            if (t < 2) {
                u32 e0 = X[(size_t)s0 * 80 + 64 + t];
                u32 e1 = X[(size_t)s1 * 80 + 64 + t];
                u32 e2 = X[(size_t)s2 * 80 + 64 + t];
                u32 e3 = X[(size_t)s3 * 80 + 64 + t];
                float el0 = bflo(e0), eh0 = bfhi(e0), el1 = bflo(e1), eh1 = bfhi(e1);
                float el2 = bflo(e2), eh2 = bfhi(e2), el3 = bflo(e3), eh3 = bfhi(e3);
                zL0 += x0.x * el0 + x1.x * el1 + x2.x * el2 + x3.x * el3;
                zH0 += x0.x * eh0 + x1.x * eh1 + x2.x * eh2 + x3.x * eh3;
                zL1 += x0.y * el0 + x1.y * el1 + x2.y * el2 + x3.y * el3;
                zH1 += x0.y * eh0 + x1.y * eh1 + x2.y * eh2 + x3.y * eh3;
                zL2 += x0.z * el0 + x1.z * el1 + x2.z * el2 + x3.z * el3;
                zH2 += x0.z * eh0 + x1.z * eh1 + x2.z * eh2 + x3.z * eh3;
                zL3 += x0.w * el0 + x1.w * el1 + x2.w * el2 + x3.w * el3;
                zH3 += x0.w * eh0 + x1.w * eh1 + x2.w * eh2 + x3.w * eh3;
            }
        }
        for (; j < deg; ++j) {
            int s0 = srcl[w][j];
            u32 v0 = X[(size_t)s0 * 80 + t];
            float4 x0 = *(const float4*)&al[w][j * 4];
            float l0 = bflo(v0), h0 = bfhi(v0);
            yL0 += x0.x * l0; yH0 += x0.x * h0;
            yL1 += x0.y * l0; yH1 += x0.y * h0;
            yL2 += x0.z * l0; yH2 += x0.z * h0;
            yL3 += x0.w * l0; yH3 += x0.w * h0;
            if (t < 2) {
                u32 e0 = X[(size_t)s0 * 80 + 64 + t];
                float el0 = bflo(e0), eh0 = bfhi(e0);
                zL0 += x0.x * el0; zH0 += x0.x * eh0;
                zL1 += x0.y * el0; zH1 += x0.y * eh0;
                zL2 += x0.z * el0; zH2 += x0.z * eh0;
                zL3 += x0.w * el0; zH3 += x0.w * eh0;
            }
        }
    } else {
        float inv0 = __shfl(inv, 0), inv1 = __shfl(inv, 1);
        float inv2 = __shfl(inv, 2), inv3 = __shfl(inv, 3);
        const float4* tmp4 = (const float4*)tmp;
        for (int j = 0; j < deg; ++j) {
            int src = csr_src[s + j];
            float4 ax = tmp4[s + j];
            float b0 = ax.x * inv0, b1 = ax.y * inv1, b2 = ax.z * inv2, b3 = ax.w * inv3;
            u32 v0 = X[(size_t)src * 80 + t];
            float l0 = bflo(v0), h0 = bfhi(v0);
            yL0 += b0 * l0; yH0 += b0 * h0;
            yL1 += b1 * l0; yH1 += b1 * h0;
            yL2 += b2 * l0; yH2 += b2 * h0;
            yL3 += b3 * l0; yH3 += b3 * h0;
            if (t < 2) {
                u32 e0 = X[(size_t)src * 80 + 64 + t];
                float el0 = bflo(e0), eh0 = bfhi(e0);
                zL0 += b0 * el0; zH0 += b0 * eh0;
                zL1 += b1 * el0; zH1 += b1 * eh0;
                zL2 += b2 * el0; zH2 += b2 * eh0;
                zL3 += b3 * el0; zH3 += b3 * eh0;
            }
        }
    }
    u32* yr = (u32*)(y + (size_t)i * YW);
    yr[t]       = pk2(yL0, yH0);
    yr[68 + t]  = pk2(yL1, yH1);
    yr[136 + t] = pk2(yL2, yH2);
    yr[204 + t] = pk2(yL3, yH3);
    if (t < 2) {
        yr[64 + t]  = pk2(zL0, zH0);
        yr[132 + t] = pk2(zL1, zH1);
        yr[200 + t] = pk2(zL2, zH2);
        yr[268 + t] = pk2(zL3, zH3);
    } else if (t < 4) {
        yr[64 + t] = 0; yr[132 + t] = 0; yr[200 + t] = 0; yr[268 + t] = 0;
    }
}

// ---------------- MLP head ----------------
__global__ __launch_bounds__(256) void k_head(
    const u32* __restrict__ genc, const u16* __restrict__ BTS1,
    const u16* __restrict__ BTS2, const float* __restrict__ b_g1,
    const float* __restrict__ b_g2, float* __restrict__ out) {
    __shared__ u32 g_sm[66];
    __shared__ float h_sm[GFC];
    __shared__ float part[OUT_DIM];
    const int g = blockIdx.x;
    const int tid = threadIdx.x;
    if (tid < 66) {
        float a0 = decf(genc[g * HID + 2 * tid]);
        float a1 = decf(genc[g * HID + 2 * tid + 1]);
        g_sm[tid] = pk2(a0, a1);
    }
    __syncthreads();
    #pragma unroll
    for (int r = 0; r < 4; ++r) {
        int o = tid + 256 * r;
        const u32* wr = (const u32*)(BTS1 + (size_t)o * 160);
        float acc = 0.f;
        for (int c = 0; c < 66; ++c) {
            u32 wv = wr[c], gv = g_sm[c];
            acc += bflo(wv) * bflo(gv) + bfhi(wv) * bfhi(gv);
        }
        acc = fmaxf(acc + b_g1[o], 0.f);
        h_sm[o] = __uint_as_float((u32)f2bf(acc) << 16);
    }
    __syncthreads();
    const int o = tid & 127, half = tid >> 7;
    const u32* wr2 = (const u32*)(BTS2 + (size_t)o * 1024 + half * 512);
    const float* hh = h_sm + half * 512;
    float acc = 0.f;
    for (int c = 0; c < 256; ++c) {
        u32 wv = wr2[c];
        acc += bflo(wv) * hh[2 * c] + bfhi(wv) * hh[2 * c + 1];
    }
    if (half == 1) part[o] = acc;
    __syncthreads();
    if (half == 0) out[(size_t)g * OUT_DIM + o] = acc + part[o] + b_g2[o];
}

// ---------------- launch ----------------
extern "C" void kernel_launch(void* const* d_in, const int* in_sizes, int n_in,
                              void* d_out, int out_size, void* d_ws, size_t ws_size,
                              hipStream_t stream) {
    const float* X       = (const float*)d_in[0];
    const int*   EI      = (const int*)d_in[1];
    const float* EW      = (const float*)d_in[2];
    const float* W_gcn   = (const float*)d_in[4];
    const float* b_gcn   = (const float*)d_in[5];
    const float* W_gat1  = (const float*)d_in[6];
    const float* a_src1  = (const float*)d_in[7];
    const float* a_dst1  = (const float*)d_in[8];
    const float* b_gat1  = (const float*)d_in[9];
    const float* W_gat2  = (const float*)d_in[10];
    const float* a_src2  = (const float*)d_in[11];
    const float* a_dst2  = (const float*)d_in[12];
    const float* b_gat2  = (const float*)d_in[13];
    const float* W_fc1   = (const float*)d_in[14];
    const float* b_fc1   = (const float*)d_in[15];
    const float* W_fc2   = (const float*)d_in[16];
    const float* b_fc2   = (const float*)d_in[17];
    const float* pro_bias= (const float*)d_in[18];
    const float* W_g1    = (const float*)d_in[19];
    const float* b_g1    = (const float*)d_in[20];
    const float* W_g2    = (const float*)d_in[21];
    const float* b_g2    = (const float*)d_in[22];
    float* OUT = (float*)d_out;

    float* ws = (float*)d_ws;
    float*    dis     = ws + O_DIS;
    int*      counts  = (int*)(ws + O_CNT);
    float*    wdeg    = ws + O_WDEG;
    int*      indptr  = (int*)(ws + O_IDP);
    int*      bsum    = (int*)(ws + O_BSUM);
    int*      csr_src = (int*)(ws + O_CSR_S);
    float*    csr_w   = ws + O_CSR_W;
    float*    esd     = ws + O_ESD;
    u32*      genc    = (u32*)(ws + O_GE);
    float*    cmp1    = ws + O_CMP1;
    float*    cmp2    = ws + O_CMP2;
    float*    tmp     = ws + O_TMP;
    u16*      U       = (u16*)(ws + O_U);
    u16*      ABX     = U + U_ABX;
    u16*      AGG     = U + U_AGG;
    u16*      y       = U + U_Y;
    u16*      ABF     = U + U_ABF;
    u16*      ABG     = U + U_ABG;
    u16*      BTG     = U + U_BTG;
    u16*      BTGCN   = U + U_BTGCN;
    u16*      BTY1    = U + U_BTY1;
    u16*      BTY2    = U + U_BTY2;
    u16*      BTS1    = U + U_BTS1;
    u16*      BTS2    = U + U_BTS2;

    const int EB = (N_EDGES + 255) / 256;
    const int NB4 = N_NODES / 4;   // 7500
    const int GB_ = MP / 64;       // 469

    // ---- weight/X conversions + zeroing (counts, wdeg, genc) ----
    k_cvtW<<<(SW_TOT + 255) / 256, 256, 0, stream>>>(
        W_fc1, W_fc2, W_gcn, W_gat1, W_gat2, W_g1, W_g2, X,
        a_src1, a_dst1, a_src2, a_dst2,
        BTG, BTGCN, BTY1, BTY2, BTS1, BTS2, cmp1, cmp2, ABX,
        (u32*)counts, (u32*)wdeg, genc);

    // ---- CSR build ----
    k_count<<<EB, 256, 0, stream>>>(EI, EW, counts, wdeg);
    k_bsum<<<NBLK, 256, 0, stream>>>(counts, wdeg, bsum, dis);
    k_apply<<<NBLK, 256, 0, stream>>>(counts, bsum, indptr);
    k_scatter<<<EB, 256, 0, stream>>>(EI, EW, indptr, counts, csr_src, csr_w);

    // ---- GCN: aggregate X-domain, then GEMM (emits x1 -> ABF/ABG + esd1) ----
    k_gcn_aggX<<<NB4, 256, 0, stream>>>(ABX, indptr, csr_src, csr_w, dis, AGG);
    k_gemm<3, true><<<GB_, 256, 0, stream>>>(AGG, BTGCN, N_NODES, HID, 64,
                                             nullptr, ABF, 160, 160, ABG, 288, 132,
                                             b_gcn, 1, 0, nullptr, nullptr, nullptr,
                                             cmp1, esd);

    // ---- GAT layer 1 ----
    k_gat_node<<<NB4, 256, 0, stream>>>(ABF, esd, indptr, csr_src, tmp, y);
    k_gemm<3, false><<<GB_, 256, 0, stream>>>(y, BTY1, N_NODES, HID, YW,
                                              nullptr, ABG, 288, 0, nullptr, 0, 0,
                                              b_gat1, 1, 0, nullptr, nullptr, nullptr,
                                              nullptr, nullptr);
    // gate 1: x2 -> ABF (x-table layer 2) + ABG cols 132.. + esd2
    k_gemm<3, true><<<GB_, 256, 0, stream>>>(ABG, BTG, N_NODES, HID, 288,
                                             nullptr, ABF, 160, 160, ABG, 288, 132,
                                             b_fc1, 0, 1, b_fc2, pro_bias, nullptr,
                                             cmp2, esd);

    // ---- GAT layer 2 ----
    k_gat_node<<<NB4, 256, 0, stream>>>(ABF, esd, indptr, csr_src, tmp, y);
    k_gemm<3, false><<<GB_, 256, 0, stream>>>(y, BTY2, N_NODES, HID, YW,
                                              nullptr, ABG, 288, 0, nullptr, 0, 0,
                                              b_gat2, 0, 0, nullptr, nullptr, nullptr,
                                              nullptr, nullptr);
    // gate 2: pool directly into genc
    k_gemm<3, false><<<GB_, 256, 0, stream>>>(ABG, BTG, N_NODES, HID, 288,
                                              nullptr, nullptr, 0, 0, nullptr, 0, 0,
                                              b_fc1, 0, 1, b_fc2, pro_bias, genc,
                                              nullptr, nullptr);

    // ---- MLP head ----
    k_head<<<GRAPHS, 256, 0, stream>>>(genc, BTS1, BTS2, b_g1, b_g2, OUT);
}